// Round 7
// baseline (510.932 us; speedup 1.0000x reference)
//
#include <hip/hip_runtime.h>
#include <math.h>

// Problem constants
#define T_TOK 1024
#define DIM 512
#define INTER 256
#define SINTER 1024
#define NEXP 64
#define TOPK 6
#define MAXTILES 512

typedef unsigned short u16;
typedef unsigned int u32;
typedef short bf16x8 __attribute__((ext_vector_type(8)));   // 8 bf16 (4 VGPRs)
typedef float f32x4  __attribute__((ext_vector_type(4)));   // MFMA 16x16 accumulator

__device__ __forceinline__ float bflo(u32 u) { return __uint_as_float(u << 16); }
__device__ __forceinline__ float bfhi(u32 u) { return __uint_as_float(u & 0xffff0000u); }

__device__ __forceinline__ u16 f2bf(float f) {
    u32 u = __float_as_uint(f);
    return (u16)((u + 0x7fffu + ((u >> 16) & 1u)) >> 16);  // RNE
}

__device__ __forceinline__ f32x4 mfma16(bf16x8 a, bf16x8 b, f32x4 c) {
    return __builtin_amdgcn_mfma_f32_16x16x32_bf16(a, b, c, 0, 0, 0);
}

// split fp32 -> (hi bf16, lo bf16): v ~= vh + vl, combined err ~2^-16|v|
__device__ __forceinline__ void split1(float v, u16& h, u16& l) {
    u32 u = __float_as_uint(v);
    u32 hb = u & 0xffff0000u;
    float r = v - __uint_as_float(hb);
    h = (u16)(hb >> 16);
    l = (u16)(__float_as_uint(r) >> 16);
}

// split 8 consecutive fp32 (32B-aligned) into hi/lo bf16x8 packed as uint4
__device__ __forceinline__ void split8u(const float* __restrict__ s, uint4& H, uint4& L) {
    const uint4* q = (const uint4*)s;
    uint4 A = q[0], B = q[1];
    u32 wv[8] = {A.x, A.y, A.z, A.w, B.x, B.y, B.z, B.w};
    u32 hp[4], lp[4];
    #pragma unroll
    for (int i = 0; i < 4; ++i) {
        u32 u0 = wv[2*i], u1 = wv[2*i+1];
        u32 h0 = u0 & 0xffff0000u, h1 = u1 & 0xffff0000u;
        float r0 = __uint_as_float(u0) - __uint_as_float(h0);
        float r1 = __uint_as_float(u1) - __uint_as_float(h1);
        hp[i] = (h0 >> 16) | h1;
        lp[i] = (__float_as_uint(r0) >> 16) | (__float_as_uint(r1) & 0xffff0000u);
    }
    H.x = hp[0]; H.y = hp[1]; H.z = hp[2]; H.w = hp[3];
    L.x = lp[0]; L.y = lp[1]; L.z = lp[2]; L.w = lp[3];
}

// load 8 consecutive elements (idx must be a multiple of 8) as floats
template<bool BF>
__device__ __forceinline__ void ld8(const void* p, size_t idx, float* f) {
    if (BF) {
        uint4 u = *(const uint4*)((const u16*)p + idx);
        f[0] = bflo(u.x); f[1] = bfhi(u.x);
        f[2] = bflo(u.y); f[3] = bfhi(u.y);
        f[4] = bflo(u.z); f[5] = bfhi(u.z);
        f[6] = bflo(u.w); f[7] = bfhi(u.w);
    } else {
        const float4* q = (const float4*)((const float*)p + idx);
        float4 a = q[0], b = q[1];
        f[0] = a.x; f[1] = a.y; f[2] = a.z; f[3] = a.w;
        f[4] = b.x; f[5] = b.y; f[6] = b.z; f[7] = b.w;
    }
}

// load 2 consecutive elements (idx even)
template<bool BF>
__device__ __forceinline__ void ld2(const void* p, size_t idx, float& a, float& b) {
    if (BF) { u32 w = *(const u32*)((const u16*)p + idx); a = bflo(w); b = bfhi(w); }
    else    { float2 v = *(const float2*)((const float*)p + idx); a = v.x; b = v.y; }
}

__device__ __forceinline__ void fma44(float& acc, const float* f, const float4& a, const float4& b) {
    acc = fmaf(f[0], a.x, acc); acc = fmaf(f[1], a.y, acc);
    acc = fmaf(f[2], a.z, acc); acc = fmaf(f[3], a.w, acc);
    acc = fmaf(f[4], b.x, acc); acc = fmaf(f[5], b.y, acc);
    acc = fmaf(f[6], b.z, acc); acc = fmaf(f[7], b.w, acc);
}

// ---------------- kernel P: dtype probe ----------------
__global__ void k_probe(const u32* __restrict__ xw, int* __restrict__ flag) {
    int cnt = 0;
    #pragma unroll
    for (int i = 0; i < 8; ++i) {
        u32 u = xw[threadIdx.x * 8 + i];
        u32 e = (u >> 7) & 0xffu;           // exponent of low-half-as-bf16
        cnt += (e >= 110 && e <= 140) ? 1 : 0;
    }
    #pragma unroll
    for (int off = 32; off; off >>= 1) cnt += __shfl_xor(cnt, off);
    if (threadIdx.x == 0) flag[0] = (cnt > 256) ? 1 : 0;
}

// ---------------- kernel 0: zero the expert counters ----------------
__global__ void k_init(int* counts) {
    counts[threadIdx.x] = 0;
}

// ---------------- kernel 1: router, 4 tokens/block (4 waves) ----------------
template<bool BF>
__device__ __forceinline__ void router_body(const void* __restrict__ xg,
                                            const void* __restrict__ wg,
                                            int* __restrict__ counts,
                                            int* __restrict__ topki,
                                            float* __restrict__ topkw,
                                            float* xsrow, int t, int lane) {
    ld8<BF>(xg, (size_t)t * DIM + lane * 8, &xsrow[lane * 8]);
    __syncthreads();

    // score for expert `lane`
    float acc = 0.f;
    for (int k = 0; k < 64; ++k) {
        float f[8]; ld8<BF>(wg, (size_t)lane * DIM + k * 8, f);
        float4 xa = *(const float4*)&xsrow[k * 8];
        float4 xb = *(const float4*)&xsrow[k * 8 + 4];
        fma44(acc, f, xa, xb);
    }

    // top-k: butterfly reduce leaves (v,id) replicated in all lanes
    float my = acc;
    float sv[TOPK]; int si[TOPK];
    #pragma unroll
    for (int s = 0; s < TOPK; ++s) {
        float v = my; int id = lane;
        #pragma unroll
        for (int off = 32; off; off >>= 1) {
            float ov = __shfl_xor(v, off);
            int   oi = __shfl_xor(id, off);
            if (ov > v || (ov == v && oi < id)) { v = ov; id = oi; }
        }
        sv[s] = v; si[s] = id;
        if (lane == id) my = -INFINITY;
    }
    if (lane == 0) {
        float m = sv[0], sum = 0.f, w[TOPK];
        #pragma unroll
        for (int s = 0; s < TOPK; ++s) { w[s] = __expf(sv[s] - m); sum += w[s]; }
        float inv = 1.f / sum;
        #pragma unroll
        for (int s = 0; s < TOPK; ++s) {
            int e = si[s];
            topki[t * TOPK + s] = e;
            topkw[t * TOPK + s] = w[s] * inv;
            atomicAdd(&counts[e], 1);
        }
    }
}

__global__ __launch_bounds__(256) void k_router(const void* xg, const void* wg,
                                                const int* __restrict__ flag,
                                                int* counts, int* topki, float* topkw) {
    __shared__ __align__(16) float xs[4][DIM];   // 8 KB
    const int wv = threadIdx.x >> 6, lane = threadIdx.x & 63;
    const int t = blockIdx.x * 4 + wv;
    if (*flag) router_body<true >(xg, wg, counts, topki, topkw, xs[wv], t, lane);
    else       router_body<false>(xg, wg, counts, topki, topkw, xs[wv], t, lane);
}

// ---------------- kernel 2: prefix sum + XCD-binned tile slots ----------------
// slot2tile[s] = tile index or -1. Expert e's tiles occupy slots == (e&7) mod 8,
// so (with 8-XCD round-robin dispatch and gridDim.x%8==0) all blocks reading
// expert e's weights land on one XCD -> each weight byte fetched from HBM once.
__global__ void k_prefix(const int* __restrict__ counts, int* __restrict__ offsets,
                         int* __restrict__ cursors, int* __restrict__ tileE,
                         int* __restrict__ tileT, int* __restrict__ tileC,
                         int* __restrict__ ntiles, int* __restrict__ slot2tile) {
    if (threadIdx.x == 0) {
        int acc = 0, nt = 0;
        for (int e = 0; e < NEXP; ++e) {
            offsets[e] = acc; cursors[e] = acc;
            int c = counts[e];
            for (int t = 0; t < c && nt < MAXTILES; t += 16) {
                tileE[nt] = e; tileT[nt] = t;
                tileC[nt] = min(16, c - t);
                ++nt;
            }
            acc += c;
        }
        *ntiles = nt;
        for (int i = 0; i < MAXTILES; ++i) slot2tile[i] = -1;
        int cb[8] = {0, 0, 0, 0, 0, 0, 0, 0};
        int ovf[MAXTILES]; int nov = 0;
        for (int t = 0; t < nt; ++t) {
            int b = tileE[t] & 7;
            int s = cb[b] * 8 + b;
            if (s < MAXTILES) { slot2tile[s] = t; cb[b]++; }
            else ovf[nov++] = t;
        }
        int p = 0;
        for (int i = 0; i < nov; ++i) {          // nt <= 448 < MAXTILES: always fits
            while (slot2tile[p] >= 0) ++p;
            slot2tile[p] = ovf[i];
        }
    }
}

// ---------------- kernel 3: scatter tokens into expert buckets ----------------
__global__ void k_scatter(const int* __restrict__ topki, const float* __restrict__ topkw,
                          int* __restrict__ cursors, int* __restrict__ tokl,
                          float* __restrict__ wgtl) {
    int t = blockIdx.x * 256 + threadIdx.x;
    #pragma unroll
    for (int s = 0; s < TOPK; ++s) {
        int e = topki[t * TOPK + s];
        float w = topkw[t * TOPK + s];
        int pos = atomicAdd(&cursors[e], 1);
        tokl[pos] = t;
        wgtl[pos] = w;
    }
}

// ============== fp32 path: split-bf16 MFMA kernels ==============

// ---------------- kernel B: bulk split fp32 tensors -> hi/lo bf16 planes ----------------
__global__ __launch_bounds__(256) void k_bsplit(
        const float* __restrict__ w1, const float* __restrict__ w3,
        const float* __restrict__ wsg, const float* __restrict__ wsu,
        const float* __restrict__ wsd, const float* __restrict__ x,
        u16* w1h, u16* w1l, u16* w3h, u16* w3l,
        u16* wsgh, u16* wsgl, u16* wsuh, u16* wsul,
        u16* wsdh, u16* wsdl, u16* xh, u16* xl,
        const int* __restrict__ flag) {
    if (*flag) return;
    const int b = blockIdx.x;
    const float* src; u16* dh; u16* dl; size_t base;
    if (b < 4096)      { src = w1;  dh = w1h;  dl = w1l;  base = (size_t)b * 2048; }
    else if (b < 8192) { src = w3;  dh = w3h;  dl = w3l;  base = (size_t)(b - 4096) * 2048; }
    else if (b < 8448) { src = wsg; dh = wsgh; dl = wsgl; base = (size_t)(b - 8192) * 2048; }
    else if (b < 8704) { src = wsu; dh = wsuh; dl = wsul; base = (size_t)(b - 8448) * 2048; }
    else if (b < 8960) { src = wsd; dh = wsdh; dl = wsdl; base = (size_t)(b - 8704) * 2048; }
    else               { src = x;   dh = xh;   dl = xl;   base = (size_t)(b - 8960) * 2048; }
    size_t idx = base + (size_t)threadIdx.x * 8;
    uint4 H, L;
    split8u(src + idx, H, L);
    *(uint4*)(dh + idx) = H;
    *(uint4*)(dl + idx) = L;
}

// ---------------- kernel W: transpose+split w2 [e][i][d] -> hi/lo [e][d][i] ----------------
__global__ __launch_bounds__(256) void k_w2ts(const float* __restrict__ w2,
                                              u16* __restrict__ w2th,
                                              u16* __restrict__ w2tl,
                                              const int* __restrict__ flag) {
    if (*flag) return;
    __shared__ u32 lt[128][65];              // packed hi<<16|lo; pad 65 breaks conflicts
    const int e  = blockIdx.x >> 4;
    const int ic = (blockIdx.x >> 3) & 1;    // i-chunk of 128
    const int dc = blockIdx.x & 7;           // d-chunk of 64
    const int tid = threadIdx.x;
    const float* src = w2 + (size_t)e * INTER * DIM + (size_t)(ic * 128) * DIM + dc * 64;
    #pragma unroll
    for (int p = 0; p < 8; ++p) {
        int f = p * 256 + tid;               // 0..2047 float4s
        int i = f >> 4, dq = f & 15;
        float4 v = *(const float4*)(src + (size_t)i * DIM + dq * 4);
        float vv[4] = {v.x, v.y, v.z, v.w};
        #pragma unroll
        for (int j = 0; j < 4; ++j) {
            u32 u = __float_as_uint(vv[j]);
            u32 hb = u & 0xffff0000u;
            float r = vv[j] - __uint_as_float(hb);
            lt[i][dq * 4 + j] = hb | (__float_as_uint(r) >> 16);
        }
    }
    __syncthreads();
    const int dl = tid & 63, q = tid >> 6;   // wave q handles i-chunk q*32
    size_t rb = ((size_t)e * DIM + dc * 64 + dl) * INTER + ic * 128 + q * 32;
    #pragma unroll
    for (int s = 0; s < 4; ++s) {
        u32 h2[4], l2[4];
        #pragma unroll
        for (int m = 0; m < 4; ++m) {
            u32 p0 = lt[q * 32 + s * 8 + m * 2][dl];
            u32 p1 = lt[q * 32 + s * 8 + m * 2 + 1][dl];
            h2[m] = (p0 >> 16) | (p1 & 0xffff0000u);
            l2[m] = (p0 & 0xffffu) | (p1 << 16);
        }
        uint4 Hv = {h2[0], h2[1], h2[2], h2[3]};
        uint4 Lv = {l2[0], l2[1], l2[2], l2[3]};
        *(uint4*)(w2th + rb + s * 8) = Hv;
        *(uint4*)(w2tl + rb + s * 8) = Lv;
    }
}

// ---------------- kernel SA5: shared up/gate, fine-grained ----------------
// grid = 64 token-tiles x 8 sinter-chunks of 128 (chunk in low bits -> per-XCD weight slice).
__global__ __launch_bounds__(256) void k_shA5(const u16* __restrict__ xh,
                                              const u16* __restrict__ xl,
                                              const u16* __restrict__ wsgh,
                                              const u16* __restrict__ wsgl,
                                              const u16* __restrict__ wsuh,
                                              const u16* __restrict__ wsul,
                                              u16* __restrict__ vh, u16* __restrict__ vl,
                                              const int* __restrict__ flag) {
    if (*flag) return;
    __shared__ __align__(16) u16 xsh[16 * 512], xsl[16 * 512];   // 32 KB swizzled
    const int tt = blockIdx.x >> 3;          // token tile (16 rows)
    const int sc = blockIdx.x & 7;           // sinter chunk of 128
    const int tid = threadIdx.x;
    const int w = tid >> 6, lane = tid & 63;
    const int lr = lane & 15, lg = lane >> 4;

    for (int idx = tid; idx < 16 * 64; idx += 256) {
        int r = idx >> 6, c = idx & 63;
        int off = r * 1024 + ((c * 16) ^ ((r & 7) << 4));
        size_t g = (size_t)(tt * 16 + r) * DIM + c * 8;
        *(uint4*)((char*)xsh + off) = *(const uint4*)(xh + g);
        *(uint4*)((char*)xsl + off) = *(const uint4*)(xl + g);
    }
    __syncthreads();

    const f32x4 z4 = {0.f, 0.f, 0.f, 0.f};
    f32x4 ag[2] = {z4, z4};
    f32x4 au[2] = {z4, z4};
    const int j0 = sc * 128 + w * 32;
    #pragma unroll 2
    for (int ks = 0; ks < 16; ++ks) {
        const int k0 = ks * 32 + lg * 8;
        const int xoff = lr * 1024 + ((k0 * 2) ^ ((lr & 7) << 4));
        bf16x8 ah = *(const bf16x8*)((const char*)xsh + xoff);
        bf16x8 al = *(const bf16x8*)((const char*)xsl + xoff);
        #pragma unroll
        for (int q = 0; q < 2; ++q) {
            const size_t row = (size_t)(j0 + q * 16 + lr) * DIM + k0;
            bf16x8 bh = *(const bf16x8*)(wsgh + row);
            bf16x8 bl = *(const bf16x8*)(wsgl + row);
            ag[q] = mfma16(ah, bh, ag[q]);
            ag[q] = mfma16(ah, bl, ag[q]);
            ag[q] = mfma16(al, bh, ag[q]);
            bh = *(const bf16x8*)(wsuh + row);
            bl = *(const bf16x8*)(wsul + row);
            au[q] = mfma16(ah, bh, au[q]);
            au[q] = mfma16(ah, bl, au[q]);
            au[q] = mfma16(al, bh, au[q]);
        }
    }
    #pragma unroll
    for (int q = 0; q < 2; ++q) {
        #pragma unroll
        for (int r = 0; r < 4; ++r) {
            const int t = lg * 4 + r;
            float g = ag[q][r];
            float v = g / (1.f + __expf(-g)) * au[q][r];
            u16 h16, l16; split1(v, h16, l16);
            size_t o = (size_t)(tt * 16 + t) * SINTER + j0 + q * 16 + lr;
            vh[o] = h16;
            vl[o] = l16;
        }
    }
}

// ---------------- kernel SB4: shared down from pre-split planes ----------------
__global__ __launch_bounds__(256) void k_shB4(const u16* __restrict__ vh,
                                              const u16* __restrict__ vl,
                                              const u16* __restrict__ wsdh,
                                              const u16* __restrict__ wsdl,
                                              float* __restrict__ accum,
                                              const int* __restrict__ flag) {
    if (*flag) return;
    const int tt = blockIdx.x >> 3;          // token tile (16)
    const int dc = blockIdx.x & 7;           // 64-dim chunk
    const int w = threadIdx.x >> 6, lane = threadIdx.x & 63;
    const int lr = lane & 15, lg = lane >> 4;
    const int d0 = dc * 64 + w * 16;
    const u16* vhrow = vh + (size_t)(tt * 16 + lr) * SINTER;
    const u16* vlrow = vl + (size_t)(tt * 16 + lr) * SINTER;
    const u16* whrow = wsdh + (size_t)(d0 + lr) * SINTER;
    const u16* wlrow = wsdl + (size_t)(d0 + lr) * SINTER;
    f32x4 acc = {0.f, 0.f, 0.f, 0.f};
    #pragma unroll 4
    for (int ks = 0; ks < 32; ++ks) {
        const int k0 = ks * 32 + lg * 8;
        bf16x8 avh = *(const bf16x8*)(vhrow + k0);
        bf16x8 avl = *(const bf16x8*)(vlrow + k0);
        bf16x8 bh  = *(const bf16x8*)(whrow + k0);
        bf16x8 bl  = *(const bf16x8*)(wlrow + k0);
        acc = mfma16(avh, bh, acc);
        acc = mfma16(avh, bl, acc);
        acc = mfma16(avl, bh, acc);
    }
    #pragma unroll
    for (int r = 0; r < 4; ++r)
        accum[(size_t)(tt * 16 + lg * 4 + r) * DIM + d0 + lr] = acc[r];
}

// ---------------- kernel RA: routed phase 1, slot-swizzled; blockIdx.y = inter half ----------------
__global__ __launch_bounds__(256) void k_rA(
        const u16* __restrict__ xh, const u16* __restrict__ xl,
        const u16* __restrict__ w1h, const u16* __restrict__ w1l,
        const u16* __restrict__ w3h, const u16* __restrict__ w3l,
        const int* __restrict__ flag, const int* __restrict__ offsets,
        const int* __restrict__ tokl, const float* __restrict__ wgtl,
        const int* __restrict__ tileE, const int* __restrict__ tileT,
        const int* __restrict__ tileC, const int* __restrict__ slot2tile,
        u16* __restrict__ hh, u16* __restrict__ hl) {
    if (*flag) return;
    const int tileIdx = slot2tile[blockIdx.x];
    if (tileIdx < 0) return;
    const int ih = blockIdx.y;               // inter half of 128
    __shared__ __align__(16) u16 xsh[16 * 512], xsl[16 * 512];   // 32 KB
    __shared__ int   stok[16];
    __shared__ float ssw[16];
    const int tid = threadIdx.x;
    const int lane = tid & 63, w = tid >> 6;
    const int lr = lane & 15, lg = lane >> 4;
    const int e = tileE[tileIdx];
    const int cnt = tileC[tileIdx];
    const int sbase = offsets[e] + tileT[tileIdx];
    const size_t wbase = (size_t)e * INTER * DIM;

    if (tid < 16) {
        int ok = tid < cnt;
        stok[tid] = ok ? tokl[sbase + tid] : tokl[sbase];   // pad: valid token, ssw=0
        ssw[tid]  = ok ? wgtl[sbase + tid] : 0.f;
    }
    __syncthreads();
    for (int idx = tid; idx < 16 * 64; idx += 256) {
        int r = idx >> 6, c = idx & 63;
        int off = r * 1024 + ((c * 16) ^ ((r & 7) << 4));
        size_t g = (size_t)stok[r] * DIM + c * 8;
        *(uint4*)((char*)xsh + off) = *(const uint4*)(xh + g);
        *(uint4*)((char*)xsl + off) = *(const uint4*)(xl + g);
    }
    __syncthreads();

    const f32x4 z4 = {0.f, 0.f, 0.f, 0.f};
    f32x4 a1[2] = {z4, z4};
    f32x4 a3[2] = {z4, z4};
    const int j0 = ih * 128 + w * 32;
    #pragma unroll 2
    for (int ks = 0; ks < 16; ++ks) {
        const int k0 = ks * 32 + lg * 8;
        const int xoff = lr * 1024 + ((k0 * 2) ^ ((lr & 7) << 4));
        bf16x8 ah = *(const bf16x8*)((const char*)xsh + xoff);
        bf16x8 al = *(const bf16x8*)((const char*)xsl + xoff);
        #pragma unroll
        for (int q = 0; q < 2; ++q) {
            const size_t row = wbase + (size_t)(j0 + q * 16 + lr) * DIM + k0;
            bf16x8 bh = *(const bf16x8*)(w1h + row);
            bf16x8 bl = *(const bf16x8*)(w1l + row);
            a1[q] = mfma16(ah, bh, a1[q]);
            a1[q] = mfma16(ah, bl, a1[q]);
            a1[q] = mfma16(al, bh, a1[q]);
            bh = *(const bf16x8*)(w3h + row);
            bl = *(const bf16x8*)(w3l + row);
            a3[q] = mfma16(ah, bh, a3[q]);
            a3[q] = mfma16(ah, bl, a3[q]);
            a3[q] = mfma16(al, bh, a3[q]);
        }
    }
    #pragma unroll
    for (int q = 0; q < 2; ++q) {
        #pragma unroll
        for (int r = 0; r < 4; ++r) {
            const int t = lg * 4 + r;
            float g = a1[q][r];
            float h = g / (1.f + __expf(-g)) * a3[q][r] * ssw[t];
            u16 hh16, hl16; split1(h, hh16, hl16);
            size_t o = (size_t)(tileIdx * 16 + t) * INTER + j0 + q * 16 + lr;
            hh[o] = hh16;
            hl[o] = hl16;
        }
    }
}

// ---------------- kernel RB: routed phase 2, slot-swizzled; blockIdx.y = dim half ----------------
__global__ __launch_bounds__(256) void k_rB(
        const u16* __restrict__ hh, const u16* __restrict__ hl,
        const u16* __restrict__ w2th, const u16* __restrict__ w2tl,
        const int* __restrict__ flag, const int* __restrict__ offsets,
        const int* __restrict__ tokl,
        const int* __restrict__ tileE, const int* __restrict__ tileT,
        const int* __restrict__ tileC, const int* __restrict__ slot2tile,
        float* __restrict__ accum) {
    if (*flag) return;
    const int tileIdx = slot2tile[blockIdx.x];
    if (tileIdx < 0) return;
    const int dh = blockIdx.y;               // dim half of 256
    const int tid = threadIdx.x;
    const int lane = tid & 63, w = tid >> 6;
    const int lr = lane & 15, lg = lane >> 4;
    const int e = tileE[tileIdx];
    const int cnt = tileC[tileIdx];
    const int sbase = offsets[e] + tileT[tileIdx];
    const size_t w2base = (size_t)e * DIM * INTER;
    const int d0 = dh * 256 + w * 64;        // wave covers 64 dims (4 subtiles)

    const u16* hrh = hh + (size_t)(tileIdx * 16 + lr) * INTER;
    const u16* hrl = hl + (size_t)(tileIdx * 16 + lr) * INTER;
    const f32x4 z4 = {0.f, 0.f, 0.f, 0.f};
    f32x4 ay[4] = {z4, z4, z4, z4};
    #pragma unroll 2
    for (int ks = 0; ks < 8; ++ks) {
        const int k0 = ks * 32 + lg * 8;
        bf16x8 ah = *(const bf16x8*)(hrh + k0);
        bf16x8 al = *(const bf16x8*)(hrl + k0);
        #pragma unroll
        for (int q = 0; q < 4; ++q) {
            const size_t row = w2base + (size_t)(d0 + q * 16 + lr) * INTER + k0;
            bf16x8 bh = *(const bf16x8*)(w2th + row);
            bf16x8 bl = *(const bf16x8*)(w2tl + row);
            ay[q] = mfma16(ah, bh, ay[q]);
            ay[q] = mfma16(ah, bl, ay[q]);
            ay[q] = mfma16(al, bh, ay[q]);
        }
    }
    #pragma unroll
    for (int q = 0; q < 4; ++q) {
        #pragma unroll
        for (int r = 0; r < 4; ++r) {
            const int t = lg * 4 + r;
            if (t < cnt)
                atomicAdd(&accum[(size_t)tokl[sbase + t] * DIM + d0 + q * 16 + lr],
                          ay[q][r]);
        }
    }
}

// ============== legacy VALU kernels (bf16 inputs, or tiny-workspace fallback) ==============

template<bool BF>
__device__ __forceinline__ void shared_body(const void* __restrict__ xg,
                                            const void* __restrict__ wsg,
                                            const void* __restrict__ wsu,
                                            const void* __restrict__ wsd,
                                            float* __restrict__ accum,
                                            float* xs /*8*DIM*/, float* vsf /*8*SINTER*/) {
    const int t0 = blockIdx.x * 8;
    const int tid = threadIdx.x;

    for (int idx = tid; idx < 8 * 64; idx += 256) {
        int r = idx >> 6, c = idx & 63;
        ld8<BF>(xg, (size_t)(t0 + r) * DIM + c * 8, &xs[r * DIM + c * 8]);
    }
    __syncthreads();

    for (int jc = 0; jc < 4; ++jc) {
        int j = jc * 256 + tid;
        float ag[8] = {0}, au[8] = {0};
        for (int k = 0; k < 64; ++k) {
            float fg[8], fu[8];
            ld8<BF>(wsg, (size_t)j * DIM + k * 8, fg);
            ld8<BF>(wsu, (size_t)j * DIM + k * 8, fu);
            #pragma unroll
            for (int r = 0; r < 8; ++r) {
                float4 xa = *(const float4*)&xs[r * DIM + k * 8];
                float4 xb = *(const float4*)&xs[r * DIM + k * 8 + 4];
                fma44(ag[r], fg, xa, xb);
                fma44(au[r], fu, xa, xb);
            }
        }
        #pragma unroll
        for (int r = 0; r < 8; ++r) {
            float g = ag[r];
            vsf[r * SINTER + j] = g / (1.f + __expf(-g)) * au[r];
        }
    }
    __syncthreads();

    const int d0 = tid, d1 = tid + 256;
    float aca[8] = {0}, acb[8] = {0};
    for (int k = 0; k < 128; ++k) {
        float fa[8], fb[8];
        ld8<BF>(wsd, (size_t)d0 * SINTER + k * 8, fa);
        ld8<BF>(wsd, (size_t)d1 * SINTER + k * 8, fb);
        #pragma unroll
        for (int r = 0; r < 8; ++r) {
            float4 v0 = *(const float4*)&vsf[r * SINTER + k * 8];
            float4 v1 = *(const float4*)&vsf[r * SINTER + k * 8 + 4];
            fma44(aca[r], fa, v0, v1);
            fma44(acb[r], fb, v0, v1);
        }
    }
    #pragma unroll
    for (int r = 0; r < 8; ++r) {
        accum[(size_t)(t0 + r) * DIM + d0] = aca[r];
        accum[(size_t)(t0 + r) * DIM + d1] = acb[r];
    }
}

__global__ __launch_bounds__(256) void k_shared(const void* xg, const void* wsg,
                                                const void* wsu, const void* wsd,
                                                const int* __restrict__ flag,
                                                float* accum, int bfonly) {
    if (bfonly && !*flag) return;
    __shared__ __align__(16) float xs[8 * DIM];
    __shared__ __align__(16) float vsf[8 * SINTER];
    if (*flag) shared_body<true >(xg, wsg, wsu, wsd, accum, xs, vsf);
    else       shared_body<false>(xg, wsg, wsu, wsd, accum, xs, vsf);
}

template<bool BF>
__device__ __forceinline__ void routed_body(const void* __restrict__ xg,
                                            const void* __restrict__ w1,
                                            const void* __restrict__ w2,
                                            const void* __restrict__ w3,
                                            const int* __restrict__ offsets,
                                            const int* __restrict__ counts,
                                            const int* __restrict__ tokl,
                                            const float* __restrict__ wgtl,
                                            float* __restrict__ accum,
                                            float* xs /*16*DIM*/, float* hsf /*16*INTER*/,
                                            int* stok, float* ssw) {
    const int e = blockIdx.x & 63;
    const int slice = blockIdx.x >> 6;
    const int tid = threadIdx.x;
    const int n = counts[e];
    const int base = offsets[e];
    const size_t wbase = (size_t)e * INTER * DIM;

    for (int tile = slice * 16; tile < n; tile += 64) {
        const int nt = min(16, n - tile);
        __syncthreads();
        if (tid < 16) {
            int ok = tid < nt;
            stok[tid] = ok ? tokl[base + tile + tid] : 0;
            ssw[tid]  = ok ? wgtl[base + tile + tid] : 0.f;
        }
        __syncthreads();
        for (int idx = tid; idx < 16 * 64; idx += 256) {
            int r = idx >> 6, c = idx & 63;
            float* xp = &xs[r * DIM + c * 8];
            if (r < nt) {
                ld8<BF>(xg, (size_t)stok[r] * DIM + c * 8, xp);
            } else {
                #pragma unroll
                for (int q = 0; q < 8; ++q) xp[q] = 0.f;
            }
        }
        __syncthreads();

        {
            float a1[16] = {0}, a3[16] = {0};
            for (int k = 0; k < 64; ++k) {
                float f1[8], f3[8];
                ld8<BF>(w1, wbase + (size_t)tid * DIM + k * 8, f1);
                ld8<BF>(w3, wbase + (size_t)tid * DIM + k * 8, f3);
                #pragma unroll
                for (int t = 0; t < 16; ++t) {
                    float4 xa = *(const float4*)&xs[t * DIM + k * 8];
                    float4 xb = *(const float4*)&xs[t * DIM + k * 8 + 4];
                    fma44(a1[t], f1, xa, xb);
                    fma44(a3[t], f3, xa, xb);
                }
            }
            #pragma unroll
            for (int t = 0; t < 16; ++t) {
                float g = a1[t];
                hsf[t * INTER + tid] = g / (1.f + __expf(-g)) * a3[t] * ssw[t];
            }
        }
        __syncthreads();

        {
            const int d0 = 2 * tid;
            float ay0[16] = {0}, ay1[16] = {0};
            for (int i = 0; i < INTER; i += 4) {
                float b0[4], b1[4];
                #pragma unroll
                for (int ii = 0; ii < 4; ++ii)
                    ld2<BF>(w2, wbase + (size_t)(i + ii) * DIM + d0, b0[ii], b1[ii]);
                #pragma unroll
                for (int t = 0; t < 16; ++t) {
                    float4 h4 = *(const float4*)&hsf[t * INTER + i];
                    ay0[t] = fmaf(h4.x, b0[0], ay0[t]); ay0[t] = fmaf(h4.y, b0[1], ay0[t]);
                    ay0[t] = fmaf(h4.z, b0[2], ay0[t]); ay0[t] = fmaf(h4.w, b0[3], ay0[t]);
                    ay1[t] = fmaf(h4.x, b1[0], ay1[t]); ay1[t] = fmaf(h4.y, b1[1], ay1[t]);
                    ay1[t] = fmaf(h4.z, b1[2], ay1[t]); ay1[t] = fmaf(h4.w, b1[3], ay1[t]);
                }
            }
            for (int t = 0; t < nt; ++t) {
                float* dst = &accum[(size_t)stok[t] * DIM + d0];
                atomicAdd(dst, ay0[t]);
                atomicAdd(dst + 1, ay1[t]);
            }
        }
    }
}

__global__ __launch_bounds__(256) void k_routed(const void* xg, const void* w1,
                                                const void* w2, const void* w3,
                                                const int* __restrict__ flag,
                                                const int* offsets, const int* counts,
                                                const int* tokl, const float* wgtl,
                                                float* accum, int bfonly) {
    if (bfonly && !*flag) return;
    __shared__ __align__(16) float xs[16 * DIM];
    __shared__ __align__(16) float hsf[16 * INTER];
    __shared__ int   stok[16];
    __shared__ float ssw[16];
    if (*flag) routed_body<true >(xg, w1, w2, w3, offsets, counts, tokl, wgtl, accum, xs, hsf, stok, ssw);
    else       routed_body<false>(xg, w1, w2, w3, offsets, counts, tokl, wgtl, accum, xs, hsf, stok, ssw);
}

// ---------------- kernel 6: fp32 accum -> output (dtype per flag) ----------------
__global__ void k_final(const float* __restrict__ accum, void* __restrict__ out,
                        const int* __restrict__ flag) {
    int i = blockIdx.x * 256 + threadIdx.x;
    float2 v = ((const float2*)accum)[i];
    if (*flag) {
        ((u32*)out)[i] = (u32)f2bf(v.x) | ((u32)f2bf(v.y) << 16);
    } else {
        ((float2*)out)[i] = v;
    }
}

extern "C" void kernel_launch(void* const* d_in, const int* in_sizes, int n_in,
                              void* d_out, int out_size, void* d_ws, size_t ws_size,
                              hipStream_t stream) {
    const void* x   = d_in[0];
    const void* wg  = d_in[1];
    const void* w1  = d_in[2];
    const void* w2  = d_in[3];
    const void* w3  = d_in[4];
    const void* wsg = d_in[5];
    const void* wsu = d_in[6];
    const void* wsd = d_in[7];

    char* ws = (char*)d_ws;
    float* accum  = (float*)ws;                              // [0, 2MiB)
    char* ctrl    = ws + ((size_t)2 << 20);
    int* counts   = (int*)ctrl;
    int* offsets  = counts + 64;
    int* cursors  = offsets + 64;
    int* topki    = cursors + 64;                            // 6144 ints
    float* topkw  = (float*)(topki + T_TOK * TOPK);          // 6144 floats
    int* tokl     = (int*)(topkw + T_TOK * TOPK);            // 6144 ints
    float* wgtl   = (float*)(tokl + T_TOK * TOPK);           // 6144 floats
    int* flag     = (int*)(wgtl + T_TOK * TOPK);
    int* tileE    = flag + 1;                                // MAXTILES ints
    int* tileT    = tileE + MAXTILES;
    int* tileC    = tileT + MAXTILES;
    int* ntiles   = tileC + MAXTILES;
    int* slot2tile = ntiles + 1;                             // MAXTILES ints
    u16* w2th = (u16*)(ws + ((size_t)3   << 20));            // 16 MiB [3,19)
    u16* w2tl = (u16*)(ws + ((size_t)19  << 20));            // 16 MiB [19,35)
    u16* vh   = (u16*)(ws + ((size_t)35  << 20));            //  2 MiB [35,37)
    u16* vl   = (u16*)(ws + ((size_t)37  << 20));            //  2 MiB [37,39)
    u16* w1h  = (u16*)(ws + ((size_t)40  << 20));            // 16 MiB [40,56)
    u16* w1l  = (u16*)(ws + ((size_t)56  << 20));            // 16 MiB [56,72)
    u16* w3h  = (u16*)(ws + ((size_t)72  << 20));            // 16 MiB [72,88)
    u16* w3l  = (u16*)(ws + ((size_t)88  << 20));            // 16 MiB [88,104)
    u16* wsgh = (u16*)(ws + ((size_t)104 << 20));            // 1 MiB each...
    u16* wsgl = (u16*)(ws + ((size_t)105 << 20));
    u16* wsuh = (u16*)(ws + ((size_t)106 << 20));
    u16* wsul = (u16*)(ws + ((size_t)107 << 20));
    u16* wsdh = (u16*)(ws + ((size_t)108 << 20));
    u16* wsdl = (u16*)(ws + ((size_t)109 << 20));
    u16* xh   = (u16*)(ws + ((size_t)110 << 20));
    u16* xl   = (u16*)(ws + ((size_t)111 << 20));
    u16* hh   = (u16*)(ws + ((size_t)112 << 20));            // 4 MiB [112,116)
    u16* hl   = (u16*)(ws + ((size_t)116 << 20));            // 4 MiB [116,120)
    const bool fast3 = ws_size >= ((size_t)120 << 20);
    const bool fast2 = !fast3 && ws_size >= ((size_t)112 << 20);

    k_probe  <<<1, 64, 0, stream>>>((const u32*)x, flag);
    k_init   <<<1, 64, 0, stream>>>(counts);
    k_router <<<T_TOK / 4, 256, 0, stream>>>(x, wg, flag, counts, topki, topkw);
    k_prefix <<<1, 64, 0, stream>>>(counts, offsets, cursors, tileE, tileT, tileC,
                                    ntiles, slot2tile);
    k_scatter<<<4, 256, 0, stream>>>(topki, topkw, cursors, tokl, wgtl);

    if (fast3) {
        k_bsplit <<<9216, 256, 0, stream>>>((const float*)w1, (const float*)w3,
                                            (const float*)wsg, (const float*)wsu,
                                            (const float*)wsd, (const float*)x,
                                            w1h, w1l, w3h, w3l, wsgh, wsgl, wsuh, wsul,
                                            wsdh, wsdl, xh, xl, flag);
        k_w2ts   <<<1024, 256, 0, stream>>>((const float*)w2, w2th, w2tl, flag);
        k_shA5   <<<512, 256, 0, stream>>>(xh, xl, wsgh, wsgl, wsuh, wsul, vh, vl, flag);
        k_shB4   <<<512, 256, 0, stream>>>(vh, vl, wsdh, wsdl, accum, flag);
        k_rA     <<<dim3(MAXTILES, 2), 256, 0, stream>>>(xh, xl, w1h, w1l, w3h, w3l, flag,
                                                         offsets, tokl, wgtl,
                                                         tileE, tileT, tileC, slot2tile,
                                                         hh, hl);
        k_rB     <<<dim3(MAXTILES, 2), 256, 0, stream>>>(hh, hl, w2th, w2tl, flag,
                                                         offsets, tokl,
                                                         tileE, tileT, tileC, slot2tile,
                                                         accum);
        // bf16-input fallback (no-ops when flag==0)
        k_shared <<<128, 256, 0, stream>>>(x, wsg, wsu, wsd, flag, accum, 1);
        k_routed <<<256, 256, 0, stream>>>(x, w1, w2, w3, flag, offsets, counts, tokl, wgtl, accum, 1);
    } else if (fast2) {
        // (fast2 tier removed in r7 simplification: fall through to legacy-style split
        //  path is not available without monolithic kernels; use legacy VALU instead)
        k_shared <<<128, 256, 0, stream>>>(x, wsg, wsu, wsd, flag, accum, 0);
        k_routed <<<256, 256, 0, stream>>>(x, w1, w2, w3, flag, offsets, counts, tokl, wgtl, accum, 0);
    } else {
        // tiny workspace: legacy VALU path for both dtypes
        k_shared <<<128, 256, 0, stream>>>(x, wsg, wsu, wsd, flag, accum, 0);
        k_routed <<<256, 256, 0, stream>>>(x, w1, w2, w3, flag, offsets, counts, tokl, wgtl, accum, 0);
    }
    k_final  <<<1024, 256, 0, stream>>>(accum, d_out, flag);
}

// Round 8
// 402.192 us; speedup vs baseline: 1.2704x; 1.2704x over previous
//
#include <hip/hip_runtime.h>
#include <math.h>

// Problem constants
#define T_TOK 1024
#define DIM 512
#define INTER 256
#define SINTER 1024
#define NEXP 64
#define TOPK 6
#define MAXTILES 512

typedef unsigned short u16;
typedef unsigned int u32;
typedef short bf16x8 __attribute__((ext_vector_type(8)));   // 8 bf16 (4 VGPRs)
typedef float f32x4  __attribute__((ext_vector_type(4)));   // MFMA 16x16 accumulator

__device__ __forceinline__ float bflo(u32 u) { return __uint_as_float(u << 16); }
__device__ __forceinline__ float bfhi(u32 u) { return __uint_as_float(u & 0xffff0000u); }

__device__ __forceinline__ u16 f2bf(float f) {
    u32 u = __float_as_uint(f);
    return (u16)((u + 0x7fffu + ((u >> 16) & 1u)) >> 16);  // RNE
}

__device__ __forceinline__ f32x4 mfma16(bf16x8 a, bf16x8 b, f32x4 c) {
    return __builtin_amdgcn_mfma_f32_16x16x32_bf16(a, b, c, 0, 0, 0);
}

// split fp32 -> (hi bf16, lo bf16): v ~= vh + vl, combined err ~2^-16|v|
__device__ __forceinline__ void split1(float v, u16& h, u16& l) {
    u32 u = __float_as_uint(v);
    u32 hb = u & 0xffff0000u;
    float r = v - __uint_as_float(hb);
    h = (u16)(hb >> 16);
    l = (u16)(__float_as_uint(r) >> 16);
}

// split 8 consecutive fp32 (32B-aligned) into hi/lo bf16x8 packed as uint4
__device__ __forceinline__ void split8u(const float* __restrict__ s, uint4& H, uint4& L) {
    const uint4* q = (const uint4*)s;
    uint4 A = q[0], B = q[1];
    u32 wv[8] = {A.x, A.y, A.z, A.w, B.x, B.y, B.z, B.w};
    u32 hp[4], lp[4];
    #pragma unroll
    for (int i = 0; i < 4; ++i) {
        u32 u0 = wv[2*i], u1 = wv[2*i+1];
        u32 h0 = u0 & 0xffff0000u, h1 = u1 & 0xffff0000u;
        float r0 = __uint_as_float(u0) - __uint_as_float(h0);
        float r1 = __uint_as_float(u1) - __uint_as_float(h1);
        hp[i] = (h0 >> 16) | h1;
        lp[i] = (__float_as_uint(r0) >> 16) | (__float_as_uint(r1) & 0xffff0000u);
    }
    H.x = hp[0]; H.y = hp[1]; H.z = hp[2]; H.w = hp[3];
    L.x = lp[0]; L.y = lp[1]; L.z = lp[2]; L.w = lp[3];
}

// load 8 consecutive elements (idx must be a multiple of 8) as floats
template<bool BF>
__device__ __forceinline__ void ld8(const void* p, size_t idx, float* f) {
    if (BF) {
        uint4 u = *(const uint4*)((const u16*)p + idx);
        f[0] = bflo(u.x); f[1] = bfhi(u.x);
        f[2] = bflo(u.y); f[3] = bfhi(u.y);
        f[4] = bflo(u.z); f[5] = bfhi(u.z);
        f[6] = bflo(u.w); f[7] = bfhi(u.w);
    } else {
        const float4* q = (const float4*)((const float*)p + idx);
        float4 a = q[0], b = q[1];
        f[0] = a.x; f[1] = a.y; f[2] = a.z; f[3] = a.w;
        f[4] = b.x; f[5] = b.y; f[6] = b.z; f[7] = b.w;
    }
}

// load 2 consecutive elements (idx even)
template<bool BF>
__device__ __forceinline__ void ld2(const void* p, size_t idx, float& a, float& b) {
    if (BF) { u32 w = *(const u32*)((const u16*)p + idx); a = bflo(w); b = bfhi(w); }
    else    { float2 v = *(const float2*)((const float*)p + idx); a = v.x; b = v.y; }
}

__device__ __forceinline__ void fma44(float& acc, const float* f, const float4& a, const float4& b) {
    acc = fmaf(f[0], a.x, acc); acc = fmaf(f[1], a.y, acc);
    acc = fmaf(f[2], a.z, acc); acc = fmaf(f[3], a.w, acc);
    acc = fmaf(f[4], b.x, acc); acc = fmaf(f[5], b.y, acc);
    acc = fmaf(f[6], b.z, acc); acc = fmaf(f[7], b.w, acc);
}

// ---------------- kernel P: dtype probe ----------------
__global__ void k_probe(const u32* __restrict__ xw, int* __restrict__ flag) {
    int cnt = 0;
    #pragma unroll
    for (int i = 0; i < 8; ++i) {
        u32 u = xw[threadIdx.x * 8 + i];
        u32 e = (u >> 7) & 0xffu;           // exponent of low-half-as-bf16
        cnt += (e >= 110 && e <= 140) ? 1 : 0;
    }
    #pragma unroll
    for (int off = 32; off; off >>= 1) cnt += __shfl_xor(cnt, off);
    if (threadIdx.x == 0) flag[0] = (cnt > 256) ? 1 : 0;
}

// ---------------- kernel 0: zero the expert counters ----------------
__global__ void k_init(int* counts) {
    counts[threadIdx.x] = 0;
}

// ---------------- kernel 1: router, 4 tokens/block (4 waves) ----------------
template<bool BF>
__device__ __forceinline__ void router_body(const void* __restrict__ xg,
                                            const void* __restrict__ wg,
                                            int* __restrict__ counts,
                                            int* __restrict__ topki,
                                            float* __restrict__ topkw,
                                            float* xsrow, int t, int lane) {
    ld8<BF>(xg, (size_t)t * DIM + lane * 8, &xsrow[lane * 8]);
    __syncthreads();

    // score for expert `lane`
    float acc = 0.f;
    for (int k = 0; k < 64; ++k) {
        float f[8]; ld8<BF>(wg, (size_t)lane * DIM + k * 8, f);
        float4 xa = *(const float4*)&xsrow[k * 8];
        float4 xb = *(const float4*)&xsrow[k * 8 + 4];
        fma44(acc, f, xa, xb);
    }

    // top-k: butterfly reduce leaves (v,id) replicated in all lanes
    float my = acc;
    float sv[TOPK]; int si[TOPK];
    #pragma unroll
    for (int s = 0; s < TOPK; ++s) {
        float v = my; int id = lane;
        #pragma unroll
        for (int off = 32; off; off >>= 1) {
            float ov = __shfl_xor(v, off);
            int   oi = __shfl_xor(id, off);
            if (ov > v || (ov == v && oi < id)) { v = ov; id = oi; }
        }
        sv[s] = v; si[s] = id;
        if (lane == id) my = -INFINITY;
    }
    if (lane == 0) {
        float m = sv[0], sum = 0.f, w[TOPK];
        #pragma unroll
        for (int s = 0; s < TOPK; ++s) { w[s] = __expf(sv[s] - m); sum += w[s]; }
        float inv = 1.f / sum;
        #pragma unroll
        for (int s = 0; s < TOPK; ++s) {
            int e = si[s];
            topki[t * TOPK + s] = e;
            topkw[t * TOPK + s] = w[s] * inv;
            atomicAdd(&counts[e], 1);
        }
    }
}

__global__ __launch_bounds__(256) void k_router(const void* xg, const void* wg,
                                                const int* __restrict__ flag,
                                                int* counts, int* topki, float* topkw) {
    __shared__ __align__(16) float xs[4][DIM];   // 8 KB
    const int wv = threadIdx.x >> 6, lane = threadIdx.x & 63;
    const int t = blockIdx.x * 4 + wv;
    if (*flag) router_body<true >(xg, wg, counts, topki, topkw, xs[wv], t, lane);
    else       router_body<false>(xg, wg, counts, topki, topkw, xs[wv], t, lane);
}

// ---------------- kernel 2: prefix sum + XCD-binned tile slots (PARALLEL) ----------------
// 64 lanes, lane e owns expert e. All prefix state in LDS; disjoint global writes.
// slot2tile[s]: expert e's tiles occupy slots == (e&7) mod 8 (one XCD's worth of
// blocks under linear round-robin), falling back to identity mapping if any bin
// would need more than MAXTILES/8 slots (correct, just unswizzled).
__global__ __launch_bounds__(64) void k_prefix(const int* __restrict__ counts,
                         int* __restrict__ offsets, int* __restrict__ cursors,
                         int* __restrict__ tileE, int* __restrict__ tileT,
                         int* __restrict__ tileC, int* __restrict__ ntiles,
                         int* __restrict__ slot2tile) {
    __shared__ int sc[NEXP], snt[NEXP], sbin[8];
    __shared__ int sflag;
    const int e = threadIdx.x;
    const int b = e & 7;
    int c = counts[e];
    sc[e] = c;
    snt[e] = (c + 15) >> 4;
    __syncthreads();

    int off = 0, tb = 0;                     // exclusive prefixes over all experts
    for (int i = 0; i < e; ++i) { off += sc[i]; tb += snt[i]; }
    int bp = 0;                              // exclusive prefix within bin (stride 8)
    for (int i = b; i < e; i += 8) bp += snt[i];
    offsets[e] = off;
    cursors[e] = off;

    if (e < 8) {                             // bin totals
        int tot = 0;
        for (int i = e; i < NEXP; i += 8) tot += snt[i];
        sbin[e] = tot;
    }
    if (e == 0) {
        int nt = 0;
        for (int i = 0; i < NEXP; ++i) nt += snt[i];
        *ntiles = nt;
    }
    #pragma unroll
    for (int i = 0; i < MAXTILES / NEXP; ++i) slot2tile[e + i * NEXP] = -1;
    __syncthreads();

    if (e == 0) {
        int f = 0;
        for (int i = 0; i < 8; ++i) if (sbin[i] > MAXTILES / 8) f = 1;
        sflag = f;
    }
    __syncthreads();

    const int swz = (sflag == 0);
    const int nt_e = snt[e];
    for (int t = 0; t < nt_e; ++t) {
        int idx = tb + t;
        tileE[idx] = e;
        tileT[idx] = t * 16;
        tileC[idx] = min(16, c - t * 16);
        int s = swz ? ((bp + t) * 8 + b) : idx;
        slot2tile[s] = idx;
    }
}

// ---------------- kernel 3: scatter tokens into expert buckets ----------------
__global__ void k_scatter(const int* __restrict__ topki, const float* __restrict__ topkw,
                          int* __restrict__ cursors, int* __restrict__ tokl,
                          float* __restrict__ wgtl) {
    int t = blockIdx.x * 256 + threadIdx.x;
    #pragma unroll
    for (int s = 0; s < TOPK; ++s) {
        int e = topki[t * TOPK + s];
        float w = topkw[t * TOPK + s];
        int pos = atomicAdd(&cursors[e], 1);
        tokl[pos] = t;
        wgtl[pos] = w;
    }
}

// ============== fp32 path: split-bf16 MFMA kernels ==============

// ---------------- kernel B: bulk split fp32 tensors -> hi/lo bf16 planes ----------------
__global__ __launch_bounds__(256) void k_bsplit(
        const float* __restrict__ w1, const float* __restrict__ w3,
        const float* __restrict__ wsg, const float* __restrict__ wsu,
        const float* __restrict__ wsd, const float* __restrict__ x,
        u16* w1h, u16* w1l, u16* w3h, u16* w3l,
        u16* wsgh, u16* wsgl, u16* wsuh, u16* wsul,
        u16* wsdh, u16* wsdl, u16* xh, u16* xl,
        const int* __restrict__ flag) {
    if (*flag) return;
    const int b = blockIdx.x;
    const float* src; u16* dh; u16* dl; size_t base;
    if (b < 4096)      { src = w1;  dh = w1h;  dl = w1l;  base = (size_t)b * 2048; }
    else if (b < 8192) { src = w3;  dh = w3h;  dl = w3l;  base = (size_t)(b - 4096) * 2048; }
    else if (b < 8448) { src = wsg; dh = wsgh; dl = wsgl; base = (size_t)(b - 8192) * 2048; }
    else if (b < 8704) { src = wsu; dh = wsuh; dl = wsul; base = (size_t)(b - 8448) * 2048; }
    else if (b < 8960) { src = wsd; dh = wsdh; dl = wsdl; base = (size_t)(b - 8704) * 2048; }
    else               { src = x;   dh = xh;   dl = xl;   base = (size_t)(b - 8960) * 2048; }
    size_t idx = base + (size_t)threadIdx.x * 8;
    uint4 H, L;
    split8u(src + idx, H, L);
    *(uint4*)(dh + idx) = H;
    *(uint4*)(dl + idx) = L;
}

// ---------------- kernel W: transpose+split w2 [e][i][d] -> hi/lo [e][d][i] ----------------
__global__ __launch_bounds__(256) void k_w2ts(const float* __restrict__ w2,
                                              u16* __restrict__ w2th,
                                              u16* __restrict__ w2tl,
                                              const int* __restrict__ flag) {
    if (*flag) return;
    __shared__ u32 lt[128][65];              // packed hi<<16|lo; pad 65 breaks conflicts
    const int e  = blockIdx.x >> 4;
    const int ic = (blockIdx.x >> 3) & 1;    // i-chunk of 128
    const int dc = blockIdx.x & 7;           // d-chunk of 64
    const int tid = threadIdx.x;
    const float* src = w2 + (size_t)e * INTER * DIM + (size_t)(ic * 128) * DIM + dc * 64;
    #pragma unroll
    for (int p = 0; p < 8; ++p) {
        int f = p * 256 + tid;               // 0..2047 float4s
        int i = f >> 4, dq = f & 15;
        float4 v = *(const float4*)(src + (size_t)i * DIM + dq * 4);
        float vv[4] = {v.x, v.y, v.z, v.w};
        #pragma unroll
        for (int j = 0; j < 4; ++j) {
            u32 u = __float_as_uint(vv[j]);
            u32 hb = u & 0xffff0000u;
            float r = vv[j] - __uint_as_float(hb);
            lt[i][dq * 4 + j] = hb | (__float_as_uint(r) >> 16);
        }
    }
    __syncthreads();
    const int dl = tid & 63, q = tid >> 6;   // wave q handles i-chunk q*32
    size_t rb = ((size_t)e * DIM + dc * 64 + dl) * INTER + ic * 128 + q * 32;
    #pragma unroll
    for (int s = 0; s < 4; ++s) {
        u32 h2[4], l2[4];
        #pragma unroll
        for (int m = 0; m < 4; ++m) {
            u32 p0 = lt[q * 32 + s * 8 + m * 2][dl];
            u32 p1 = lt[q * 32 + s * 8 + m * 2 + 1][dl];
            h2[m] = (p0 >> 16) | (p1 & 0xffff0000u);
            l2[m] = (p0 & 0xffffu) | (p1 << 16);
        }
        uint4 Hv = {h2[0], h2[1], h2[2], h2[3]};
        uint4 Lv = {l2[0], l2[1], l2[2], l2[3]};
        *(uint4*)(w2th + rb + s * 8) = Hv;
        *(uint4*)(w2tl + rb + s * 8) = Lv;
    }
}

// ---------------- kernel SA5: shared up/gate, fine-grained ----------------
__global__ __launch_bounds__(256) void k_shA5(const u16* __restrict__ xh,
                                              const u16* __restrict__ xl,
                                              const u16* __restrict__ wsgh,
                                              const u16* __restrict__ wsgl,
                                              const u16* __restrict__ wsuh,
                                              const u16* __restrict__ wsul,
                                              u16* __restrict__ vh, u16* __restrict__ vl,
                                              const int* __restrict__ flag) {
    if (*flag) return;
    __shared__ __align__(16) u16 xsh[16 * 512], xsl[16 * 512];   // 32 KB swizzled
    const int tt = blockIdx.x >> 3;          // token tile (16 rows)
    const int sc = blockIdx.x & 7;           // sinter chunk of 128
    const int tid = threadIdx.x;
    const int w = tid >> 6, lane = tid & 63;
    const int lr = lane & 15, lg = lane >> 4;

    for (int idx = tid; idx < 16 * 64; idx += 256) {
        int r = idx >> 6, c = idx & 63;
        int off = r * 1024 + ((c * 16) ^ ((r & 7) << 4));
        size_t g = (size_t)(tt * 16 + r) * DIM + c * 8;
        *(uint4*)((char*)xsh + off) = *(const uint4*)(xh + g);
        *(uint4*)((char*)xsl + off) = *(const uint4*)(xl + g);
    }
    __syncthreads();

    const f32x4 z4 = {0.f, 0.f, 0.f, 0.f};
    f32x4 ag[2] = {z4, z4};
    f32x4 au[2] = {z4, z4};
    const int j0 = sc * 128 + w * 32;
    #pragma unroll 2
    for (int ks = 0; ks < 16; ++ks) {
        const int k0 = ks * 32 + lg * 8;
        const int xoff = lr * 1024 + ((k0 * 2) ^ ((lr & 7) << 4));
        bf16x8 ah = *(const bf16x8*)((const char*)xsh + xoff);
        bf16x8 al = *(const bf16x8*)((const char*)xsl + xoff);
        #pragma unroll
        for (int q = 0; q < 2; ++q) {
            const size_t row = (size_t)(j0 + q * 16 + lr) * DIM + k0;
            bf16x8 bh = *(const bf16x8*)(wsgh + row);
            bf16x8 bl = *(const bf16x8*)(wsgl + row);
            ag[q] = mfma16(ah, bh, ag[q]);
            ag[q] = mfma16(ah, bl, ag[q]);
            ag[q] = mfma16(al, bh, ag[q]);
            bh = *(const bf16x8*)(wsuh + row);
            bl = *(const bf16x8*)(wsul + row);
            au[q] = mfma16(ah, bh, au[q]);
            au[q] = mfma16(ah, bl, au[q]);
            au[q] = mfma16(al, bh, au[q]);
        }
    }
    #pragma unroll
    for (int q = 0; q < 2; ++q) {
        #pragma unroll
        for (int r = 0; r < 4; ++r) {
            const int t = lg * 4 + r;
            float g = ag[q][r];
            float v = g / (1.f + __expf(-g)) * au[q][r];
            u16 h16, l16; split1(v, h16, l16);
            size_t o = (size_t)(tt * 16 + t) * SINTER + j0 + q * 16 + lr;
            vh[o] = h16;
            vl[o] = l16;
        }
    }
}

// ---------------- kernel SB4: shared down from pre-split planes ----------------
__global__ __launch_bounds__(256) void k_shB4(const u16* __restrict__ vh,
                                              const u16* __restrict__ vl,
                                              const u16* __restrict__ wsdh,
                                              const u16* __restrict__ wsdl,
                                              float* __restrict__ accum,
                                              const int* __restrict__ flag) {
    if (*flag) return;
    const int tt = blockIdx.x >> 3;          // token tile (16)
    const int dc = blockIdx.x & 7;           // 64-dim chunk
    const int w = threadIdx.x >> 6, lane = threadIdx.x & 63;
    const int lr = lane & 15, lg = lane >> 4;
    const int d0 = dc * 64 + w * 16;
    const u16* vhrow = vh + (size_t)(tt * 16 + lr) * SINTER;
    const u16* vlrow = vl + (size_t)(tt * 16 + lr) * SINTER;
    const u16* whrow = wsdh + (size_t)(d0 + lr) * SINTER;
    const u16* wlrow = wsdl + (size_t)(d0 + lr) * SINTER;
    f32x4 acc = {0.f, 0.f, 0.f, 0.f};
    #pragma unroll 4
    for (int ks = 0; ks < 32; ++ks) {
        const int k0 = ks * 32 + lg * 8;
        bf16x8 avh = *(const bf16x8*)(vhrow + k0);
        bf16x8 avl = *(const bf16x8*)(vlrow + k0);
        bf16x8 bh  = *(const bf16x8*)(whrow + k0);
        bf16x8 bl  = *(const bf16x8*)(wlrow + k0);
        acc = mfma16(avh, bh, acc);
        acc = mfma16(avh, bl, acc);
        acc = mfma16(avl, bh, acc);
    }
    #pragma unroll
    for (int r = 0; r < 4; ++r)
        accum[(size_t)(tt * 16 + lg * 4 + r) * DIM + d0 + lr] = acc[r];
}

// ---------------- kernel RA: routed phase 1, slot-swizzled; blockIdx.y = inter half ----------------
__global__ __launch_bounds__(256) void k_rA(
        const u16* __restrict__ xh, const u16* __restrict__ xl,
        const u16* __restrict__ w1h, const u16* __restrict__ w1l,
        const u16* __restrict__ w3h, const u16* __restrict__ w3l,
        const int* __restrict__ flag, const int* __restrict__ offsets,
        const int* __restrict__ tokl, const float* __restrict__ wgtl,
        const int* __restrict__ tileE, const int* __restrict__ tileT,
        const int* __restrict__ tileC, const int* __restrict__ slot2tile,
        u16* __restrict__ hh, u16* __restrict__ hl) {
    if (*flag) return;
    const int tileIdx = slot2tile[blockIdx.x];
    if (tileIdx < 0) return;
    const int ih = blockIdx.y;               // inter half of 128
    __shared__ __align__(16) u16 xsh[16 * 512], xsl[16 * 512];   // 32 KB
    __shared__ int   stok[16];
    __shared__ float ssw[16];
    const int tid = threadIdx.x;
    const int lane = tid & 63, w = tid >> 6;
    const int lr = lane & 15, lg = lane >> 4;
    const int e = tileE[tileIdx];
    const int cnt = tileC[tileIdx];
    const int sbase = offsets[e] + tileT[tileIdx];
    const size_t wbase = (size_t)e * INTER * DIM;

    if (tid < 16) {
        int ok = tid < cnt;
        stok[tid] = ok ? tokl[sbase + tid] : tokl[sbase];   // pad: valid token, ssw=0
        ssw[tid]  = ok ? wgtl[sbase + tid] : 0.f;
    }
    __syncthreads();
    for (int idx = tid; idx < 16 * 64; idx += 256) {
        int r = idx >> 6, c = idx & 63;
        int off = r * 1024 + ((c * 16) ^ ((r & 7) << 4));
        size_t g = (size_t)stok[r] * DIM + c * 8;
        *(uint4*)((char*)xsh + off) = *(const uint4*)(xh + g);
        *(uint4*)((char*)xsl + off) = *(const uint4*)(xl + g);
    }
    __syncthreads();

    const f32x4 z4 = {0.f, 0.f, 0.f, 0.f};
    f32x4 a1[2] = {z4, z4};
    f32x4 a3[2] = {z4, z4};
    const int j0 = ih * 128 + w * 32;
    #pragma unroll 2
    for (int ks = 0; ks < 16; ++ks) {
        const int k0 = ks * 32 + lg * 8;
        const int xoff = lr * 1024 + ((k0 * 2) ^ ((lr & 7) << 4));
        bf16x8 ah = *(const bf16x8*)((const char*)xsh + xoff);
        bf16x8 al = *(const bf16x8*)((const char*)xsl + xoff);
        #pragma unroll
        for (int q = 0; q < 2; ++q) {
            const size_t row = wbase + (size_t)(j0 + q * 16 + lr) * DIM + k0;
            bf16x8 bh = *(const bf16x8*)(w1h + row);
            bf16x8 bl = *(const bf16x8*)(w1l + row);
            a1[q] = mfma16(ah, bh, a1[q]);
            a1[q] = mfma16(ah, bl, a1[q]);
            a1[q] = mfma16(al, bh, a1[q]);
            bh = *(const bf16x8*)(w3h + row);
            bl = *(const bf16x8*)(w3l + row);
            a3[q] = mfma16(ah, bh, a3[q]);
            a3[q] = mfma16(ah, bl, a3[q]);
            a3[q] = mfma16(al, bh, a3[q]);
        }
    }
    #pragma unroll
    for (int q = 0; q < 2; ++q) {
        #pragma unroll
        for (int r = 0; r < 4; ++r) {
            const int t = lg * 4 + r;
            float g = a1[q][r];
            float h = g / (1.f + __expf(-g)) * a3[q][r] * ssw[t];
            u16 hh16, hl16; split1(h, hh16, hl16);
            size_t o = (size_t)(tileIdx * 16 + t) * INTER + j0 + q * 16 + lr;
            hh[o] = hh16;
            hl[o] = hl16;
        }
    }
}

// ---------------- kernel RB: routed phase 2, slot-swizzled; blockIdx.y = dim half ----------------
__global__ __launch_bounds__(256) void k_rB(
        const u16* __restrict__ hh, const u16* __restrict__ hl,
        const u16* __restrict__ w2th, const u16* __restrict__ w2tl,
        const int* __restrict__ flag, const int* __restrict__ offsets,
        const int* __restrict__ tokl,
        const int* __restrict__ tileE, const int* __restrict__ tileT,
        const int* __restrict__ tileC, const int* __restrict__ slot2tile,
        float* __restrict__ accum) {
    if (*flag) return;
    const int tileIdx = slot2tile[blockIdx.x];
    if (tileIdx < 0) return;
    const int dh = blockIdx.y;               // dim half of 256
    const int tid = threadIdx.x;
    const int lane = tid & 63, w = tid >> 6;
    const int lr = lane & 15, lg = lane >> 4;
    const int e = tileE[tileIdx];
    const int cnt = tileC[tileIdx];
    const int sbase = offsets[e] + tileT[tileIdx];
    const size_t w2base = (size_t)e * DIM * INTER;
    const int d0 = dh * 256 + w * 64;        // wave covers 64 dims (4 subtiles)

    const u16* hrh = hh + (size_t)(tileIdx * 16 + lr) * INTER;
    const u16* hrl = hl + (size_t)(tileIdx * 16 + lr) * INTER;
    const f32x4 z4 = {0.f, 0.f, 0.f, 0.f};
    f32x4 ay[4] = {z4, z4, z4, z4};
    #pragma unroll 2
    for (int ks = 0; ks < 8; ++ks) {
        const int k0 = ks * 32 + lg * 8;
        bf16x8 ah = *(const bf16x8*)(hrh + k0);
        bf16x8 al = *(const bf16x8*)(hrl + k0);
        #pragma unroll
        for (int q = 0; q < 4; ++q) {
            const size_t row = w2base + (size_t)(d0 + q * 16 + lr) * INTER + k0;
            bf16x8 bh = *(const bf16x8*)(w2th + row);
            bf16x8 bl = *(const bf16x8*)(w2tl + row);
            ay[q] = mfma16(ah, bh, ay[q]);
            ay[q] = mfma16(ah, bl, ay[q]);
            ay[q] = mfma16(al, bh, ay[q]);
        }
    }
    #pragma unroll
    for (int q = 0; q < 4; ++q) {
        #pragma unroll
        for (int r = 0; r < 4; ++r) {
            const int t = lg * 4 + r;
            if (t < cnt)
                atomicAdd(&accum[(size_t)tokl[sbase + t] * DIM + d0 + q * 16 + lr],
                          ay[q][r]);
        }
    }
}

// ============== legacy VALU kernels (bf16 inputs, or tiny-workspace fallback) ==============

template<bool BF>
__device__ __forceinline__ void shared_body(const void* __restrict__ xg,
                                            const void* __restrict__ wsg,
                                            const void* __restrict__ wsu,
                                            const void* __restrict__ wsd,
                                            float* __restrict__ accum,
                                            float* xs /*8*DIM*/, float* vsf /*8*SINTER*/) {
    const int t0 = blockIdx.x * 8;
    const int tid = threadIdx.x;

    for (int idx = tid; idx < 8 * 64; idx += 256) {
        int r = idx >> 6, c = idx & 63;
        ld8<BF>(xg, (size_t)(t0 + r) * DIM + c * 8, &xs[r * DIM + c * 8]);
    }
    __syncthreads();

    for (int jc = 0; jc < 4; ++jc) {
        int j = jc * 256 + tid;
        float ag[8] = {0}, au[8] = {0};
        for (int k = 0; k < 64; ++k) {
            float fg[8], fu[8];
            ld8<BF>(wsg, (size_t)j * DIM + k * 8, fg);
            ld8<BF>(wsu, (size_t)j * DIM + k * 8, fu);
            #pragma unroll
            for (int r = 0; r < 8; ++r) {
                float4 xa = *(const float4*)&xs[r * DIM + k * 8];
                float4 xb = *(const float4*)&xs[r * DIM + k * 8 + 4];
                fma44(ag[r], fg, xa, xb);
                fma44(au[r], fu, xa, xb);
            }
        }
        #pragma unroll
        for (int r = 0; r < 8; ++r) {
            float g = ag[r];
            vsf[r * SINTER + j] = g / (1.f + __expf(-g)) * au[r];
        }
    }
    __syncthreads();

    const int d0 = tid, d1 = tid + 256;
    float aca[8] = {0}, acb[8] = {0};
    for (int k = 0; k < 128; ++k) {
        float fa[8], fb[8];
        ld8<BF>(wsd, (size_t)d0 * SINTER + k * 8, fa);
        ld8<BF>(wsd, (size_t)d1 * SINTER + k * 8, fb);
        #pragma unroll
        for (int r = 0; r < 8; ++r) {
            float4 v0 = *(const float4*)&vsf[r * SINTER + k * 8];
            float4 v1 = *(const float4*)&vsf[r * SINTER + k * 8 + 4];
            fma44(aca[r], fa, v0, v1);
            fma44(acb[r], fb, v0, v1);
        }
    }
    #pragma unroll
    for (int r = 0; r < 8; ++r) {
        accum[(size_t)(t0 + r) * DIM + d0] = aca[r];
        accum[(size_t)(t0 + r) * DIM + d1] = acb[r];
    }
}

__global__ __launch_bounds__(256) void k_shared(const void* xg, const void* wsg,
                                                const void* wsu, const void* wsd,
                                                const int* __restrict__ flag,
                                                float* accum, int bfonly) {
    if (bfonly && !*flag) return;
    __shared__ __align__(16) float xs[8 * DIM];
    __shared__ __align__(16) float vsf[8 * SINTER];
    if (*flag) shared_body<true >(xg, wsg, wsu, wsd, accum, xs, vsf);
    else       shared_body<false>(xg, wsg, wsu, wsd, accum, xs, vsf);
}

template<bool BF>
__device__ __forceinline__ void routed_body(const void* __restrict__ xg,
                                            const void* __restrict__ w1,
                                            const void* __restrict__ w2,
                                            const void* __restrict__ w3,
                                            const int* __restrict__ offsets,
                                            const int* __restrict__ counts,
                                            const int* __restrict__ tokl,
                                            const float* __restrict__ wgtl,
                                            float* __restrict__ accum,
                                            float* xs /*16*DIM*/, float* hsf /*16*INTER*/,
                                            int* stok, float* ssw) {
    const int e = blockIdx.x & 63;
    const int slice = blockIdx.x >> 6;
    const int tid = threadIdx.x;
    const int n = counts[e];
    const int base = offsets[e];
    const size_t wbase = (size_t)e * INTER * DIM;

    for (int tile = slice * 16; tile < n; tile += 64) {
        const int nt = min(16, n - tile);
        __syncthreads();
        if (tid < 16) {
            int ok = tid < nt;
            stok[tid] = ok ? tokl[base + tile + tid] : 0;
            ssw[tid]  = ok ? wgtl[base + tile + tid] : 0.f;
        }
        __syncthreads();
        for (int idx = tid; idx < 16 * 64; idx += 256) {
            int r = idx >> 6, c = idx & 63;
            float* xp = &xs[r * DIM + c * 8];
            if (r < nt) {
                ld8<BF>(xg, (size_t)stok[r] * DIM + c * 8, xp);
            } else {
                #pragma unroll
                for (int q = 0; q < 8; ++q) xp[q] = 0.f;
            }
        }
        __syncthreads();

        {
            float a1[16] = {0}, a3[16] = {0};
            for (int k = 0; k < 64; ++k) {
                float f1[8], f3[8];
                ld8<BF>(w1, wbase + (size_t)tid * DIM + k * 8, f1);
                ld8<BF>(w3, wbase + (size_t)tid * DIM + k * 8, f3);
                #pragma unroll
                for (int t = 0; t < 16; ++t) {
                    float4 xa = *(const float4*)&xs[t * DIM + k * 8];
                    float4 xb = *(const float4*)&xs[t * DIM + k * 8 + 4];
                    fma44(a1[t], f1, xa, xb);
                    fma44(a3[t], f3, xa, xb);
                }
            }
            #pragma unroll
            for (int t = 0; t < 16; ++t) {
                float g = a1[t];
                hsf[t * INTER + tid] = g / (1.f + __expf(-g)) * a3[t] * ssw[t];
            }
        }
        __syncthreads();

        {
            const int d0 = 2 * tid;
            float ay0[16] = {0}, ay1[16] = {0};
            for (int i = 0; i < INTER; i += 4) {
                float b0[4], b1[4];
                #pragma unroll
                for (int ii = 0; ii < 4; ++ii)
                    ld2<BF>(w2, wbase + (size_t)(i + ii) * DIM + d0, b0[ii], b1[ii]);
                #pragma unroll
                for (int t = 0; t < 16; ++t) {
                    float4 h4 = *(const float4*)&hsf[t * INTER + i];
                    ay0[t] = fmaf(h4.x, b0[0], ay0[t]); ay0[t] = fmaf(h4.y, b0[1], ay0[t]);
                    ay0[t] = fmaf(h4.z, b0[2], ay0[t]); ay0[t] = fmaf(h4.w, b0[3], ay0[t]);
                    ay1[t] = fmaf(h4.x, b1[0], ay1[t]); ay1[t] = fmaf(h4.y, b1[1], ay1[t]);
                    ay1[t] = fmaf(h4.z, b1[2], ay1[t]); ay1[t] = fmaf(h4.w, b1[3], ay1[t]);
                }
            }
            for (int t = 0; t < nt; ++t) {
                float* dst = &accum[(size_t)stok[t] * DIM + d0];
                atomicAdd(dst, ay0[t]);
                atomicAdd(dst + 1, ay1[t]);
            }
        }
    }
}

__global__ __launch_bounds__(256) void k_routed(const void* xg, const void* w1,
                                                const void* w2, const void* w3,
                                                const int* __restrict__ flag,
                                                const int* offsets, const int* counts,
                                                const int* tokl, const float* wgtl,
                                                float* accum, int bfonly) {
    if (bfonly && !*flag) return;
    __shared__ __align__(16) float xs[16 * DIM];
    __shared__ __align__(16) float hsf[16 * INTER];
    __shared__ int   stok[16];
    __shared__ float ssw[16];
    if (*flag) routed_body<true >(xg, w1, w2, w3, offsets, counts, tokl, wgtl, accum, xs, hsf, stok, ssw);
    else       routed_body<false>(xg, w1, w2, w3, offsets, counts, tokl, wgtl, accum, xs, hsf, stok, ssw);
}

// ---------------- kernel 6: fp32 accum -> output (dtype per flag) ----------------
__global__ void k_final(const float* __restrict__ accum, void* __restrict__ out,
                        const int* __restrict__ flag) {
    int i = blockIdx.x * 256 + threadIdx.x;
    float2 v = ((const float2*)accum)[i];
    if (*flag) {
        ((u32*)out)[i] = (u32)f2bf(v.x) | ((u32)f2bf(v.y) << 16);
    } else {
        ((float2*)out)[i] = v;
    }
}

extern "C" void kernel_launch(void* const* d_in, const int* in_sizes, int n_in,
                              void* d_out, int out_size, void* d_ws, size_t ws_size,
                              hipStream_t stream) {
    const void* x   = d_in[0];
    const void* wg  = d_in[1];
    const void* w1  = d_in[2];
    const void* w2  = d_in[3];
    const void* w3  = d_in[4];
    const void* wsg = d_in[5];
    const void* wsu = d_in[6];
    const void* wsd = d_in[7];

    char* ws = (char*)d_ws;
    float* accum  = (float*)ws;                              // [0, 2MiB)
    char* ctrl    = ws + ((size_t)2 << 20);
    int* counts   = (int*)ctrl;
    int* offsets  = counts + 64;
    int* cursors  = offsets + 64;
    int* topki    = cursors + 64;                            // 6144 ints
    float* topkw  = (float*)(topki + T_TOK * TOPK);          // 6144 floats
    int* tokl     = (int*)(topkw + T_TOK * TOPK);            // 6144 ints
    float* wgtl   = (float*)(tokl + T_TOK * TOPK);           // 6144 floats
    int* flag     = (int*)(wgtl + T_TOK * TOPK);
    int* tileE    = flag + 1;                                // MAXTILES ints
    int* tileT    = tileE + MAXTILES;
    int* tileC    = tileT + MAXTILES;
    int* ntiles   = tileC + MAXTILES;
    int* slot2tile = ntiles + 1;                             // MAXTILES ints
    u16* w2th = (u16*)(ws + ((size_t)3   << 20));            // 16 MiB [3,19)
    u16* w2tl = (u16*)(ws + ((size_t)19  << 20));            // 16 MiB [19,35)
    u16* vh   = (u16*)(ws + ((size_t)35  << 20));            //  2 MiB [35,37)
    u16* vl   = (u16*)(ws + ((size_t)37  << 20));            //  2 MiB [37,39)
    u16* w1h  = (u16*)(ws + ((size_t)40  << 20));            // 16 MiB [40,56)
    u16* w1l  = (u16*)(ws + ((size_t)56  << 20));            // 16 MiB [56,72)
    u16* w3h  = (u16*)(ws + ((size_t)72  << 20));            // 16 MiB [72,88)
    u16* w3l  = (u16*)(ws + ((size_t)88  << 20));            // 16 MiB [88,104)
    u16* wsgh = (u16*)(ws + ((size_t)104 << 20));            // 1 MiB each...
    u16* wsgl = (u16*)(ws + ((size_t)105 << 20));
    u16* wsuh = (u16*)(ws + ((size_t)106 << 20));
    u16* wsul = (u16*)(ws + ((size_t)107 << 20));
    u16* wsdh = (u16*)(ws + ((size_t)108 << 20));
    u16* wsdl = (u16*)(ws + ((size_t)109 << 20));
    u16* xh   = (u16*)(ws + ((size_t)110 << 20));
    u16* xl   = (u16*)(ws + ((size_t)111 << 20));
    u16* hh   = (u16*)(ws + ((size_t)112 << 20));            // 4 MiB [112,116)
    u16* hl   = (u16*)(ws + ((size_t)116 << 20));            // 4 MiB [116,120)
    const bool fast3 = ws_size >= ((size_t)120 << 20);

    k_probe  <<<1, 64, 0, stream>>>((const u32*)x, flag);
    k_init   <<<1, 64, 0, stream>>>(counts);
    k_router <<<T_TOK / 4, 256, 0, stream>>>(x, wg, flag, counts, topki, topkw);
    k_prefix <<<1, 64, 0, stream>>>(counts, offsets, cursors, tileE, tileT, tileC,
                                    ntiles, slot2tile);
    k_scatter<<<4, 256, 0, stream>>>(topki, topkw, cursors, tokl, wgtl);

    if (fast3) {
        k_bsplit <<<9216, 256, 0, stream>>>((const float*)w1, (const float*)w3,
                                            (const float*)wsg, (const float*)wsu,
                                            (const float*)wsd, (const float*)x,
                                            w1h, w1l, w3h, w3l, wsgh, wsgl, wsuh, wsul,
                                            wsdh, wsdl, xh, xl, flag);
        k_w2ts   <<<1024, 256, 0, stream>>>((const float*)w2, w2th, w2tl, flag);
        k_shA5   <<<512, 256, 0, stream>>>(xh, xl, wsgh, wsgl, wsuh, wsul, vh, vl, flag);
        k_shB4   <<<512, 256, 0, stream>>>(vh, vl, wsdh, wsdl, accum, flag);
        k_rA     <<<dim3(MAXTILES, 2), 256, 0, stream>>>(xh, xl, w1h, w1l, w3h, w3l, flag,
                                                         offsets, tokl, wgtl,
                                                         tileE, tileT, tileC, slot2tile,
                                                         hh, hl);
        k_rB     <<<dim3(MAXTILES, 2), 256, 0, stream>>>(hh, hl, w2th, w2tl, flag,
                                                         offsets, tokl,
                                                         tileE, tileT, tileC, slot2tile,
                                                         accum);
        // bf16-input fallback (no-ops when flag==0)
        k_shared <<<128, 256, 0, stream>>>(x, wsg, wsu, wsd, flag, accum, 1);
        k_routed <<<256, 256, 0, stream>>>(x, w1, w2, w3, flag, offsets, counts, tokl, wgtl, accum, 1);
    } else {
        // small workspace: legacy VALU path for both dtypes
        k_shared <<<128, 256, 0, stream>>>(x, wsg, wsu, wsd, flag, accum, 0);
        k_routed <<<256, 256, 0, stream>>>(x, w1, w2, w3, flag, offsets, counts, tokl, wgtl, accum, 0);
    }
    k_final  <<<1024, 256, 0, stream>>>(accum, d_out, flag);
}

// Round 10
// 394.703 us; speedup vs baseline: 1.2945x; 1.0190x over previous
//
#include <hip/hip_runtime.h>
#include <math.h>

// Problem constants
#define T_TOK 1024
#define DIM 512
#define INTER 256
#define SINTER 1024
#define NEXP 64
#define TOPK 6
#define MAXTILES 512

typedef unsigned short u16;
typedef unsigned int u32;
typedef short bf16x8 __attribute__((ext_vector_type(8)));   // 8 bf16 (4 VGPRs)
typedef float f32x4  __attribute__((ext_vector_type(4)));   // MFMA 16x16 accumulator

__device__ __forceinline__ float bflo(u32 u) { return __uint_as_float(u << 16); }
__device__ __forceinline__ float bfhi(u32 u) { return __uint_as_float(u & 0xffff0000u); }

__device__ __forceinline__ u16 f2bf(float f) {
    u32 u = __float_as_uint(f);
    return (u16)((u + 0x7fffu + ((u >> 16) & 1u)) >> 16);  // RNE
}

__device__ __forceinline__ f32x4 mfma16(bf16x8 a, bf16x8 b, f32x4 c) {
    return __builtin_amdgcn_mfma_f32_16x16x32_bf16(a, b, c, 0, 0, 0);
}

// split fp32 -> (hi bf16, lo bf16): v ~= vh + vl, combined err ~2^-16|v|
__device__ __forceinline__ void split1(float v, u16& h, u16& l) {
    u32 u = __float_as_uint(v);
    u32 hb = u & 0xffff0000u;
    float r = v - __uint_as_float(hb);
    h = (u16)(hb >> 16);
    l = (u16)(__float_as_uint(r) >> 16);
}

// split 8 consecutive fp32 (32B-aligned) into hi/lo bf16x8 packed as uint4
__device__ __forceinline__ void split8u(const float* __restrict__ s, uint4& H, uint4& L) {
    const uint4* q = (const uint4*)s;
    uint4 A = q[0], B = q[1];
    u32 wv[8] = {A.x, A.y, A.z, A.w, B.x, B.y, B.z, B.w};
    u32 hp[4], lp[4];
    #pragma unroll
    for (int i = 0; i < 4; ++i) {
        u32 u0 = wv[2*i], u1 = wv[2*i+1];
        u32 h0 = u0 & 0xffff0000u, h1 = u1 & 0xffff0000u;
        float r0 = __uint_as_float(u0) - __uint_as_float(h0);
        float r1 = __uint_as_float(u1) - __uint_as_float(h1);
        hp[i] = (h0 >> 16) | h1;
        lp[i] = (__float_as_uint(r0) >> 16) | (__float_as_uint(r1) & 0xffff0000u);
    }
    H.x = hp[0]; H.y = hp[1]; H.z = hp[2]; H.w = hp[3];
    L.x = lp[0]; L.y = lp[1]; L.z = lp[2]; L.w = lp[3];
}

// load 8 consecutive elements (idx must be a multiple of 8) as floats
template<bool BF>
__device__ __forceinline__ void ld8(const void* p, size_t idx, float* f) {
    if (BF) {
        uint4 u = *(const uint4*)((const u16*)p + idx);
        f[0] = bflo(u.x); f[1] = bfhi(u.x);
        f[2] = bflo(u.y); f[3] = bfhi(u.y);
        f[4] = bflo(u.z); f[5] = bfhi(u.z);
        f[6] = bflo(u.w); f[7] = bfhi(u.w);
    } else {
        const float4* q = (const float4*)((const float*)p + idx);
        float4 a = q[0], b = q[1];
        f[0] = a.x; f[1] = a.y; f[2] = a.z; f[3] = a.w;
        f[4] = b.x; f[5] = b.y; f[6] = b.z; f[7] = b.w;
    }
}

// load 2 consecutive elements (idx even)
template<bool BF>
__device__ __forceinline__ void ld2(const void* p, size_t idx, float& a, float& b) {
    if (BF) { u32 w = *(const u32*)((const u16*)p + idx); a = bflo(w); b = bfhi(w); }
    else    { float2 v = *(const float2*)((const float*)p + idx); a = v.x; b = v.y; }
}

__device__ __forceinline__ void fma44(float& acc, const float* f, const float4& a, const float4& b) {
    acc = fmaf(f[0], a.x, acc); acc = fmaf(f[1], a.y, acc);
    acc = fmaf(f[2], a.z, acc); acc = fmaf(f[3], a.w, acc);
    acc = fmaf(f[4], b.x, acc); acc = fmaf(f[5], b.y, acc);
    acc = fmaf(f[6], b.z, acc); acc = fmaf(f[7], b.w, acc);
}

// ---------------- kernel PI: dtype probe + zero counters ----------------
__global__ void k_probe_init(const u32* __restrict__ xw, int* __restrict__ flag,
                             int* __restrict__ counts) {
    counts[threadIdx.x] = 0;
    int cnt = 0;
    #pragma unroll
    for (int i = 0; i < 8; ++i) {
        u32 u = xw[threadIdx.x * 8 + i];
        u32 e = (u >> 7) & 0xffu;           // exponent of low-half-as-bf16
        cnt += (e >= 110 && e <= 140) ? 1 : 0;
    }
    #pragma unroll
    for (int off = 32; off; off >>= 1) cnt += __shfl_xor(cnt, off);
    if (threadIdx.x == 0) flag[0] = (cnt > 256) ? 1 : 0;
}

// ---------------- router body (one token per wave) ----------------
template<bool BF>
__device__ __forceinline__ void router_body(const void* __restrict__ xg,
                                            const void* __restrict__ wg,
                                            int* __restrict__ counts,
                                            int* __restrict__ topki,
                                            float* __restrict__ topkw,
                                            float* xsrow, int t, int lane) {
    ld8<BF>(xg, (size_t)t * DIM + lane * 8, &xsrow[lane * 8]);
    __syncthreads();

    float acc = 0.f;
    for (int k = 0; k < 64; ++k) {
        float f[8]; ld8<BF>(wg, (size_t)lane * DIM + k * 8, f);
        float4 xa = *(const float4*)&xsrow[k * 8];
        float4 xb = *(const float4*)&xsrow[k * 8 + 4];
        fma44(acc, f, xa, xb);
    }

    float my = acc;
    float sv[TOPK]; int si[TOPK];
    #pragma unroll
    for (int s = 0; s < TOPK; ++s) {
        float v = my; int id = lane;
        #pragma unroll
        for (int off = 32; off; off >>= 1) {
            float ov = __shfl_xor(v, off);
            int   oi = __shfl_xor(id, off);
            if (ov > v || (ov == v && oi < id)) { v = ov; id = oi; }
        }
        sv[s] = v; si[s] = id;
        if (lane == id) my = -INFINITY;
    }
    if (lane == 0) {
        float m = sv[0], sum = 0.f, w[TOPK];
        #pragma unroll
        for (int s = 0; s < TOPK; ++s) { w[s] = __expf(sv[s] - m); sum += w[s]; }
        float inv = 1.f / sum;
        #pragma unroll
        for (int s = 0; s < TOPK; ++s) {
            int e = si[s];
            topki[t * TOPK + s] = e;
            topkw[t * TOPK + s] = w[s] * inv;
            atomicAdd(&counts[e], 1);
        }
    }
}

// ---- kernel PREP: router [0,256) | bsplit [256,9472) | w2ts [9472,10496) | zero accum [10496,10752) ----
__global__ __launch_bounds__(256) void k_prep(
        const float* __restrict__ xf, const void* __restrict__ xg,
        const void* __restrict__ wgate,
        const float* __restrict__ w1, const float* __restrict__ w3,
        const float* __restrict__ wsg, const float* __restrict__ wsu,
        const float* __restrict__ wsd, const float* __restrict__ w2,
        u16* w1h, u16* w1l, u16* w3h, u16* w3l,
        u16* wsgh, u16* wsgl, u16* wsuh, u16* wsul,
        u16* wsdh, u16* wsdl, u16* xh, u16* xl,
        u16* w2th, u16* w2tl,
        int* counts, int* topki, float* topkw,
        float* __restrict__ accum,
        const int* __restrict__ flag, int dosplit) {
    __shared__ __align__(16) char smem[33280];   // max(router 8KB, w2ts 33.25KB)
    const int b = blockIdx.x;
    const int tid = threadIdx.x;

    if (b < 256) {
        // ---- router: 4 tokens per block (1 per wave) ----
        float* xs = (float*)smem;
        const int wv = tid >> 6, lane = tid & 63;
        const int t = b * 4 + wv;
        if (*flag) router_body<true >(xg, wgate, counts, topki, topkw, xs + wv * DIM, t, lane);
        else       router_body<false>(xg, wgate, counts, topki, topkw, xs + wv * DIM, t, lane);
        return;
    }
    if (b >= 10496) {
        // ---- zero accum (needed: k_dn's shB/rB both accumulate atomically) ----
        const uint4 z = {0u, 0u, 0u, 0u};
        ((uint4*)accum)[(size_t)(b - 10496) * 256 + tid] = z;
        return;
    }
    if (*flag || !dosplit) return;

    if (b < 256 + 9216) {
        // ---- bulk split fp32 -> hi/lo planes ----
        const int bb = b - 256;
        const float* src; u16* dh; u16* dl; size_t base;
        if (bb < 4096)      { src = w1;  dh = w1h;  dl = w1l;  base = (size_t)bb * 2048; }
        else if (bb < 8192) { src = w3;  dh = w3h;  dl = w3l;  base = (size_t)(bb - 4096) * 2048; }
        else if (bb < 8448) { src = wsg; dh = wsgh; dl = wsgl; base = (size_t)(bb - 8192) * 2048; }
        else if (bb < 8704) { src = wsu; dh = wsuh; dl = wsul; base = (size_t)(bb - 8448) * 2048; }
        else if (bb < 8960) { src = wsd; dh = wsdh; dl = wsdl; base = (size_t)(bb - 8704) * 2048; }
        else                { src = xf;  dh = xh;   dl = xl;   base = (size_t)(bb - 8960) * 2048; }
        size_t idx = base + (size_t)tid * 8;
        uint4 H, L;
        split8u(src + idx, H, L);
        *(uint4*)(dh + idx) = H;
        *(uint4*)(dl + idx) = L;
        return;
    }

    // ---- w2 transpose+split [e][i][d] -> hi/lo [e][d][i] ----
    {
        const int bb = b - 9472;
        u32 (*lt)[65] = (u32(*)[65])smem;        // 128 x 65 packed hi<<16|lo
        const int e  = bb >> 4;
        const int ic = (bb >> 3) & 1;            // i-chunk of 128
        const int dc = bb & 7;                   // d-chunk of 64
        const float* src = w2 + (size_t)e * INTER * DIM + (size_t)(ic * 128) * DIM + dc * 64;
        #pragma unroll
        for (int p = 0; p < 8; ++p) {
            int f = p * 256 + tid;
            int i = f >> 4, dq = f & 15;
            float4 v = *(const float4*)(src + (size_t)i * DIM + dq * 4);
            float vv[4] = {v.x, v.y, v.z, v.w};
            #pragma unroll
            for (int j = 0; j < 4; ++j) {
                u32 u = __float_as_uint(vv[j]);
                u32 hb = u & 0xffff0000u;
                float r = vv[j] - __uint_as_float(hb);
                lt[i][dq * 4 + j] = hb | (__float_as_uint(r) >> 16);
            }
        }
        __syncthreads();
        const int dl = tid & 63, q = tid >> 6;
        size_t rb = ((size_t)e * DIM + dc * 64 + dl) * INTER + ic * 128 + q * 32;
        #pragma unroll
        for (int s = 0; s < 4; ++s) {
            u32 h2[4], l2[4];
            #pragma unroll
            for (int m = 0; m < 4; ++m) {
                u32 p0 = lt[q * 32 + s * 8 + m * 2][dl];
                u32 p1 = lt[q * 32 + s * 8 + m * 2 + 1][dl];
                h2[m] = (p0 >> 16) | (p1 & 0xffff0000u);
                l2[m] = (p0 & 0xffffu) | (p1 << 16);
            }
            uint4 Hv = {h2[0], h2[1], h2[2], h2[3]};
            uint4 Lv = {l2[0], l2[1], l2[2], l2[3]};
            *(uint4*)(w2th + rb + s * 8) = Hv;
            *(uint4*)(w2tl + rb + s * 8) = Lv;
        }
    }
}

// ---------------- kernel 2: prefix sum + XCD-binned tile slots (parallel, r8-proven) ----------------
__global__ __launch_bounds__(64) void k_prefix(const int* __restrict__ counts,
                         int* __restrict__ offsets, int* __restrict__ cursors,
                         int* __restrict__ tileE, int* __restrict__ tileT,
                         int* __restrict__ tileC, int* __restrict__ ntiles,
                         int* __restrict__ slot2tile) {
    __shared__ int sc[NEXP], snt[NEXP], sbin[8];
    __shared__ int sflag;
    const int e = threadIdx.x;
    const int b = e & 7;
    int c = counts[e];
    sc[e] = c;
    snt[e] = (c + 15) >> 4;
    __syncthreads();

    int off = 0, tb = 0;
    for (int i = 0; i < e; ++i) { off += sc[i]; tb += snt[i]; }
    int bp = 0;
    for (int i = b; i < e; i += 8) bp += snt[i];
    offsets[e] = off;
    cursors[e] = off;

    if (e < 8) {
        int tot = 0;
        for (int i = e; i < NEXP; i += 8) tot += snt[i];
        sbin[e] = tot;
    }
    if (e == 0) {
        int nt = 0;
        for (int i = 0; i < NEXP; ++i) nt += snt[i];
        *ntiles = nt;
    }
    #pragma unroll
    for (int i = 0; i < MAXTILES / NEXP; ++i) slot2tile[e + i * NEXP] = -1;
    __syncthreads();

    if (e == 0) {
        int f = 0;
        for (int i = 0; i < 8; ++i) if (sbin[i] > MAXTILES / 8) f = 1;
        sflag = f;
    }
    __syncthreads();

    const int swz = (sflag == 0);
    const int nt_e = snt[e];
    for (int t = 0; t < nt_e; ++t) {
        int idx = tb + t;
        tileE[idx] = e;
        tileT[idx] = t * 16;
        tileC[idx] = min(16, c - t * 16);
        int s = swz ? ((bp + t) * 8 + b) : idx;
        slot2tile[s] = idx;
    }
}

// ---------------- kernel 3: scatter tokens into expert buckets ----------------
__global__ void k_scatter(const int* __restrict__ topki, const float* __restrict__ topkw,
                          int* __restrict__ cursors, int* __restrict__ tokl,
                          float* __restrict__ wgtl) {
    int t = blockIdx.x * 256 + threadIdx.x;
    #pragma unroll
    for (int s = 0; s < TOPK; ++s) {
        int e = topki[t * TOPK + s];
        float w = topkw[t * TOPK + s];
        int pos = atomicAdd(&cursors[e], 1);
        tokl[pos] = t;
        wgtl[pos] = w;
    }
}

// ---------------- up-projection bodies ----------------
__device__ __forceinline__ void rA_body(
        const u16* __restrict__ xh, const u16* __restrict__ xl,
        const u16* __restrict__ w1h, const u16* __restrict__ w1l,
        const u16* __restrict__ w3h, const u16* __restrict__ w3l,
        const int* __restrict__ offsets, const int* __restrict__ tokl,
        const float* __restrict__ wgtl, const int* __restrict__ tileE,
        const int* __restrict__ tileT, const int* __restrict__ tileC,
        u16* __restrict__ hh, u16* __restrict__ hl,
        int tileIdx, int ih, u16* xsh, u16* xsl, int* stok, float* ssw) {
    const int tid = threadIdx.x;
    const int lane = tid & 63, w = tid >> 6;
    const int lr = lane & 15, lg = lane >> 4;
    const int e = tileE[tileIdx];
    const int cnt = tileC[tileIdx];
    const int sbase = offsets[e] + tileT[tileIdx];
    const size_t wbase = (size_t)e * INTER * DIM;

    if (tid < 16) {
        int ok = tid < cnt;
        stok[tid] = ok ? tokl[sbase + tid] : tokl[sbase];   // pad: valid token, ssw=0
        ssw[tid]  = ok ? wgtl[sbase + tid] : 0.f;
    }
    __syncthreads();
    for (int idx = tid; idx < 16 * 64; idx += 256) {
        int r = idx >> 6, c = idx & 63;
        int off = r * 1024 + ((c * 16) ^ ((r & 7) << 4));
        size_t g = (size_t)stok[r] * DIM + c * 8;
        *(uint4*)((char*)xsh + off) = *(const uint4*)(xh + g);
        *(uint4*)((char*)xsl + off) = *(const uint4*)(xl + g);
    }
    __syncthreads();

    const f32x4 z4 = {0.f, 0.f, 0.f, 0.f};
    f32x4 a1[2] = {z4, z4};
    f32x4 a3[2] = {z4, z4};
    const int j0 = ih * 128 + w * 32;
    #pragma unroll 4
    for (int ks = 0; ks < 16; ++ks) {
        const int k0 = ks * 32 + lg * 8;
        const int xoff = lr * 1024 + ((k0 * 2) ^ ((lr & 7) << 4));
        bf16x8 ah = *(const bf16x8*)((const char*)xsh + xoff);
        bf16x8 al = *(const bf16x8*)((const char*)xsl + xoff);
        #pragma unroll
        for (int q = 0; q < 2; ++q) {
            const size_t row = wbase + (size_t)(j0 + q * 16 + lr) * DIM + k0;
            bf16x8 bh = *(const bf16x8*)(w1h + row);
            bf16x8 bl = *(const bf16x8*)(w1l + row);
            a1[q] = mfma16(ah, bh, a1[q]);
            a1[q] = mfma16(ah, bl, a1[q]);
            a1[q] = mfma16(al, bh, a1[q]);
            bh = *(const bf16x8*)(w3h + row);
            bl = *(const bf16x8*)(w3l + row);
            a3[q] = mfma16(ah, bh, a3[q]);
            a3[q] = mfma16(ah, bl, a3[q]);
            a3[q] = mfma16(al, bh, a3[q]);
        }
    }
    #pragma unroll
    for (int q = 0; q < 2; ++q) {
        #pragma unroll
        for (int r = 0; r < 4; ++r) {
            const int t = lg * 4 + r;
            float g = a1[q][r];
            float h = g / (1.f + __expf(-g)) * a3[q][r] * ssw[t];
            u16 hh16, hl16; split1(h, hh16, hl16);
            size_t o = (size_t)(tileIdx * 16 + t) * INTER + j0 + q * 16 + lr;
            hh[o] = hh16;
            hl[o] = hl16;
        }
    }
}

__device__ __forceinline__ void shA_body(
        const u16* __restrict__ xh, const u16* __restrict__ xl,
        const u16* __restrict__ wsgh, const u16* __restrict__ wsgl,
        const u16* __restrict__ wsuh, const u16* __restrict__ wsul,
        u16* __restrict__ vh, u16* __restrict__ vl,
        int tt, int sc, u16* xsh, u16* xsl) {
    const int tid = threadIdx.x;
    const int w = tid >> 6, lane = tid & 63;
    const int lr = lane & 15, lg = lane >> 4;

    for (int idx = tid; idx < 16 * 64; idx += 256) {
        int r = idx >> 6, c = idx & 63;
        int off = r * 1024 + ((c * 16) ^ ((r & 7) << 4));
        size_t g = (size_t)(tt * 16 + r) * DIM + c * 8;
        *(uint4*)((char*)xsh + off) = *(const uint4*)(xh + g);
        *(uint4*)((char*)xsl + off) = *(const uint4*)(xl + g);
    }
    __syncthreads();

    const f32x4 z4 = {0.f, 0.f, 0.f, 0.f};
    f32x4 ag[2] = {z4, z4};
    f32x4 au[2] = {z4, z4};
    const int j0 = sc * 128 + w * 32;
    #pragma unroll 4
    for (int ks = 0; ks < 16; ++ks) {
        const int k0 = ks * 32 + lg * 8;
        const int xoff = lr * 1024 + ((k0 * 2) ^ ((lr & 7) << 4));
        bf16x8 ah = *(const bf16x8*)((const char*)xsh + xoff);
        bf16x8 al = *(const bf16x8*)((const char*)xsl + xoff);
        #pragma unroll
        for (int q = 0; q < 2; ++q) {
            const size_t row = (size_t)(j0 + q * 16 + lr) * DIM + k0;
            bf16x8 bh = *(const bf16x8*)(wsgh + row);
            bf16x8 bl = *(const bf16x8*)(wsgl + row);
            ag[q] = mfma16(ah, bh, ag[q]);
            ag[q] = mfma16(ah, bl, ag[q]);
            ag[q] = mfma16(al, bh, ag[q]);
            bh = *(const bf16x8*)(wsuh + row);
            bl = *(const bf16x8*)(wsul + row);
            au[q] = mfma16(ah, bh, au[q]);
            au[q] = mfma16(ah, bl, au[q]);
            au[q] = mfma16(al, bh, au[q]);
        }
    }
    #pragma unroll
    for (int q = 0; q < 2; ++q) {
        #pragma unroll
        for (int r = 0; r < 4; ++r) {
            const int t = lg * 4 + r;
            float g = ag[q][r];
            float v = g / (1.f + __expf(-g)) * au[q][r];
            u16 h16, l16; split1(v, h16, l16);
            size_t o = (size_t)(tt * 16 + t) * SINTER + j0 + q * 16 + lr;
            vh[o] = h16;
            vl[o] = l16;
        }
    }
}

// ---------------- kernel UP: rA [0,1024) | shA [1024,1536) ----------------
// rA: slot = b%512 (keeps expert->XCD bin in low 3 bits), ih = b/512.
__global__ __launch_bounds__(256) void k_up(
        const u16* __restrict__ xh, const u16* __restrict__ xl,
        const u16* __restrict__ w1h, const u16* __restrict__ w1l,
        const u16* __restrict__ w3h, const u16* __restrict__ w3l,
        const u16* __restrict__ wsgh, const u16* __restrict__ wsgl,
        const u16* __restrict__ wsuh, const u16* __restrict__ wsul,
        const int* __restrict__ flag, const int* __restrict__ offsets,
        const int* __restrict__ tokl, const float* __restrict__ wgtl,
        const int* __restrict__ tileE, const int* __restrict__ tileT,
        const int* __restrict__ tileC, const int* __restrict__ slot2tile,
        u16* __restrict__ hh, u16* __restrict__ hl,
        u16* __restrict__ vh, u16* __restrict__ vl) {
    if (*flag) return;
    __shared__ __align__(16) char smem[33024];   // xsh 16K | xsl 16K | stok 64 | ssw 64
    u16* xsh = (u16*)smem;
    u16* xsl = (u16*)(smem + 16384);
    const int b = blockIdx.x;
    if (b < 1024) {
        const int tileIdx = slot2tile[b & 511];
        if (tileIdx < 0) return;
        int* stok = (int*)(smem + 32768);
        float* ssw = (float*)(smem + 32832);
        rA_body(xh, xl, w1h, w1l, w3h, w3l, offsets, tokl, wgtl,
                tileE, tileT, tileC, hh, hl, tileIdx, b >> 9, xsh, xsl, stok, ssw);
    } else {
        const int bb = b - 1024;
        shA_body(xh, xl, wsgh, wsgl, wsuh, wsul, vh, vl, bb >> 3, bb & 7, xsh, xsl);
    }
}

// ---------------- down-projection bodies (no LDS; BOTH accumulate atomically into zeroed accum) ----------------
__device__ __forceinline__ void rB_body(
        const u16* __restrict__ hh, const u16* __restrict__ hl,
        const u16* __restrict__ w2th, const u16* __restrict__ w2tl,
        const int* __restrict__ offsets, const int* __restrict__ tokl,
        const int* __restrict__ tileE, const int* __restrict__ tileT,
        const int* __restrict__ tileC, float* __restrict__ accum,
        int tileIdx, int dh) {
    const int tid = threadIdx.x;
    const int lane = tid & 63, w = tid >> 6;
    const int lr = lane & 15, lg = lane >> 4;
    const int e = tileE[tileIdx];
    const int cnt = tileC[tileIdx];
    const int sbase = offsets[e] + tileT[tileIdx];
    const size_t w2base = (size_t)e * DIM * INTER;
    const int d0 = dh * 256 + w * 64;

    const u16* hrh = hh + (size_t)(tileIdx * 16 + lr) * INTER;
    const u16* hrl = hl + (size_t)(tileIdx * 16 + lr) * INTER;
    const f32x4 z4 = {0.f, 0.f, 0.f, 0.f};
    f32x4 ay[4] = {z4, z4, z4, z4};
    #pragma unroll 4
    for (int ks = 0; ks < 8; ++ks) {
        const int k0 = ks * 32 + lg * 8;
        bf16x8 ah = *(const bf16x8*)(hrh + k0);
        bf16x8 al = *(const bf16x8*)(hrl + k0);
        #pragma unroll
        for (int q = 0; q < 4; ++q) {
            const size_t row = w2base + (size_t)(d0 + q * 16 + lr) * INTER + k0;
            bf16x8 bh = *(const bf16x8*)(w2th + row);
            bf16x8 bl = *(const bf16x8*)(w2tl + row);
            ay[q] = mfma16(ah, bh, ay[q]);
            ay[q] = mfma16(ah, bl, ay[q]);
            ay[q] = mfma16(al, bh, ay[q]);
        }
    }
    #pragma unroll
    for (int q = 0; q < 4; ++q) {
        #pragma unroll
        for (int r = 0; r < 4; ++r) {
            const int t = lg * 4 + r;
            if (t < cnt)
                atomicAdd(&accum[(size_t)tokl[sbase + t] * DIM + d0 + q * 16 + lr],
                          ay[q][r]);
        }
    }
}

__device__ __forceinline__ void shB_body(
        const u16* __restrict__ vh, const u16* __restrict__ vl,
        const u16* __restrict__ wsdh, const u16* __restrict__ wsdl,
        float* __restrict__ accum, int tt, int dc) {
    const int w = threadIdx.x >> 6, lane = threadIdx.x & 63;
    const int lr = lane & 15, lg = lane >> 4;
    const int d0 = dc * 64 + w * 16;
    const u16* vhrow = vh + (size_t)(tt * 16 + lr) * SINTER;
    const u16* vlrow = vl + (size_t)(tt * 16 + lr) * SINTER;
    const u16* whrow = wsdh + (size_t)(d0 + lr) * SINTER;
    const u16* wlrow = wsdl + (size_t)(d0 + lr) * SINTER;
    f32x4 acc = {0.f, 0.f, 0.f, 0.f};
    #pragma unroll 8
    for (int ks = 0; ks < 32; ++ks) {
        const int k0 = ks * 32 + lg * 8;
        bf16x8 avh = *(const bf16x8*)(vhrow + k0);
        bf16x8 avl = *(const bf16x8*)(vlrow + k0);
        bf16x8 bh  = *(const bf16x8*)(whrow + k0);
        bf16x8 bl  = *(const bf16x8*)(wlrow + k0);
        acc = mfma16(avh, bh, acc);
        acc = mfma16(avh, bl, acc);
        acc = mfma16(avl, bh, acc);
    }
    // atomicAdd (not store): rB blocks run concurrently in the same kernel (r9 race fix)
    #pragma unroll
    for (int r = 0; r < 4; ++r)
        atomicAdd(&accum[(size_t)(tt * 16 + lg * 4 + r) * DIM + d0 + lr], acc[r]);
}

// ---------------- kernel DN: rB [0,1024) | shB [1024,1536) ----------------
__global__ __launch_bounds__(256) void k_dn(
        const u16* __restrict__ hh, const u16* __restrict__ hl,
        const u16* __restrict__ w2th, const u16* __restrict__ w2tl,
        const u16* __restrict__ vh, const u16* __restrict__ vl,
        const u16* __restrict__ wsdh, const u16* __restrict__ wsdl,
        const int* __restrict__ flag, const int* __restrict__ offsets,
        const int* __restrict__ tokl,
        const int* __restrict__ tileE, const int* __restrict__ tileT,
        const int* __restrict__ tileC, const int* __restrict__ slot2tile,
        float* __restrict__ accum) {
    if (*flag) return;
    const int b = blockIdx.x;
    if (b < 1024) {
        const int tileIdx = slot2tile[b & 511];
        if (tileIdx < 0) return;
        rB_body(hh, hl, w2th, w2tl, offsets, tokl, tileE, tileT, tileC,
                accum, tileIdx, b >> 9);
    } else {
        const int bb = b - 1024;
        shB_body(vh, vl, wsdh, wsdl, accum, bb >> 3, bb & 7);
    }
}

// ============== legacy VALU kernels (bf16 inputs, or tiny-workspace fallback) ==============

template<bool BF>
__device__ __forceinline__ void shared_body(const void* __restrict__ xg,
                                            const void* __restrict__ wsg,
                                            const void* __restrict__ wsu,
                                            const void* __restrict__ wsd,
                                            float* __restrict__ accum,
                                            float* xs /*8*DIM*/, float* vsf /*8*SINTER*/) {
    const int t0 = blockIdx.x * 8;
    const int tid = threadIdx.x;

    for (int idx = tid; idx < 8 * 64; idx += 256) {
        int r = idx >> 6, c = idx & 63;
        ld8<BF>(xg, (size_t)(t0 + r) * DIM + c * 8, &xs[r * DIM + c * 8]);
    }
    __syncthreads();

    for (int jc = 0; jc < 4; ++jc) {
        int j = jc * 256 + tid;
        float ag[8] = {0}, au[8] = {0};
        for (int k = 0; k < 64; ++k) {
            float fg[8], fu[8];
            ld8<BF>(wsg, (size_t)j * DIM + k * 8, fg);
            ld8<BF>(wsu, (size_t)j * DIM + k * 8, fu);
            #pragma unroll
            for (int r = 0; r < 8; ++r) {
                float4 xa = *(const float4*)&xs[r * DIM + k * 8];
                float4 xb = *(const float4*)&xs[r * DIM + k * 8 + 4];
                fma44(ag[r], fg, xa, xb);
                fma44(au[r], fu, xa, xb);
            }
        }
        #pragma unroll
        for (int r = 0; r < 8; ++r) {
            float g = ag[r];
            vsf[r * SINTER + j] = g / (1.f + __expf(-g)) * au[r];
        }
    }
    __syncthreads();

    const int d0 = tid, d1 = tid + 256;
    float aca[8] = {0}, acb[8] = {0};
    for (int k = 0; k < 128; ++k) {
        float fa[8], fb[8];
        ld8<BF>(wsd, (size_t)d0 * SINTER + k * 8, fa);
        ld8<BF>(wsd, (size_t)d1 * SINTER + k * 8, fb);
        #pragma unroll
        for (int r = 0; r < 8; ++r) {
            float4 v0 = *(const float4*)&vsf[r * SINTER + k * 8];
            float4 v1 = *(const float4*)&vsf[r * SINTER + k * 8 + 4];
            fma44(aca[r], fa, v0, v1);
            fma44(acb[r], fb, v0, v1);
        }
    }
    #pragma unroll
    for (int r = 0; r < 8; ++r) {
        accum[(size_t)(t0 + r) * DIM + d0] = aca[r];
        accum[(size_t)(t0 + r) * DIM + d1] = acb[r];
    }
}

__global__ __launch_bounds__(256) void k_shared(const void* xg, const void* wsg,
                                                const void* wsu, const void* wsd,
                                                const int* __restrict__ flag,
                                                float* accum, int bfonly) {
    if (bfonly && !*flag) return;
    __shared__ __align__(16) float xs[8 * DIM];
    __shared__ __align__(16) float vsf[8 * SINTER];
    if (*flag) shared_body<true >(xg, wsg, wsu, wsd, accum, xs, vsf);
    else       shared_body<false>(xg, wsg, wsu, wsd, accum, xs, vsf);
}

template<bool BF>
__device__ __forceinline__ void routed_body(const void* __restrict__ xg,
                                            const void* __restrict__ w1,
                                            const void* __restrict__ w2,
                                            const void* __restrict__ w3,
                                            const int* __restrict__ offsets,
                                            const int* __restrict__ counts,
                                            const int* __restrict__ tokl,
                                            const float* __restrict__ wgtl,
                                            float* __restrict__ accum,
                                            float* xs /*16*DIM*/, float* hsf /*16*INTER*/,
                                            int* stok, float* ssw) {
    const int e = blockIdx.x & 63;
    const int slice = blockIdx.x >> 6;
    const int tid = threadIdx.x;
    const int n = counts[e];
    const int base = offsets[e];
    const size_t wbase = (size_t)e * INTER * DIM;

    for (int tile = slice * 16; tile < n; tile += 64) {
        const int nt = min(16, n - tile);
        __syncthreads();
        if (tid < 16) {
            int ok = tid < nt;
            stok[tid] = ok ? tokl[base + tile + tid] : 0;
            ssw[tid]  = ok ? wgtl[base + tile + tid] : 0.f;
        }
        __syncthreads();
        for (int idx = tid; idx < 16 * 64; idx += 256) {
            int r = idx >> 6, c = idx & 63;
            float* xp = &xs[r * DIM + c * 8];
            if (r < nt) {
                ld8<BF>(xg, (size_t)stok[r] * DIM + c * 8, xp);
            } else {
                #pragma unroll
                for (int q = 0; q < 8; ++q) xp[q] = 0.f;
            }
        }
        __syncthreads();

        {
            float a1[16] = {0}, a3[16] = {0};
            for (int k = 0; k < 64; ++k) {
                float f1[8], f3[8];
                ld8<BF>(w1, wbase + (size_t)tid * DIM + k * 8, f1);
                ld8<BF>(w3, wbase + (size_t)tid * DIM + k * 8, f3);
                #pragma unroll
                for (int t = 0; t < 16; ++t) {
                    float4 xa = *(const float4*)&xs[t * DIM + k * 8];
                    float4 xb = *(const float4*)&xs[t * DIM + k * 8 + 4];
                    fma44(a1[t], f1, xa, xb);
                    fma44(a3[t], f3, xa, xb);
                }
            }
            #pragma unroll
            for (int t = 0; t < 16; ++t) {
                float g = a1[t];
                hsf[t * INTER + tid] = g / (1.f + __expf(-g)) * a3[t] * ssw[t];
            }
        }
        __syncthreads();

        {
            const int d0 = 2 * tid;
            float ay0[16] = {0}, ay1[16] = {0};
            for (int i = 0; i < INTER; i += 4) {
                float b0[4], b1[4];
                #pragma unroll
                for (int ii = 0; ii < 4; ++ii)
                    ld2<BF>(w2, wbase + (size_t)(i + ii) * DIM + d0, b0[ii], b1[ii]);
                #pragma unroll
                for (int t = 0; t < 16; ++t) {
                    float4 h4 = *(const float4*)&hsf[t * INTER + i];
                    ay0[t] = fmaf(h4.x, b0[0], ay0[t]); ay0[t] = fmaf(h4.y, b0[1], ay0[t]);
                    ay0[t] = fmaf(h4.z, b0[2], ay0[t]); ay0[t] = fmaf(h4.w, b0[3], ay0[t]);
                    ay1[t] = fmaf(h4.x, b1[0], ay1[t]); ay1[t] = fmaf(h4.y, b1[1], ay1[t]);
                    ay1[t] = fmaf(h4.z, b1[2], ay1[t]); ay1[t] = fmaf(h4.w, b1[3], ay1[t]);
                }
            }
            for (int t = 0; t < nt; ++t) {
                float* dst = &accum[(size_t)stok[t] * DIM + d0];
                atomicAdd(dst, ay0[t]);
                atomicAdd(dst + 1, ay1[t]);
            }
        }
    }
}

__global__ __launch_bounds__(256) void k_routed(const void* xg, const void* w1,
                                                const void* w2, const void* w3,
                                                const int* __restrict__ flag,
                                                const int* offsets, const int* counts,
                                                const int* tokl, const float* wgtl,
                                                float* accum, int bfonly) {
    if (bfonly && !*flag) return;
    __shared__ __align__(16) float xs[16 * DIM];
    __shared__ __align__(16) float hsf[16 * INTER];
    __shared__ int   stok[16];
    __shared__ float ssw[16];
    if (*flag) routed_body<true >(xg, w1, w2, w3, offsets, counts, tokl, wgtl, accum, xs, hsf, stok, ssw);
    else       routed_body<false>(xg, w1, w2, w3, offsets, counts, tokl, wgtl, accum, xs, hsf, stok, ssw);
}

// ---------------- kernel 6: fp32 accum -> output (dtype per flag) ----------------
__global__ void k_final(const float* __restrict__ accum, void* __restrict__ out,
                        const int* __restrict__ flag) {
    int i = blockIdx.x * 256 + threadIdx.x;
    float2 v = ((const float2*)accum)[i];
    if (*flag) {
        ((u32*)out)[i] = (u32)f2bf(v.x) | ((u32)f2bf(v.y) << 16);
    } else {
        ((float2*)out)[i] = v;
    }
}

extern "C" void kernel_launch(void* const* d_in, const int* in_sizes, int n_in,
                              void* d_out, int out_size, void* d_ws, size_t ws_size,
                              hipStream_t stream) {
    const void* x   = d_in[0];
    const void* wg  = d_in[1];
    const void* w1  = d_in[2];
    const void* w2  = d_in[3];
    const void* w3  = d_in[4];
    const void* wsg = d_in[5];
    const void* wsu = d_in[6];
    const void* wsd = d_in[7];

    char* ws = (char*)d_ws;
    float* accum  = (float*)ws;                              // [0, 2MiB)
    char* ctrl    = ws + ((size_t)2 << 20);
    int* counts   = (int*)ctrl;
    int* offsets  = counts + 64;
    int* cursors  = offsets + 64;
    int* topki    = cursors + 64;                            // 6144 ints
    float* topkw  = (float*)(topki + T_TOK * TOPK);          // 6144 floats
    int* tokl     = (int*)(topkw + T_TOK * TOPK);            // 6144 ints
    float* wgtl   = (float*)(tokl + T_TOK * TOPK);           // 6144 floats
    int* flag     = (int*)(wgtl + T_TOK * TOPK);
    int* tileE    = flag + 1;                                // MAXTILES ints
    int* tileT    = tileE + MAXTILES;
    int* tileC    = tileT + MAXTILES;
    int* ntiles   = tileC + MAXTILES;
    int* slot2tile = ntiles + 1;                             // MAXTILES ints
    u16* w2th = (u16*)(ws + ((size_t)3   << 20));            // 16 MiB [3,19)
    u16* w2tl = (u16*)(ws + ((size_t)19  << 20));            // 16 MiB [19,35)
    u16* vh   = (u16*)(ws + ((size_t)35  << 20));            //  2 MiB [35,37)
    u16* vl   = (u16*)(ws + ((size_t)37  << 20));            //  2 MiB [37,39)
    u16* w1h  = (u16*)(ws + ((size_t)40  << 20));            // 16 MiB [40,56)
    u16* w1l  = (u16*)(ws + ((size_t)56  << 20));            // 16 MiB [56,72)
    u16* w3h  = (u16*)(ws + ((size_t)72  << 20));            // 16 MiB [72,88)
    u16* w3l  = (u16*)(ws + ((size_t)88  << 20));            // 16 MiB [88,104)
    u16* wsgh = (u16*)(ws + ((size_t)104 << 20));            // 1 MiB each...
    u16* wsgl = (u16*)(ws + ((size_t)105 << 20));
    u16* wsuh = (u16*)(ws + ((size_t)106 << 20));
    u16* wsul = (u16*)(ws + ((size_t)107 << 20));
    u16* wsdh = (u16*)(ws + ((size_t)108 << 20));
    u16* wsdl = (u16*)(ws + ((size_t)109 << 20));
    u16* xh   = (u16*)(ws + ((size_t)110 << 20));
    u16* xl   = (u16*)(ws + ((size_t)111 << 20));
    u16* hh   = (u16*)(ws + ((size_t)112 << 20));            // 4 MiB [112,116)
    u16* hl   = (u16*)(ws + ((size_t)116 << 20));            // 4 MiB [116,120)
    const bool fast3 = ws_size >= ((size_t)120 << 20);

    k_probe_init<<<1, 64, 0, stream>>>((const u32*)x, flag, counts);
    k_prep  <<<10752, 256, 0, stream>>>((const float*)x, x, wg,
                                        (const float*)w1, (const float*)w3,
                                        (const float*)wsg, (const float*)wsu,
                                        (const float*)wsd, (const float*)w2,
                                        w1h, w1l, w3h, w3l, wsgh, wsgl, wsuh, wsul,
                                        wsdh, wsdl, xh, xl, w2th, w2tl,
                                        counts, topki, topkw, accum, flag, fast3 ? 1 : 0);
    k_prefix<<<1, 64, 0, stream>>>(counts, offsets, cursors, tileE, tileT, tileC,
                                   ntiles, slot2tile);
    k_scatter<<<4, 256, 0, stream>>>(topki, topkw, cursors, tokl, wgtl);

    if (fast3) {
        k_up <<<1536, 256, 0, stream>>>(xh, xl, w1h, w1l, w3h, w3l,
                                        wsgh, wsgl, wsuh, wsul, flag,
                                        offsets, tokl, wgtl,
                                        tileE, tileT, tileC, slot2tile,
                                        hh, hl, vh, vl);
        k_dn <<<1536, 256, 0, stream>>>(hh, hl, w2th, w2tl, vh, vl, wsdh, wsdl,
                                        flag, offsets, tokl,
                                        tileE, tileT, tileC, slot2tile, accum);
        // bf16-input fallback (no-ops when flag==0)
        k_shared <<<128, 256, 0, stream>>>(x, wsg, wsu, wsd, flag, accum, 1);
        k_routed <<<256, 256, 0, stream>>>(x, w1, w2, w3, flag, offsets, counts, tokl, wgtl, accum, 1);
    } else {
        // small workspace: legacy VALU path for both dtypes
        k_shared <<<128, 256, 0, stream>>>(x, wsg, wsu, wsd, flag, accum, 0);
        k_routed <<<256, 256, 0, stream>>>(x, w1, w2, w3, flag, offsets, counts, tokl, wgtl, accum, 0);
    }
    k_final  <<<1024, 256, 0, stream>>>(accum, d_out, flag);
}

// Round 11
// 382.562 us; speedup vs baseline: 1.3356x; 1.0317x over previous
//
#include <hip/hip_runtime.h>
#include <math.h>

// Problem constants
#define T_TOK 1024
#define DIM 512
#define INTER 256
#define SINTER 1024
#define NEXP 64
#define TOPK 6
#define MAXTILES 512

typedef unsigned short u16;
typedef unsigned int u32;
typedef short bf16x8 __attribute__((ext_vector_type(8)));   // 8 bf16 (4 VGPRs)
typedef float f32x4  __attribute__((ext_vector_type(4)));   // MFMA 16x16 accumulator

__device__ __forceinline__ float bflo(u32 u) { return __uint_as_float(u << 16); }
__device__ __forceinline__ float bfhi(u32 u) { return __uint_as_float(u & 0xffff0000u); }

__device__ __forceinline__ u16 f2bf(float f) {
    u32 u = __float_as_uint(f);
    return (u16)((u + 0x7fffu + ((u >> 16) & 1u)) >> 16);  // RNE
}

__device__ __forceinline__ f32x4 mfma16(bf16x8 a, bf16x8 b, f32x4 c) {
    return __builtin_amdgcn_mfma_f32_16x16x32_bf16(a, b, c, 0, 0, 0);
}

// split fp32 -> (hi bf16, lo bf16): v ~= vh + vl, combined err ~2^-16|v|
__device__ __forceinline__ void split1(float v, u16& h, u16& l) {
    u32 u = __float_as_uint(v);
    u32 hb = u & 0xffff0000u;
    float r = v - __uint_as_float(hb);
    h = (u16)(hb >> 16);
    l = (u16)(__float_as_uint(r) >> 16);
}

// split 8 consecutive fp32 (32B-aligned) into hi/lo bf16x8 packed as uint4
__device__ __forceinline__ void split8u(const float* __restrict__ s, uint4& H, uint4& L) {
    const uint4* q = (const uint4*)s;
    uint4 A = q[0], B = q[1];
    u32 wv[8] = {A.x, A.y, A.z, A.w, B.x, B.y, B.z, B.w};
    u32 hp[4], lp[4];
    #pragma unroll
    for (int i = 0; i < 4; ++i) {
        u32 u0 = wv[2*i], u1 = wv[2*i+1];
        u32 h0 = u0 & 0xffff0000u, h1 = u1 & 0xffff0000u;
        float r0 = __uint_as_float(u0) - __uint_as_float(h0);
        float r1 = __uint_as_float(u1) - __uint_as_float(h1);
        hp[i] = (h0 >> 16) | h1;
        lp[i] = (__float_as_uint(r0) >> 16) | (__float_as_uint(r1) & 0xffff0000u);
    }
    H.x = hp[0]; H.y = hp[1]; H.z = hp[2]; H.w = hp[3];
    L.x = lp[0]; L.y = lp[1]; L.z = lp[2]; L.w = lp[3];
}

// load 8 consecutive elements (idx must be a multiple of 8) as floats
template<bool BF>
__device__ __forceinline__ void ld8(const void* p, size_t idx, float* f) {
    if (BF) {
        uint4 u = *(const uint4*)((const u16*)p + idx);
        f[0] = bflo(u.x); f[1] = bfhi(u.x);
        f[2] = bflo(u.y); f[3] = bfhi(u.y);
        f[4] = bflo(u.z); f[5] = bfhi(u.z);
        f[6] = bflo(u.w); f[7] = bfhi(u.w);
    } else {
        const float4* q = (const float4*)((const float*)p + idx);
        float4 a = q[0], b = q[1];
        f[0] = a.x; f[1] = a.y; f[2] = a.z; f[3] = a.w;
        f[4] = b.x; f[5] = b.y; f[6] = b.z; f[7] = b.w;
    }
}

// load 2 consecutive elements (idx even)
template<bool BF>
__device__ __forceinline__ void ld2(const void* p, size_t idx, float& a, float& b) {
    if (BF) { u32 w = *(const u32*)((const u16*)p + idx); a = bflo(w); b = bfhi(w); }
    else    { float2 v = *(const float2*)((const float*)p + idx); a = v.x; b = v.y; }
}

__device__ __forceinline__ void fma44(float& acc, const float* f, const float4& a, const float4& b) {
    acc = fmaf(f[0], a.x, acc); acc = fmaf(f[1], a.y, acc);
    acc = fmaf(f[2], a.z, acc); acc = fmaf(f[3], a.w, acc);
    acc = fmaf(f[4], b.x, acc); acc = fmaf(f[5], b.y, acc);
    acc = fmaf(f[6], b.z, acc); acc = fmaf(f[7], b.w, acc);
}

// ---------------- kernel PI: dtype probe + zero counters ----------------
__global__ void k_probe_init(const u32* __restrict__ xw, int* __restrict__ flag,
                             int* __restrict__ counts) {
    counts[threadIdx.x] = 0;
    int cnt = 0;
    #pragma unroll
    for (int i = 0; i < 8; ++i) {
        u32 u = xw[threadIdx.x * 8 + i];
        u32 e = (u >> 7) & 0xffu;           // exponent of low-half-as-bf16
        cnt += (e >= 110 && e <= 140) ? 1 : 0;
    }
    #pragma unroll
    for (int off = 32; off; off >>= 1) cnt += __shfl_xor(cnt, off);
    if (threadIdx.x == 0) flag[0] = (cnt > 256) ? 1 : 0;
}

// ---------------- router body (one token per wave) ----------------
template<bool BF>
__device__ __forceinline__ void router_body(const void* __restrict__ xg,
                                            const void* __restrict__ wg,
                                            int* __restrict__ counts,
                                            int* __restrict__ topki,
                                            float* __restrict__ topkw,
                                            float* xsrow, int t, int lane) {
    ld8<BF>(xg, (size_t)t * DIM + lane * 8, &xsrow[lane * 8]);
    __syncthreads();

    float acc = 0.f;
    for (int k = 0; k < 64; ++k) {
        float f[8]; ld8<BF>(wg, (size_t)lane * DIM + k * 8, f);
        float4 xa = *(const float4*)&xsrow[k * 8];
        float4 xb = *(const float4*)&xsrow[k * 8 + 4];
        fma44(acc, f, xa, xb);
    }

    float my = acc;
    float sv[TOPK]; int si[TOPK];
    #pragma unroll
    for (int s = 0; s < TOPK; ++s) {
        float v = my; int id = lane;
        #pragma unroll
        for (int off = 32; off; off >>= 1) {
            float ov = __shfl_xor(v, off);
            int   oi = __shfl_xor(id, off);
            if (ov > v || (ov == v && oi < id)) { v = ov; id = oi; }
        }
        sv[s] = v; si[s] = id;
        if (lane == id) my = -INFINITY;
    }
    if (lane == 0) {
        float m = sv[0], sum = 0.f, w[TOPK];
        #pragma unroll
        for (int s = 0; s < TOPK; ++s) { w[s] = __expf(sv[s] - m); sum += w[s]; }
        float inv = 1.f / sum;
        #pragma unroll
        for (int s = 0; s < TOPK; ++s) {
            int e = si[s];
            topki[t * TOPK + s] = e;
            topkw[t * TOPK + s] = w[s] * inv;
            atomicAdd(&counts[e], 1);
        }
    }
}

// ---- kernel PREP: router [0,256) | bsplit [256,9472) | w2ts [9472,10496) | zero accum [10496,10752) ----
__global__ __launch_bounds__(256) void k_prep(
        const float* __restrict__ xf, const void* __restrict__ xg,
        const void* __restrict__ wgate,
        const float* __restrict__ w1, const float* __restrict__ w3,
        const float* __restrict__ wsg, const float* __restrict__ wsu,
        const float* __restrict__ wsd, const float* __restrict__ w2,
        u16* w1h, u16* w1l, u16* w3h, u16* w3l,
        u16* wsgh, u16* wsgl, u16* wsuh, u16* wsul,
        u16* wsdh, u16* wsdl, u16* xh, u16* xl,
        u16* w2th, u16* w2tl,
        int* counts, int* topki, float* topkw,
        float* __restrict__ accum,
        const int* __restrict__ flag, int dosplit) {
    __shared__ __align__(16) char smem[33280];   // max(router 8KB, w2ts 33.25KB)
    const int b = blockIdx.x;
    const int tid = threadIdx.x;

    if (b < 256) {
        // ---- router: 4 tokens per block (1 per wave) ----
        float* xs = (float*)smem;
        const int wv = tid >> 6, lane = tid & 63;
        const int t = b * 4 + wv;
        if (*flag) router_body<true >(xg, wgate, counts, topki, topkw, xs + wv * DIM, t, lane);
        else       router_body<false>(xg, wgate, counts, topki, topkw, xs + wv * DIM, t, lane);
        return;
    }
    if (b >= 10496) {
        // ---- zero accum (needed: k_dn's shB/rB both accumulate atomically) ----
        const uint4 z = {0u, 0u, 0u, 0u};
        ((uint4*)accum)[(size_t)(b - 10496) * 256 + tid] = z;
        return;
    }
    if (*flag || !dosplit) return;

    if (b < 256 + 9216) {
        // ---- bulk split fp32 -> hi/lo planes ----
        const int bb = b - 256;
        const float* src; u16* dh; u16* dl; size_t base;
        if (bb < 4096)      { src = w1;  dh = w1h;  dl = w1l;  base = (size_t)bb * 2048; }
        else if (bb < 8192) { src = w3;  dh = w3h;  dl = w3l;  base = (size_t)(bb - 4096) * 2048; }
        else if (bb < 8448) { src = wsg; dh = wsgh; dl = wsgl; base = (size_t)(bb - 8192) * 2048; }
        else if (bb < 8704) { src = wsu; dh = wsuh; dl = wsul; base = (size_t)(bb - 8448) * 2048; }
        else if (bb < 8960) { src = wsd; dh = wsdh; dl = wsdl; base = (size_t)(bb - 8704) * 2048; }
        else                { src = xf;  dh = xh;   dl = xl;   base = (size_t)(bb - 8960) * 2048; }
        size_t idx = base + (size_t)tid * 8;
        uint4 H, L;
        split8u(src + idx, H, L);
        *(uint4*)(dh + idx) = H;
        *(uint4*)(dl + idx) = L;
        return;
    }

    // ---- w2 transpose+split [e][i][d] -> hi/lo [e][d][i] ----
    {
        const int bb = b - 9472;
        u32 (*lt)[65] = (u32(*)[65])smem;        // 128 x 65 packed hi<<16|lo
        const int e  = bb >> 4;
        const int ic = (bb >> 3) & 1;            // i-chunk of 128
        const int dc = bb & 7;                   // d-chunk of 64
        const float* src = w2 + (size_t)e * INTER * DIM + (size_t)(ic * 128) * DIM + dc * 64;
        #pragma unroll
        for (int p = 0; p < 8; ++p) {
            int f = p * 256 + tid;
            int i = f >> 4, dq = f & 15;
            float4 v = *(const float4*)(src + (size_t)i * DIM + dq * 4);
            float vv[4] = {v.x, v.y, v.z, v.w};
            #pragma unroll
            for (int j = 0; j < 4; ++j) {
                u32 u = __float_as_uint(vv[j]);
                u32 hb = u & 0xffff0000u;
                float r = vv[j] - __uint_as_float(hb);
                lt[i][dq * 4 + j] = hb | (__float_as_uint(r) >> 16);
            }
        }
        __syncthreads();
        const int dl = tid & 63, q = tid >> 6;
        size_t rb = ((size_t)e * DIM + dc * 64 + dl) * INTER + ic * 128 + q * 32;
        #pragma unroll
        for (int s = 0; s < 4; ++s) {
            u32 h2[4], l2[4];
            #pragma unroll
            for (int m = 0; m < 4; ++m) {
                u32 p0 = lt[q * 32 + s * 8 + m * 2][dl];
                u32 p1 = lt[q * 32 + s * 8 + m * 2 + 1][dl];
                h2[m] = (p0 >> 16) | (p1 & 0xffff0000u);
                l2[m] = (p0 & 0xffffu) | (p1 << 16);
            }
            uint4 Hv = {h2[0], h2[1], h2[2], h2[3]};
            uint4 Lv = {l2[0], l2[1], l2[2], l2[3]};
            *(uint4*)(w2th + rb + s * 8) = Hv;
            *(uint4*)(w2tl + rb + s * 8) = Lv;
        }
    }
}

// ---------------- kernel 2: prefix sum + XCD-binned tile slots (parallel, r8-proven) ----------------
__global__ __launch_bounds__(64) void k_prefix(const int* __restrict__ counts,
                         int* __restrict__ offsets, int* __restrict__ cursors,
                         int* __restrict__ tileE, int* __restrict__ tileT,
                         int* __restrict__ tileC, int* __restrict__ ntiles,
                         int* __restrict__ slot2tile) {
    __shared__ int sc[NEXP], snt[NEXP], sbin[8];
    __shared__ int sflag;
    const int e = threadIdx.x;
    const int b = e & 7;
    int c = counts[e];
    sc[e] = c;
    snt[e] = (c + 15) >> 4;
    __syncthreads();

    int off = 0, tb = 0;
    for (int i = 0; i < e; ++i) { off += sc[i]; tb += snt[i]; }
    int bp = 0;
    for (int i = b; i < e; i += 8) bp += snt[i];
    offsets[e] = off;
    cursors[e] = off;

    if (e < 8) {
        int tot = 0;
        for (int i = e; i < NEXP; i += 8) tot += snt[i];
        sbin[e] = tot;
    }
    if (e == 0) {
        int nt = 0;
        for (int i = 0; i < NEXP; ++i) nt += snt[i];
        *ntiles = nt;
    }
    #pragma unroll
    for (int i = 0; i < MAXTILES / NEXP; ++i) slot2tile[e + i * NEXP] = -1;
    __syncthreads();

    if (e == 0) {
        int f = 0;
        for (int i = 0; i < 8; ++i) if (sbin[i] > MAXTILES / 8) f = 1;
        sflag = f;
    }
    __syncthreads();

    const int swz = (sflag == 0);
    const int nt_e = snt[e];
    for (int t = 0; t < nt_e; ++t) {
        int idx = tb + t;
        tileE[idx] = e;
        tileT[idx] = t * 16;
        tileC[idx] = min(16, c - t * 16);
        int s = swz ? ((bp + t) * 8 + b) : idx;
        slot2tile[s] = idx;
    }
}

// ---------------- kernel 3: scatter tokens into expert buckets ----------------
__global__ void k_scatter(const int* __restrict__ topki, const float* __restrict__ topkw,
                          int* __restrict__ cursors, int* __restrict__ tokl,
                          float* __restrict__ wgtl) {
    int t = blockIdx.x * 256 + threadIdx.x;
    #pragma unroll
    for (int s = 0; s < TOPK; ++s) {
        int e = topki[t * TOPK + s];
        float w = topkw[t * TOPK + s];
        int pos = atomicAdd(&cursors[e], 1);
        tokl[pos] = t;
        wgtl[pos] = w;
    }
}

// ---------------- up-projection bodies ----------------
__device__ __forceinline__ void rA_body(
        const u16* __restrict__ xh, const u16* __restrict__ xl,
        const u16* __restrict__ w1h, const u16* __restrict__ w1l,
        const u16* __restrict__ w3h, const u16* __restrict__ w3l,
        const int* __restrict__ offsets, const int* __restrict__ tokl,
        const float* __restrict__ wgtl, const int* __restrict__ tileE,
        const int* __restrict__ tileT, const int* __restrict__ tileC,
        u16* __restrict__ hh, u16* __restrict__ hl,
        int tileIdx, int ih, u16* xsh, u16* xsl, int* stok, float* ssw) {
    const int tid = threadIdx.x;
    const int lane = tid & 63, w = tid >> 6;
    const int lr = lane & 15, lg = lane >> 4;
    const int e = tileE[tileIdx];
    const int cnt = tileC[tileIdx];
    const int sbase = offsets[e] + tileT[tileIdx];
    const size_t wbase = (size_t)e * INTER * DIM;

    if (tid < 16) {
        int ok = tid < cnt;
        stok[tid] = ok ? tokl[sbase + tid] : tokl[sbase];   // pad: valid token, ssw=0
        ssw[tid]  = ok ? wgtl[sbase + tid] : 0.f;
    }
    __syncthreads();
    for (int idx = tid; idx < 16 * 64; idx += 256) {
        int r = idx >> 6, c = idx & 63;
        int off = r * 1024 + ((c * 16) ^ ((r & 7) << 4));
        size_t g = (size_t)stok[r] * DIM + c * 8;
        *(uint4*)((char*)xsh + off) = *(const uint4*)(xh + g);
        *(uint4*)((char*)xsl + off) = *(const uint4*)(xl + g);
    }
    __syncthreads();

    const f32x4 z4 = {0.f, 0.f, 0.f, 0.f};
    f32x4 a1[2] = {z4, z4};
    f32x4 a3[2] = {z4, z4};
    const int j0 = ih * 128 + w * 32;
    #pragma unroll 4
    for (int ks = 0; ks < 16; ++ks) {
        const int k0 = ks * 32 + lg * 8;
        const int xoff = lr * 1024 + ((k0 * 2) ^ ((lr & 7) << 4));
        bf16x8 ah = *(const bf16x8*)((const char*)xsh + xoff);
        bf16x8 al = *(const bf16x8*)((const char*)xsl + xoff);
        #pragma unroll
        for (int q = 0; q < 2; ++q) {
            const size_t row = wbase + (size_t)(j0 + q * 16 + lr) * DIM + k0;
            bf16x8 bh = *(const bf16x8*)(w1h + row);
            bf16x8 bl = *(const bf16x8*)(w1l + row);
            a1[q] = mfma16(ah, bh, a1[q]);
            a1[q] = mfma16(ah, bl, a1[q]);
            a1[q] = mfma16(al, bh, a1[q]);
            bh = *(const bf16x8*)(w3h + row);
            bl = *(const bf16x8*)(w3l + row);
            a3[q] = mfma16(ah, bh, a3[q]);
            a3[q] = mfma16(ah, bl, a3[q]);
            a3[q] = mfma16(al, bh, a3[q]);
        }
    }
    #pragma unroll
    for (int q = 0; q < 2; ++q) {
        #pragma unroll
        for (int r = 0; r < 4; ++r) {
            const int t = lg * 4 + r;
            float g = a1[q][r];
            float h = g / (1.f + __expf(-g)) * a3[q][r] * ssw[t];
            u16 hh16, hl16; split1(h, hh16, hl16);
            size_t o = (size_t)(tileIdx * 16 + t) * INTER + j0 + q * 16 + lr;
            hh[o] = hh16;
            hl[o] = hl16;
        }
    }
}

__device__ __forceinline__ void shA_body(
        const u16* __restrict__ xh, const u16* __restrict__ xl,
        const u16* __restrict__ wsgh, const u16* __restrict__ wsgl,
        const u16* __restrict__ wsuh, const u16* __restrict__ wsul,
        u16* __restrict__ vh, u16* __restrict__ vl,
        int tt, int sc, u16* xsh, u16* xsl) {
    const int tid = threadIdx.x;
    const int w = tid >> 6, lane = tid & 63;
    const int lr = lane & 15, lg = lane >> 4;

    for (int idx = tid; idx < 16 * 64; idx += 256) {
        int r = idx >> 6, c = idx & 63;
        int off = r * 1024 + ((c * 16) ^ ((r & 7) << 4));
        size_t g = (size_t)(tt * 16 + r) * DIM + c * 8;
        *(uint4*)((char*)xsh + off) = *(const uint4*)(xh + g);
        *(uint4*)((char*)xsl + off) = *(const uint4*)(xl + g);
    }
    __syncthreads();

    const f32x4 z4 = {0.f, 0.f, 0.f, 0.f};
    f32x4 ag[2] = {z4, z4};
    f32x4 au[2] = {z4, z4};
    const int j0 = sc * 128 + w * 32;
    #pragma unroll 4
    for (int ks = 0; ks < 16; ++ks) {
        const int k0 = ks * 32 + lg * 8;
        const int xoff = lr * 1024 + ((k0 * 2) ^ ((lr & 7) << 4));
        bf16x8 ah = *(const bf16x8*)((const char*)xsh + xoff);
        bf16x8 al = *(const bf16x8*)((const char*)xsl + xoff);
        #pragma unroll
        for (int q = 0; q < 2; ++q) {
            const size_t row = (size_t)(j0 + q * 16 + lr) * DIM + k0;
            bf16x8 bh = *(const bf16x8*)(wsgh + row);
            bf16x8 bl = *(const bf16x8*)(wsgl + row);
            ag[q] = mfma16(ah, bh, ag[q]);
            ag[q] = mfma16(ah, bl, ag[q]);
            ag[q] = mfma16(al, bh, ag[q]);
            bh = *(const bf16x8*)(wsuh + row);
            bl = *(const bf16x8*)(wsul + row);
            au[q] = mfma16(ah, bh, au[q]);
            au[q] = mfma16(ah, bl, au[q]);
            au[q] = mfma16(al, bh, au[q]);
        }
    }
    #pragma unroll
    for (int q = 0; q < 2; ++q) {
        #pragma unroll
        for (int r = 0; r < 4; ++r) {
            const int t = lg * 4 + r;
            float g = ag[q][r];
            float v = g / (1.f + __expf(-g)) * au[q][r];
            u16 h16, l16; split1(v, h16, l16);
            size_t o = (size_t)(tt * 16 + t) * SINTER + j0 + q * 16 + lr;
            vh[o] = h16;
            vl[o] = l16;
        }
    }
}

// ---------------- kernel UP: rA [0,1024) | shA [1024,1536) ----------------
// rA: slot = b%512 (keeps expert->XCD bin in low 3 bits), ih = b/512.
// launch_bounds(256,4): LDS caps residency at 4 blocks/CU anyway; raising the
// allocator's VGPR budget to 128 lets the scheduler keep ~2x loads in flight (r10 fix).
__global__ __launch_bounds__(256, 4) void k_up(
        const u16* __restrict__ xh, const u16* __restrict__ xl,
        const u16* __restrict__ w1h, const u16* __restrict__ w1l,
        const u16* __restrict__ w3h, const u16* __restrict__ w3l,
        const u16* __restrict__ wsgh, const u16* __restrict__ wsgl,
        const u16* __restrict__ wsuh, const u16* __restrict__ wsul,
        const int* __restrict__ flag, const int* __restrict__ offsets,
        const int* __restrict__ tokl, const float* __restrict__ wgtl,
        const int* __restrict__ tileE, const int* __restrict__ tileT,
        const int* __restrict__ tileC, const int* __restrict__ slot2tile,
        u16* __restrict__ hh, u16* __restrict__ hl,
        u16* __restrict__ vh, u16* __restrict__ vl) {
    if (*flag) return;
    __shared__ __align__(16) char smem[33024];   // xsh 16K | xsl 16K | stok 64 | ssw 64
    u16* xsh = (u16*)smem;
    u16* xsl = (u16*)(smem + 16384);
    const int b = blockIdx.x;
    if (b < 1024) {
        const int tileIdx = slot2tile[b & 511];
        if (tileIdx < 0) return;
        int* stok = (int*)(smem + 32768);
        float* ssw = (float*)(smem + 32832);
        rA_body(xh, xl, w1h, w1l, w3h, w3l, offsets, tokl, wgtl,
                tileE, tileT, tileC, hh, hl, tileIdx, b >> 9, xsh, xsl, stok, ssw);
    } else {
        const int bb = b - 1024;
        shA_body(xh, xl, wsgh, wsgl, wsuh, wsul, vh, vl, bb >> 3, bb & 7, xsh, xsl);
    }
}

// ---------------- down-projection bodies (no LDS; BOTH accumulate atomically into zeroed accum) ----------------
__device__ __forceinline__ void rB_body(
        const u16* __restrict__ hh, const u16* __restrict__ hl,
        const u16* __restrict__ w2th, const u16* __restrict__ w2tl,
        const int* __restrict__ offsets, const int* __restrict__ tokl,
        const int* __restrict__ tileE, const int* __restrict__ tileT,
        const int* __restrict__ tileC, float* __restrict__ accum,
        int tileIdx, int dh) {
    const int tid = threadIdx.x;
    const int lane = tid & 63, w = tid >> 6;
    const int lr = lane & 15, lg = lane >> 4;
    const int e = tileE[tileIdx];
    const int cnt = tileC[tileIdx];
    const int sbase = offsets[e] + tileT[tileIdx];
    const size_t w2base = (size_t)e * DIM * INTER;
    const int d0 = dh * 256 + w * 64;

    const u16* hrh = hh + (size_t)(tileIdx * 16 + lr) * INTER;
    const u16* hrl = hl + (size_t)(tileIdx * 16 + lr) * INTER;
    const f32x4 z4 = {0.f, 0.f, 0.f, 0.f};
    f32x4 ay[4] = {z4, z4, z4, z4};
    #pragma unroll 4
    for (int ks = 0; ks < 8; ++ks) {
        const int k0 = ks * 32 + lg * 8;
        bf16x8 ah = *(const bf16x8*)(hrh + k0);
        bf16x8 al = *(const bf16x8*)(hrl + k0);
        #pragma unroll
        for (int q = 0; q < 4; ++q) {
            const size_t row = w2base + (size_t)(d0 + q * 16 + lr) * INTER + k0;
            bf16x8 bh = *(const bf16x8*)(w2th + row);
            bf16x8 bl = *(const bf16x8*)(w2tl + row);
            ay[q] = mfma16(ah, bh, ay[q]);
            ay[q] = mfma16(ah, bl, ay[q]);
            ay[q] = mfma16(al, bh, ay[q]);
        }
    }
    #pragma unroll
    for (int q = 0; q < 4; ++q) {
        #pragma unroll
        for (int r = 0; r < 4; ++r) {
            const int t = lg * 4 + r;
            if (t < cnt)
                atomicAdd(&accum[(size_t)tokl[sbase + t] * DIM + d0 + q * 16 + lr],
                          ay[q][r]);
        }
    }
}

__device__ __forceinline__ void shB_body(
        const u16* __restrict__ vh, const u16* __restrict__ vl,
        const u16* __restrict__ wsdh, const u16* __restrict__ wsdl,
        float* __restrict__ accum, int tt, int dc) {
    const int w = threadIdx.x >> 6, lane = threadIdx.x & 63;
    const int lr = lane & 15, lg = lane >> 4;
    const int d0 = dc * 64 + w * 16;
    const u16* vhrow = vh + (size_t)(tt * 16 + lr) * SINTER;
    const u16* vlrow = vl + (size_t)(tt * 16 + lr) * SINTER;
    const u16* whrow = wsdh + (size_t)(d0 + lr) * SINTER;
    const u16* wlrow = wsdl + (size_t)(d0 + lr) * SINTER;
    f32x4 acc = {0.f, 0.f, 0.f, 0.f};
    #pragma unroll 8
    for (int ks = 0; ks < 32; ++ks) {
        const int k0 = ks * 32 + lg * 8;
        bf16x8 avh = *(const bf16x8*)(vhrow + k0);
        bf16x8 avl = *(const bf16x8*)(vlrow + k0);
        bf16x8 bh  = *(const bf16x8*)(whrow + k0);
        bf16x8 bl  = *(const bf16x8*)(wlrow + k0);
        acc = mfma16(avh, bh, acc);
        acc = mfma16(avh, bl, acc);
        acc = mfma16(avl, bh, acc);
    }
    // atomicAdd (not store): rB blocks run concurrently in the same kernel (r9 race fix)
    #pragma unroll
    for (int r = 0; r < 4; ++r)
        atomicAdd(&accum[(size_t)(tt * 16 + lg * 4 + r) * DIM + d0 + lr], acc[r]);
}

// ---------------- kernel DN: rB [0,1024) | shB [1024,1536) ----------------
__global__ __launch_bounds__(256, 4) void k_dn(
        const u16* __restrict__ hh, const u16* __restrict__ hl,
        const u16* __restrict__ w2th, const u16* __restrict__ w2tl,
        const u16* __restrict__ vh, const u16* __restrict__ vl,
        const u16* __restrict__ wsdh, const u16* __restrict__ wsdl,
        const int* __restrict__ flag, const int* __restrict__ offsets,
        const int* __restrict__ tokl,
        const int* __restrict__ tileE, const int* __restrict__ tileT,
        const int* __restrict__ tileC, const int* __restrict__ slot2tile,
        float* __restrict__ accum) {
    if (*flag) return;
    const int b = blockIdx.x;
    if (b < 1024) {
        const int tileIdx = slot2tile[b & 511];
        if (tileIdx < 0) return;
        rB_body(hh, hl, w2th, w2tl, offsets, tokl, tileE, tileT, tileC,
                accum, tileIdx, b >> 9);
    } else {
        const int bb = b - 1024;
        shB_body(vh, vl, wsdh, wsdl, accum, bb >> 3, bb & 7);
    }
}

// ============== legacy VALU kernels (bf16 inputs, or tiny-workspace fallback) ==============

template<bool BF>
__device__ __forceinline__ void shared_body(const void* __restrict__ xg,
                                            const void* __restrict__ wsg,
                                            const void* __restrict__ wsu,
                                            const void* __restrict__ wsd,
                                            float* __restrict__ accum,
                                            float* xs /*8*DIM*/, float* vsf /*8*SINTER*/) {
    const int t0 = blockIdx.x * 8;
    const int tid = threadIdx.x;

    for (int idx = tid; idx < 8 * 64; idx += 256) {
        int r = idx >> 6, c = idx & 63;
        ld8<BF>(xg, (size_t)(t0 + r) * DIM + c * 8, &xs[r * DIM + c * 8]);
    }
    __syncthreads();

    for (int jc = 0; jc < 4; ++jc) {
        int j = jc * 256 + tid;
        float ag[8] = {0}, au[8] = {0};
        for (int k = 0; k < 64; ++k) {
            float fg[8], fu[8];
            ld8<BF>(wsg, (size_t)j * DIM + k * 8, fg);
            ld8<BF>(wsu, (size_t)j * DIM + k * 8, fu);
            #pragma unroll
            for (int r = 0; r < 8; ++r) {
                float4 xa = *(const float4*)&xs[r * DIM + k * 8];
                float4 xb = *(const float4*)&xs[r * DIM + k * 8 + 4];
                fma44(ag[r], fg, xa, xb);
                fma44(au[r], fu, xa, xb);
            }
        }
        #pragma unroll
        for (int r = 0; r < 8; ++r) {
            float g = ag[r];
            vsf[r * SINTER + j] = g / (1.f + __expf(-g)) * au[r];
        }
    }
    __syncthreads();

    const int d0 = tid, d1 = tid + 256;
    float aca[8] = {0}, acb[8] = {0};
    for (int k = 0; k < 128; ++k) {
        float fa[8], fb[8];
        ld8<BF>(wsd, (size_t)d0 * SINTER + k * 8, fa);
        ld8<BF>(wsd, (size_t)d1 * SINTER + k * 8, fb);
        #pragma unroll
        for (int r = 0; r < 8; ++r) {
            float4 v0 = *(const float4*)&vsf[r * SINTER + k * 8];
            float4 v1 = *(const float4*)&vsf[r * SINTER + k * 8 + 4];
            fma44(aca[r], fa, v0, v1);
            fma44(acb[r], fb, v0, v1);
        }
    }
    #pragma unroll
    for (int r = 0; r < 8; ++r) {
        accum[(size_t)(t0 + r) * DIM + d0] = aca[r];
        accum[(size_t)(t0 + r) * DIM + d1] = acb[r];
    }
}

__global__ __launch_bounds__(256) void k_shared(const void* xg, const void* wsg,
                                                const void* wsu, const void* wsd,
                                                const int* __restrict__ flag,
                                                float* accum, int bfonly) {
    if (bfonly && !*flag) return;
    __shared__ __align__(16) float xs[8 * DIM];
    __shared__ __align__(16) float vsf[8 * SINTER];
    if (*flag) shared_body<true >(xg, wsg, wsu, wsd, accum, xs, vsf);
    else       shared_body<false>(xg, wsg, wsu, wsd, accum, xs, vsf);
}

template<bool BF>
__device__ __forceinline__ void routed_body(const void* __restrict__ xg,
                                            const void* __restrict__ w1,
                                            const void* __restrict__ w2,
                                            const void* __restrict__ w3,
                                            const int* __restrict__ offsets,
                                            const int* __restrict__ counts,
                                            const int* __restrict__ tokl,
                                            const float* __restrict__ wgtl,
                                            float* __restrict__ accum,
                                            float* xs /*16*DIM*/, float* hsf /*16*INTER*/,
                                            int* stok, float* ssw) {
    const int e = blockIdx.x & 63;
    const int slice = blockIdx.x >> 6;
    const int tid = threadIdx.x;
    const int n = counts[e];
    const int base = offsets[e];
    const size_t wbase = (size_t)e * INTER * DIM;

    for (int tile = slice * 16; tile < n; tile += 64) {
        const int nt = min(16, n - tile);
        __syncthreads();
        if (tid < 16) {
            int ok = tid < nt;
            stok[tid] = ok ? tokl[base + tile + tid] : 0;
            ssw[tid]  = ok ? wgtl[base + tile + tid] : 0.f;
        }
        __syncthreads();
        for (int idx = tid; idx < 16 * 64; idx += 256) {
            int r = idx >> 6, c = idx & 63;
            float* xp = &xs[r * DIM + c * 8];
            if (r < nt) {
                ld8<BF>(xg, (size_t)stok[r] * DIM + c * 8, xp);
            } else {
                #pragma unroll
                for (int q = 0; q < 8; ++q) xp[q] = 0.f;
            }
        }
        __syncthreads();

        {
            float a1[16] = {0}, a3[16] = {0};
            for (int k = 0; k < 64; ++k) {
                float f1[8], f3[8];
                ld8<BF>(w1, wbase + (size_t)tid * DIM + k * 8, f1);
                ld8<BF>(w3, wbase + (size_t)tid * DIM + k * 8, f3);
                #pragma unroll
                for (int t = 0; t < 16; ++t) {
                    float4 xa = *(const float4*)&xs[t * DIM + k * 8];
                    float4 xb = *(const float4*)&xs[t * DIM + k * 8 + 4];
                    fma44(a1[t], f1, xa, xb);
                    fma44(a3[t], f3, xa, xb);
                }
            }
            #pragma unroll
            for (int t = 0; t < 16; ++t) {
                float g = a1[t];
                hsf[t * INTER + tid] = g / (1.f + __expf(-g)) * a3[t] * ssw[t];
            }
        }
        __syncthreads();

        {
            const int d0 = 2 * tid;
            float ay0[16] = {0}, ay1[16] = {0};
            for (int i = 0; i < INTER; i += 4) {
                float b0[4], b1[4];
                #pragma unroll
                for (int ii = 0; ii < 4; ++ii)
                    ld2<BF>(w2, wbase + (size_t)(i + ii) * DIM + d0, b0[ii], b1[ii]);
                #pragma unroll
                for (int t = 0; t < 16; ++t) {
                    float4 h4 = *(const float4*)&hsf[t * INTER + i];
                    ay0[t] = fmaf(h4.x, b0[0], ay0[t]); ay0[t] = fmaf(h4.y, b0[1], ay0[t]);
                    ay0[t] = fmaf(h4.z, b0[2], ay0[t]); ay0[t] = fmaf(h4.w, b0[3], ay0[t]);
                    ay1[t] = fmaf(h4.x, b1[0], ay1[t]); ay1[t] = fmaf(h4.y, b1[1], ay1[t]);
                    ay1[t] = fmaf(h4.z, b1[2], ay1[t]); ay1[t] = fmaf(h4.w, b1[3], ay1[t]);
                }
            }
            for (int t = 0; t < nt; ++t) {
                float* dst = &accum[(size_t)stok[t] * DIM + d0];
                atomicAdd(dst, ay0[t]);
                atomicAdd(dst + 1, ay1[t]);
            }
        }
    }
}

__global__ __launch_bounds__(256) void k_routed(const void* xg, const void* w1,
                                                const void* w2, const void* w3,
                                                const int* __restrict__ flag,
                                                const int* offsets, const int* counts,
                                                const int* tokl, const float* wgtl,
                                                float* accum, int bfonly) {
    if (bfonly && !*flag) return;
    __shared__ __align__(16) float xs[16 * DIM];
    __shared__ __align__(16) float hsf[16 * INTER];
    __shared__ int   stok[16];
    __shared__ float ssw[16];
    if (*flag) routed_body<true >(xg, w1, w2, w3, offsets, counts, tokl, wgtl, accum, xs, hsf, stok, ssw);
    else       routed_body<false>(xg, w1, w2, w3, offsets, counts, tokl, wgtl, accum, xs, hsf, stok, ssw);
}

// ---------------- kernel 6: fp32 accum -> output (dtype per flag) ----------------
__global__ void k_final(const float* __restrict__ accum, void* __restrict__ out,
                        const int* __restrict__ flag) {
    int i = blockIdx.x * 256 + threadIdx.x;
    float2 v = ((const float2*)accum)[i];
    if (*flag) {
        ((u32*)out)[i] = (u32)f2bf(v.x) | ((u32)f2bf(v.y) << 16);
    } else {
        ((float2*)out)[i] = v;
    }
}

extern "C" void kernel_launch(void* const* d_in, const int* in_sizes, int n_in,
                              void* d_out, int out_size, void* d_ws, size_t ws_size,
                              hipStream_t stream) {
    const void* x   = d_in[0];
    const void* wg  = d_in[1];
    const void* w1  = d_in[2];
    const void* w2  = d_in[3];
    const void* w3  = d_in[4];
    const void* wsg = d_in[5];
    const void* wsu = d_in[6];
    const void* wsd = d_in[7];

    char* ws = (char*)d_ws;
    float* accum  = (float*)ws;                              // [0, 2MiB)
    char* ctrl    = ws + ((size_t)2 << 20);
    int* counts   = (int*)ctrl;
    int* offsets  = counts + 64;
    int* cursors  = offsets + 64;
    int* topki    = cursors + 64;                            // 6144 ints
    float* topkw  = (float*)(topki + T_TOK * TOPK);          // 6144 floats
    int* tokl     = (int*)(topkw + T_TOK * TOPK);            // 6144 ints
    float* wgtl   = (float*)(tokl + T_TOK * TOPK);           // 6144 floats
    int* flag     = (int*)(wgtl + T_TOK * TOPK);
    int* tileE    = flag + 1;                                // MAXTILES ints
    int* tileT    = tileE + MAXTILES;
    int* tileC    = tileT + MAXTILES;
    int* ntiles   = tileC + MAXTILES;
    int* slot2tile = ntiles + 1;                             // MAXTILES ints
    u16* w2th = (u16*)(ws + ((size_t)3   << 20));            // 16 MiB [3,19)
    u16* w2tl = (u16*)(ws + ((size_t)19  << 20));            // 16 MiB [19,35)
    u16* vh   = (u16*)(ws + ((size_t)35  << 20));            //  2 MiB [35,37)
    u16* vl   = (u16*)(ws + ((size_t)37  << 20));            //  2 MiB [37,39)
    u16* w1h  = (u16*)(ws + ((size_t)40  << 20));            // 16 MiB [40,56)
    u16* w1l  = (u16*)(ws + ((size_t)56  << 20));            // 16 MiB [56,72)
    u16* w3h  = (u16*)(ws + ((size_t)72  << 20));            // 16 MiB [72,88)
    u16* w3l  = (u16*)(ws + ((size_t)88  << 20));            // 16 MiB [88,104)
    u16* wsgh = (u16*)(ws + ((size_t)104 << 20));            // 1 MiB each...
    u16* wsgl = (u16*)(ws + ((size_t)105 << 20));
    u16* wsuh = (u16*)(ws + ((size_t)106 << 20));
    u16* wsul = (u16*)(ws + ((size_t)107 << 20));
    u16* wsdh = (u16*)(ws + ((size_t)108 << 20));
    u16* wsdl = (u16*)(ws + ((size_t)109 << 20));
    u16* xh   = (u16*)(ws + ((size_t)110 << 20));
    u16* xl   = (u16*)(ws + ((size_t)111 << 20));
    u16* hh   = (u16*)(ws + ((size_t)112 << 20));            // 4 MiB [112,116)
    u16* hl   = (u16*)(ws + ((size_t)116 << 20));            // 4 MiB [116,120)
    const bool fast3 = ws_size >= ((size_t)120 << 20);

    k_probe_init<<<1, 64, 0, stream>>>((const u32*)x, flag, counts);
    k_prep  <<<10752, 256, 0, stream>>>((const float*)x, x, wg,
                                        (const float*)w1, (const float*)w3,
                                        (const float*)wsg, (const float*)wsu,
                                        (const float*)wsd, (const float*)w2,
                                        w1h, w1l, w3h, w3l, wsgh, wsgl, wsuh, wsul,
                                        wsdh, wsdl, xh, xl, w2th, w2tl,
                                        counts, topki, topkw, accum, flag, fast3 ? 1 : 0);
    k_prefix<<<1, 64, 0, stream>>>(counts, offsets, cursors, tileE, tileT, tileC,
                                   ntiles, slot2tile);
    k_scatter<<<4, 256, 0, stream>>>(topki, topkw, cursors, tokl, wgtl);

    if (fast3) {
        k_up <<<1536, 256, 0, stream>>>(xh, xl, w1h, w1l, w3h, w3l,
                                        wsgh, wsgl, wsuh, wsul, flag,
                                        offsets, tokl, wgtl,
                                        tileE, tileT, tileC, slot2tile,
                                        hh, hl, vh, vl);
        k_dn <<<1536, 256, 0, stream>>>(hh, hl, w2th, w2tl, vh, vl, wsdh, wsdl,
                                        flag, offsets, tokl,
                                        tileE, tileT, tileC, slot2tile, accum);
        // bf16-input fallback (no-ops when flag==0)
        k_shared <<<128, 256, 0, stream>>>(x, wsg, wsu, wsd, flag, accum, 1);
        k_routed <<<256, 256, 0, stream>>>(x, w1, w2, w3, flag, offsets, counts, tokl, wgtl, accum, 1);
    } else {
        // small workspace: legacy VALU path for both dtypes
        k_shared <<<128, 256, 0, stream>>>(x, wsg, wsu, wsd, flag, accum, 0);
        k_routed <<<256, 256, 0, stream>>>(x, w1, w2, w3, flag, offsets, counts, tokl, wgtl, accum, 0);
    }
    k_final  <<<1024, 256, 0, stream>>>(accum, d_out, flag);
}

// Round 12
// 378.889 us; speedup vs baseline: 1.3485x; 1.0097x over previous
//
#include <hip/hip_runtime.h>
#include <math.h>

// Problem constants
#define T_TOK 1024
#define DIM 512
#define INTER 256
#define SINTER 1024
#define NEXP 64
#define TOPK 6
#define MAXTILES 512

typedef unsigned short u16;
typedef unsigned int u32;
typedef short bf16x8 __attribute__((ext_vector_type(8)));   // 8 bf16 (4 VGPRs)
typedef float f32x4  __attribute__((ext_vector_type(4)));   // MFMA 16x16 accumulator

__device__ __forceinline__ float bflo(u32 u) { return __uint_as_float(u << 16); }
__device__ __forceinline__ float bfhi(u32 u) { return __uint_as_float(u & 0xffff0000u); }

__device__ __forceinline__ u16 f2bf(float f) {
    u32 u = __float_as_uint(f);
    return (u16)((u + 0x7fffu + ((u >> 16) & 1u)) >> 16);  // RNE
}

__device__ __forceinline__ f32x4 mfma16(bf16x8 a, bf16x8 b, f32x4 c) {
    return __builtin_amdgcn_mfma_f32_16x16x32_bf16(a, b, c, 0, 0, 0);
}

// split fp32 -> (hi bf16, lo bf16): v ~= vh + vl, combined err ~2^-16|v|
__device__ __forceinline__ void split1(float v, u16& h, u16& l) {
    u32 u = __float_as_uint(v);
    u32 hb = u & 0xffff0000u;
    float r = v - __uint_as_float(hb);
    h = (u16)(hb >> 16);
    l = (u16)(__float_as_uint(r) >> 16);
}

// split 8 consecutive fp32 (32B-aligned) into hi/lo bf16x8 packed as uint4
__device__ __forceinline__ void split8u(const float* __restrict__ s, uint4& H, uint4& L) {
    const uint4* q = (const uint4*)s;
    uint4 A = q[0], B = q[1];
    u32 wv[8] = {A.x, A.y, A.z, A.w, B.x, B.y, B.z, B.w};
    u32 hp[4], lp[4];
    #pragma unroll
    for (int i = 0; i < 4; ++i) {
        u32 u0 = wv[2*i], u1 = wv[2*i+1];
        u32 h0 = u0 & 0xffff0000u, h1 = u1 & 0xffff0000u;
        float r0 = __uint_as_float(u0) - __uint_as_float(h0);
        float r1 = __uint_as_float(u1) - __uint_as_float(h1);
        hp[i] = (h0 >> 16) | h1;
        lp[i] = (__float_as_uint(r0) >> 16) | (__float_as_uint(r1) & 0xffff0000u);
    }
    H.x = hp[0]; H.y = hp[1]; H.z = hp[2]; H.w = hp[3];
    L.x = lp[0]; L.y = lp[1]; L.z = lp[2]; L.w = lp[3];
}

// load 8 consecutive elements (idx must be a multiple of 8) as floats
template<bool BF>
__device__ __forceinline__ void ld8(const void* p, size_t idx, float* f) {
    if (BF) {
        uint4 u = *(const uint4*)((const u16*)p + idx);
        f[0] = bflo(u.x); f[1] = bfhi(u.x);
        f[2] = bflo(u.y); f[3] = bfhi(u.y);
        f[4] = bflo(u.z); f[5] = bfhi(u.z);
        f[6] = bflo(u.w); f[7] = bfhi(u.w);
    } else {
        const float4* q = (const float4*)((const float*)p + idx);
        float4 a = q[0], b = q[1];
        f[0] = a.x; f[1] = a.y; f[2] = a.z; f[3] = a.w;
        f[4] = b.x; f[5] = b.y; f[6] = b.z; f[7] = b.w;
    }
}

// load 2 consecutive elements (idx even)
template<bool BF>
__device__ __forceinline__ void ld2(const void* p, size_t idx, float& a, float& b) {
    if (BF) { u32 w = *(const u32*)((const u16*)p + idx); a = bflo(w); b = bfhi(w); }
    else    { float2 v = *(const float2*)((const float*)p + idx); a = v.x; b = v.y; }
}

__device__ __forceinline__ void fma44(float& acc, const float* f, const float4& a, const float4& b) {
    acc = fmaf(f[0], a.x, acc); acc = fmaf(f[1], a.y, acc);
    acc = fmaf(f[2], a.z, acc); acc = fmaf(f[3], a.w, acc);
    acc = fmaf(f[4], b.x, acc); acc = fmaf(f[5], b.y, acc);
    acc = fmaf(f[6], b.z, acc); acc = fmaf(f[7], b.w, acc);
}

// ---------------- kernel PI: dtype probe + zero counters ----------------
__global__ void k_probe_init(const u32* __restrict__ xw, int* __restrict__ flag,
                             int* __restrict__ counts) {
    counts[threadIdx.x] = 0;
    int cnt = 0;
    #pragma unroll
    for (int i = 0; i < 8; ++i) {
        u32 u = xw[threadIdx.x * 8 + i];
        u32 e = (u >> 7) & 0xffu;           // exponent of low-half-as-bf16
        cnt += (e >= 110 && e <= 140) ? 1 : 0;
    }
    #pragma unroll
    for (int off = 32; off; off >>= 1) cnt += __shfl_xor(cnt, off);
    if (threadIdx.x == 0) flag[0] = (cnt > 256) ? 1 : 0;
}

// ---------------- router body (one token per wave) ----------------
template<bool BF>
__device__ __forceinline__ void router_body(const void* __restrict__ xg,
                                            const void* __restrict__ wg,
                                            int* __restrict__ counts,
                                            int* __restrict__ topki,
                                            float* __restrict__ topkw,
                                            float* xsrow, int t, int lane) {
    ld8<BF>(xg, (size_t)t * DIM + lane * 8, &xsrow[lane * 8]);
    __syncthreads();

    float acc = 0.f;
    for (int k = 0; k < 64; ++k) {
        float f[8]; ld8<BF>(wg, (size_t)lane * DIM + k * 8, f);
        float4 xa = *(const float4*)&xsrow[k * 8];
        float4 xb = *(const float4*)&xsrow[k * 8 + 4];
        fma44(acc, f, xa, xb);
    }

    float my = acc;
    float sv[TOPK]; int si[TOPK];
    #pragma unroll
    for (int s = 0; s < TOPK; ++s) {
        float v = my; int id = lane;
        #pragma unroll
        for (int off = 32; off; off >>= 1) {
            float ov = __shfl_xor(v, off);
            int   oi = __shfl_xor(id, off);
            if (ov > v || (ov == v && oi < id)) { v = ov; id = oi; }
        }
        sv[s] = v; si[s] = id;
        if (lane == id) my = -INFINITY;
    }
    if (lane == 0) {
        float m = sv[0], sum = 0.f, w[TOPK];
        #pragma unroll
        for (int s = 0; s < TOPK; ++s) { w[s] = __expf(sv[s] - m); sum += w[s]; }
        float inv = 1.f / sum;
        #pragma unroll
        for (int s = 0; s < TOPK; ++s) {
            int e = si[s];
            topki[t * TOPK + s] = e;
            topkw[t * TOPK + s] = w[s] * inv;
            atomicAdd(&counts[e], 1);
        }
    }
}

// ---- kernel PREP: router [0,256) | bsplit [256,9472) | w2ts [9472,10496) | zero accum [10496,10752) ----
__global__ __launch_bounds__(256) void k_prep(
        const float* __restrict__ xf, const void* __restrict__ xg,
        const void* __restrict__ wgate,
        const float* __restrict__ w1, const float* __restrict__ w3,
        const float* __restrict__ wsg, const float* __restrict__ wsu,
        const float* __restrict__ wsd, const float* __restrict__ w2,
        u16* w1h, u16* w1l, u16* w3h, u16* w3l,
        u16* wsgh, u16* wsgl, u16* wsuh, u16* wsul,
        u16* wsdh, u16* wsdl, u16* xh, u16* xl,
        u16* w2th, u16* w2tl,
        int* counts, int* topki, float* topkw,
        float* __restrict__ accum,
        const int* __restrict__ flag, int dosplit) {
    __shared__ __align__(16) char smem[33280];   // max(router 8KB, w2ts 33.25KB)
    const int b = blockIdx.x;
    const int tid = threadIdx.x;

    if (b < 256) {
        // ---- router: 4 tokens per block (1 per wave) ----
        float* xs = (float*)smem;
        const int wv = tid >> 6, lane = tid & 63;
        const int t = b * 4 + wv;
        if (*flag) router_body<true >(xg, wgate, counts, topki, topkw, xs + wv * DIM, t, lane);
        else       router_body<false>(xg, wgate, counts, topki, topkw, xs + wv * DIM, t, lane);
        return;
    }
    if (b >= 10496) {
        // ---- zero accum ----
        const uint4 z = {0u, 0u, 0u, 0u};
        ((uint4*)accum)[(size_t)(b - 10496) * 256 + tid] = z;
        return;
    }
    if (*flag || !dosplit) return;

    if (b < 256 + 9216) {
        // ---- bulk split fp32 -> hi/lo planes ----
        const int bb = b - 256;
        const float* src; u16* dh; u16* dl; size_t base;
        if (bb < 4096)      { src = w1;  dh = w1h;  dl = w1l;  base = (size_t)bb * 2048; }
        else if (bb < 8192) { src = w3;  dh = w3h;  dl = w3l;  base = (size_t)(bb - 4096) * 2048; }
        else if (bb < 8448) { src = wsg; dh = wsgh; dl = wsgl; base = (size_t)(bb - 8192) * 2048; }
        else if (bb < 8704) { src = wsu; dh = wsuh; dl = wsul; base = (size_t)(bb - 8448) * 2048; }
        else if (bb < 8960) { src = wsd; dh = wsdh; dl = wsdl; base = (size_t)(bb - 8704) * 2048; }
        else                { src = xf;  dh = xh;   dl = xl;   base = (size_t)(bb - 8960) * 2048; }
        size_t idx = base + (size_t)tid * 8;
        uint4 H, L;
        split8u(src + idx, H, L);
        *(uint4*)(dh + idx) = H;
        *(uint4*)(dl + idx) = L;
        return;
    }

    // ---- w2 transpose+split [e][i][d] -> hi/lo [e][d][i] ----
    {
        const int bb = b - 9472;
        u32 (*lt)[65] = (u32(*)[65])smem;        // 128 x 65 packed hi<<16|lo
        const int e  = bb >> 4;
        const int ic = (bb >> 3) & 1;            // i-chunk of 128
        const int dc = bb & 7;                   // d-chunk of 64
        const float* src = w2 + (size_t)e * INTER * DIM + (size_t)(ic * 128) * DIM + dc * 64;
        #pragma unroll
        for (int p = 0; p < 8; ++p) {
            int f = p * 256 + tid;
            int i = f >> 4, dq = f & 15;
            float4 v = *(const float4*)(src + (size_t)i * DIM + dq * 4);
            float vv[4] = {v.x, v.y, v.z, v.w};
            #pragma unroll
            for (int j = 0; j < 4; ++j) {
                u32 u = __float_as_uint(vv[j]);
                u32 hb = u & 0xffff0000u;
                float r = vv[j] - __uint_as_float(hb);
                lt[i][dq * 4 + j] = hb | (__float_as_uint(r) >> 16);
            }
        }
        __syncthreads();
        const int dl = tid & 63, q = tid >> 6;
        size_t rb = ((size_t)e * DIM + dc * 64 + dl) * INTER + ic * 128 + q * 32;
        #pragma unroll
        for (int s = 0; s < 4; ++s) {
            u32 h2[4], l2[4];
            #pragma unroll
            for (int m = 0; m < 4; ++m) {
                u32 p0 = lt[q * 32 + s * 8 + m * 2][dl];
                u32 p1 = lt[q * 32 + s * 8 + m * 2 + 1][dl];
                h2[m] = (p0 >> 16) | (p1 & 0xffff0000u);
                l2[m] = (p0 & 0xffffu) | (p1 << 16);
            }
            uint4 Hv = {h2[0], h2[1], h2[2], h2[3]};
            uint4 Lv = {l2[0], l2[1], l2[2], l2[3]};
            *(uint4*)(w2th + rb + s * 8) = Hv;
            *(uint4*)(w2tl + rb + s * 8) = Lv;
        }
    }
}

// ---------------- kernel 2: prefix sum + XCD-binned tile slots (parallel, r8-proven) ----------------
__global__ __launch_bounds__(64) void k_prefix(const int* __restrict__ counts,
                         int* __restrict__ offsets, int* __restrict__ cursors,
                         int* __restrict__ tileE, int* __restrict__ tileT,
                         int* __restrict__ tileC, int* __restrict__ ntiles,
                         int* __restrict__ slot2tile) {
    __shared__ int sc[NEXP], snt[NEXP], sbin[8];
    __shared__ int sflag;
    const int e = threadIdx.x;
    const int b = e & 7;
    int c = counts[e];
    sc[e] = c;
    snt[e] = (c + 15) >> 4;
    __syncthreads();

    int off = 0, tb = 0;
    for (int i = 0; i < e; ++i) { off += sc[i]; tb += snt[i]; }
    int bp = 0;
    for (int i = b; i < e; i += 8) bp += snt[i];
    offsets[e] = off;
    cursors[e] = off;

    if (e < 8) {
        int tot = 0;
        for (int i = e; i < NEXP; i += 8) tot += snt[i];
        sbin[e] = tot;
    }
    if (e == 0) {
        int nt = 0;
        for (int i = 0; i < NEXP; ++i) nt += snt[i];
        *ntiles = nt;
    }
    #pragma unroll
    for (int i = 0; i < MAXTILES / NEXP; ++i) slot2tile[e + i * NEXP] = -1;
    __syncthreads();

    if (e == 0) {
        int f = 0;
        for (int i = 0; i < 8; ++i) if (sbin[i] > MAXTILES / 8) f = 1;
        sflag = f;
    }
    __syncthreads();

    const int swz = (sflag == 0);
    const int nt_e = snt[e];
    for (int t = 0; t < nt_e; ++t) {
        int idx = tb + t;
        tileE[idx] = e;
        tileT[idx] = t * 16;
        tileC[idx] = min(16, c - t * 16);
        int s = swz ? ((bp + t) * 8 + b) : idx;
        slot2tile[s] = idx;
    }
}

// ---------------- kernel 3: scatter tokens into expert buckets (+ record positions) ----------------
__global__ void k_scatter(const int* __restrict__ topki, const float* __restrict__ topkw,
                          int* __restrict__ cursors, int* __restrict__ tokl,
                          float* __restrict__ wgtl, int* __restrict__ posl) {
    int t = blockIdx.x * 256 + threadIdx.x;
    #pragma unroll
    for (int s = 0; s < TOPK; ++s) {
        int e = topki[t * TOPK + s];
        float w = topkw[t * TOPK + s];
        int pos = atomicAdd(&cursors[e], 1);
        tokl[pos] = t;
        wgtl[pos] = w;
        posl[t * TOPK + s] = pos;
    }
}

// ---------------- up-projection bodies ----------------
__device__ __forceinline__ void rA_body(
        const u16* __restrict__ xh, const u16* __restrict__ xl,
        const u16* __restrict__ w1h, const u16* __restrict__ w1l,
        const u16* __restrict__ w3h, const u16* __restrict__ w3l,
        const int* __restrict__ offsets, const int* __restrict__ tokl,
        const float* __restrict__ wgtl, const int* __restrict__ tileE,
        const int* __restrict__ tileT, const int* __restrict__ tileC,
        u16* __restrict__ hh, u16* __restrict__ hl,
        int tileIdx, int ih, u16* xsh, u16* xsl, int* stok, float* ssw) {
    const int tid = threadIdx.x;
    const int lane = tid & 63, w = tid >> 6;
    const int lr = lane & 15, lg = lane >> 4;
    const int e = tileE[tileIdx];
    const int cnt = tileC[tileIdx];
    const int sbase = offsets[e] + tileT[tileIdx];
    const size_t wbase = (size_t)e * INTER * DIM;

    if (tid < 16) {
        int ok = tid < cnt;
        stok[tid] = ok ? tokl[sbase + tid] : tokl[sbase];   // pad: valid token, ssw=0
        ssw[tid]  = ok ? wgtl[sbase + tid] : 0.f;
    }
    __syncthreads();
    for (int idx = tid; idx < 16 * 64; idx += 256) {
        int r = idx >> 6, c = idx & 63;
        int off = r * 1024 + ((c * 16) ^ ((r & 7) << 4));
        size_t g = (size_t)stok[r] * DIM + c * 8;
        *(uint4*)((char*)xsh + off) = *(const uint4*)(xh + g);
        *(uint4*)((char*)xsl + off) = *(const uint4*)(xl + g);
    }
    __syncthreads();

    const f32x4 z4 = {0.f, 0.f, 0.f, 0.f};
    f32x4 a1[2] = {z4, z4};
    f32x4 a3[2] = {z4, z4};
    const int j0 = ih * 128 + w * 32;
    #pragma unroll 4
    for (int ks = 0; ks < 16; ++ks) {
        const int k0 = ks * 32 + lg * 8;
        const int xoff = lr * 1024 + ((k0 * 2) ^ ((lr & 7) << 4));
        bf16x8 ah = *(const bf16x8*)((const char*)xsh + xoff);
        bf16x8 al = *(const bf16x8*)((const char*)xsl + xoff);
        #pragma unroll
        for (int q = 0; q < 2; ++q) {
            const size_t row = wbase + (size_t)(j0 + q * 16 + lr) * DIM + k0;
            bf16x8 bh = *(const bf16x8*)(w1h + row);
            bf16x8 bl = *(const bf16x8*)(w1l + row);
            a1[q] = mfma16(ah, bh, a1[q]);
            a1[q] = mfma16(ah, bl, a1[q]);
            a1[q] = mfma16(al, bh, a1[q]);
            bh = *(const bf16x8*)(w3h + row);
            bl = *(const bf16x8*)(w3l + row);
            a3[q] = mfma16(ah, bh, a3[q]);
            a3[q] = mfma16(ah, bl, a3[q]);
            a3[q] = mfma16(al, bh, a3[q]);
        }
    }
    #pragma unroll
    for (int q = 0; q < 2; ++q) {
        #pragma unroll
        for (int r = 0; r < 4; ++r) {
            const int t = lg * 4 + r;
            float g = a1[q][r];
            float h = g / (1.f + __expf(-g)) * a3[q][r] * ssw[t];
            u16 hh16, hl16; split1(h, hh16, hl16);
            size_t o = (size_t)(tileIdx * 16 + t) * INTER + j0 + q * 16 + lr;
            hh[o] = hh16;
            hl[o] = hl16;
        }
    }
}

__device__ __forceinline__ void shA_body(
        const u16* __restrict__ xh, const u16* __restrict__ xl,
        const u16* __restrict__ wsgh, const u16* __restrict__ wsgl,
        const u16* __restrict__ wsuh, const u16* __restrict__ wsul,
        u16* __restrict__ vh, u16* __restrict__ vl,
        int tt, int sc, u16* xsh, u16* xsl) {
    const int tid = threadIdx.x;
    const int w = tid >> 6, lane = tid & 63;
    const int lr = lane & 15, lg = lane >> 4;

    for (int idx = tid; idx < 16 * 64; idx += 256) {
        int r = idx >> 6, c = idx & 63;
        int off = r * 1024 + ((c * 16) ^ ((r & 7) << 4));
        size_t g = (size_t)(tt * 16 + r) * DIM + c * 8;
        *(uint4*)((char*)xsh + off) = *(const uint4*)(xh + g);
        *(uint4*)((char*)xsl + off) = *(const uint4*)(xl + g);
    }
    __syncthreads();

    const f32x4 z4 = {0.f, 0.f, 0.f, 0.f};
    f32x4 ag[2] = {z4, z4};
    f32x4 au[2] = {z4, z4};
    const int j0 = sc * 128 + w * 32;
    #pragma unroll 4
    for (int ks = 0; ks < 16; ++ks) {
        const int k0 = ks * 32 + lg * 8;
        const int xoff = lr * 1024 + ((k0 * 2) ^ ((lr & 7) << 4));
        bf16x8 ah = *(const bf16x8*)((const char*)xsh + xoff);
        bf16x8 al = *(const bf16x8*)((const char*)xsl + xoff);
        #pragma unroll
        for (int q = 0; q < 2; ++q) {
            const size_t row = (size_t)(j0 + q * 16 + lr) * DIM + k0;
            bf16x8 bh = *(const bf16x8*)(wsgh + row);
            bf16x8 bl = *(const bf16x8*)(wsgl + row);
            ag[q] = mfma16(ah, bh, ag[q]);
            ag[q] = mfma16(ah, bl, ag[q]);
            ag[q] = mfma16(al, bh, ag[q]);
            bh = *(const bf16x8*)(wsuh + row);
            bl = *(const bf16x8*)(wsul + row);
            au[q] = mfma16(ah, bh, au[q]);
            au[q] = mfma16(ah, bl, au[q]);
            au[q] = mfma16(al, bh, au[q]);
        }
    }
    #pragma unroll
    for (int q = 0; q < 2; ++q) {
        #pragma unroll
        for (int r = 0; r < 4; ++r) {
            const int t = lg * 4 + r;
            float g = ag[q][r];
            float v = g / (1.f + __expf(-g)) * au[q][r];
            u16 h16, l16; split1(v, h16, l16);
            size_t o = (size_t)(tt * 16 + t) * SINTER + j0 + q * 16 + lr;
            vh[o] = h16;
            vl[o] = l16;
        }
    }
}

// ---------------- kernel UP: rA [0,1024) | shA [1024,1536) ----------------
__global__ __launch_bounds__(256, 4) void k_up(
        const u16* __restrict__ xh, const u16* __restrict__ xl,
        const u16* __restrict__ w1h, const u16* __restrict__ w1l,
        const u16* __restrict__ w3h, const u16* __restrict__ w3l,
        const u16* __restrict__ wsgh, const u16* __restrict__ wsgl,
        const u16* __restrict__ wsuh, const u16* __restrict__ wsul,
        const int* __restrict__ flag, const int* __restrict__ offsets,
        const int* __restrict__ tokl, const float* __restrict__ wgtl,
        const int* __restrict__ tileE, const int* __restrict__ tileT,
        const int* __restrict__ tileC, const int* __restrict__ slot2tile,
        u16* __restrict__ hh, u16* __restrict__ hl,
        u16* __restrict__ vh, u16* __restrict__ vl) {
    if (*flag) return;
    __shared__ __align__(16) char smem[33024];   // xsh 16K | xsl 16K | stok 64 | ssw 64
    u16* xsh = (u16*)smem;
    u16* xsl = (u16*)(smem + 16384);
    const int b = blockIdx.x;
    if (b < 1024) {
        const int tileIdx = slot2tile[b & 511];
        if (tileIdx < 0) return;
        int* stok = (int*)(smem + 32768);
        float* ssw = (float*)(smem + 32832);
        rA_body(xh, xl, w1h, w1l, w3h, w3l, offsets, tokl, wgtl,
                tileE, tileT, tileC, hh, hl, tileIdx, b >> 9, xsh, xsl, stok, ssw);
    } else {
        const int bb = b - 1024;
        shA_body(xh, xl, wsgh, wsgl, wsuh, wsul, vh, vl, bb >> 3, bb & 7, xsh, xsl);
    }
}

// ---------------- down-projection bodies (no LDS; NO ATOMICS — r12 de-atomicize) ----------------
// rB plain-stores Y to ybuf[pos][dim] (each pos,dim written by exactly one block).
__device__ __forceinline__ void rB_body(
        const u16* __restrict__ hh, const u16* __restrict__ hl,
        const u16* __restrict__ w2th, const u16* __restrict__ w2tl,
        const int* __restrict__ offsets,
        const int* __restrict__ tileE, const int* __restrict__ tileT,
        const int* __restrict__ tileC, float* __restrict__ ybuf,
        int tileIdx, int dh) {
    const int tid = threadIdx.x;
    const int lane = tid & 63, w = tid >> 6;
    const int lr = lane & 15, lg = lane >> 4;
    const int e = tileE[tileIdx];
    const int cnt = tileC[tileIdx];
    const int sbase = offsets[e] + tileT[tileIdx];
    const size_t w2base = (size_t)e * DIM * INTER;
    const int d0 = dh * 256 + w * 64;

    const u16* hrh = hh + (size_t)(tileIdx * 16 + lr) * INTER;
    const u16* hrl = hl + (size_t)(tileIdx * 16 + lr) * INTER;
    const f32x4 z4 = {0.f, 0.f, 0.f, 0.f};
    f32x4 ay[4] = {z4, z4, z4, z4};
    #pragma unroll 4
    for (int ks = 0; ks < 8; ++ks) {
        const int k0 = ks * 32 + lg * 8;
        bf16x8 ah = *(const bf16x8*)(hrh + k0);
        bf16x8 al = *(const bf16x8*)(hrl + k0);
        #pragma unroll
        for (int q = 0; q < 4; ++q) {
            const size_t row = w2base + (size_t)(d0 + q * 16 + lr) * INTER + k0;
            bf16x8 bh = *(const bf16x8*)(w2th + row);
            bf16x8 bl = *(const bf16x8*)(w2tl + row);
            ay[q] = mfma16(ah, bh, ay[q]);
            ay[q] = mfma16(ah, bl, ay[q]);
            ay[q] = mfma16(al, bh, ay[q]);
        }
    }
    #pragma unroll
    for (int q = 0; q < 4; ++q) {
        #pragma unroll
        for (int r = 0; r < 4; ++r) {
            const int t = lg * 4 + r;
            if (t < cnt)
                ybuf[(size_t)(sbase + t) * DIM + d0 + q * 16 + lr] = ay[q][r];
        }
    }
}

// shB plain-stores to accum (sole writer of accum in k_dn).
__device__ __forceinline__ void shB_body(
        const u16* __restrict__ vh, const u16* __restrict__ vl,
        const u16* __restrict__ wsdh, const u16* __restrict__ wsdl,
        float* __restrict__ accum, int tt, int dc) {
    const int w = threadIdx.x >> 6, lane = threadIdx.x & 63;
    const int lr = lane & 15, lg = lane >> 4;
    const int d0 = dc * 64 + w * 16;
    const u16* vhrow = vh + (size_t)(tt * 16 + lr) * SINTER;
    const u16* vlrow = vl + (size_t)(tt * 16 + lr) * SINTER;
    const u16* whrow = wsdh + (size_t)(d0 + lr) * SINTER;
    const u16* wlrow = wsdl + (size_t)(d0 + lr) * SINTER;
    f32x4 acc = {0.f, 0.f, 0.f, 0.f};
    #pragma unroll 8
    for (int ks = 0; ks < 32; ++ks) {
        const int k0 = ks * 32 + lg * 8;
        bf16x8 avh = *(const bf16x8*)(vhrow + k0);
        bf16x8 avl = *(const bf16x8*)(vlrow + k0);
        bf16x8 bh  = *(const bf16x8*)(whrow + k0);
        bf16x8 bl  = *(const bf16x8*)(wlrow + k0);
        acc = mfma16(avh, bh, acc);
        acc = mfma16(avh, bl, acc);
        acc = mfma16(avl, bh, acc);
    }
    #pragma unroll
    for (int r = 0; r < 4; ++r)
        accum[(size_t)(tt * 16 + lg * 4 + r) * DIM + d0 + lr] = acc[r];
}

// ---------------- kernel DN: rB [0,1024) | shB [1024,1536) ----------------
__global__ __launch_bounds__(256, 4) void k_dn(
        const u16* __restrict__ hh, const u16* __restrict__ hl,
        const u16* __restrict__ w2th, const u16* __restrict__ w2tl,
        const u16* __restrict__ vh, const u16* __restrict__ vl,
        const u16* __restrict__ wsdh, const u16* __restrict__ wsdl,
        const int* __restrict__ flag, const int* __restrict__ offsets,
        const int* __restrict__ tileE, const int* __restrict__ tileT,
        const int* __restrict__ tileC, const int* __restrict__ slot2tile,
        float* __restrict__ ybuf, float* __restrict__ accum) {
    if (*flag) return;
    const int b = blockIdx.x;
    if (b < 1024) {
        const int tileIdx = slot2tile[b & 511];
        if (tileIdx < 0) return;
        rB_body(hh, hl, w2th, w2tl, offsets, tileE, tileT, tileC,
                ybuf, tileIdx, b >> 9);
    } else {
        const int bb = b - 1024;
        shB_body(vh, vl, wsdh, wsdl, accum, bb >> 3, bb & 7);
    }
}

// ============== legacy VALU kernels (bf16 inputs, or tiny-workspace fallback) ==============

template<bool BF>
__device__ __forceinline__ void shared_body(const void* __restrict__ xg,
                                            const void* __restrict__ wsg,
                                            const void* __restrict__ wsu,
                                            const void* __restrict__ wsd,
                                            float* __restrict__ accum,
                                            float* xs /*8*DIM*/, float* vsf /*8*SINTER*/) {
    const int t0 = blockIdx.x * 8;
    const int tid = threadIdx.x;

    for (int idx = tid; idx < 8 * 64; idx += 256) {
        int r = idx >> 6, c = idx & 63;
        ld8<BF>(xg, (size_t)(t0 + r) * DIM + c * 8, &xs[r * DIM + c * 8]);
    }
    __syncthreads();

    for (int jc = 0; jc < 4; ++jc) {
        int j = jc * 256 + tid;
        float ag[8] = {0}, au[8] = {0};
        for (int k = 0; k < 64; ++k) {
            float fg[8], fu[8];
            ld8<BF>(wsg, (size_t)j * DIM + k * 8, fg);
            ld8<BF>(wsu, (size_t)j * DIM + k * 8, fu);
            #pragma unroll
            for (int r = 0; r < 8; ++r) {
                float4 xa = *(const float4*)&xs[r * DIM + k * 8];
                float4 xb = *(const float4*)&xs[r * DIM + k * 8 + 4];
                fma44(ag[r], fg, xa, xb);
                fma44(au[r], fu, xa, xb);
            }
        }
        #pragma unroll
        for (int r = 0; r < 8; ++r) {
            float g = ag[r];
            vsf[r * SINTER + j] = g / (1.f + __expf(-g)) * au[r];
        }
    }
    __syncthreads();

    const int d0 = tid, d1 = tid + 256;
    float aca[8] = {0}, acb[8] = {0};
    for (int k = 0; k < 128; ++k) {
        float fa[8], fb[8];
        ld8<BF>(wsd, (size_t)d0 * SINTER + k * 8, fa);
        ld8<BF>(wsd, (size_t)d1 * SINTER + k * 8, fb);
        #pragma unroll
        for (int r = 0; r < 8; ++r) {
            float4 v0 = *(const float4*)&vsf[r * SINTER + k * 8];
            float4 v1 = *(const float4*)&vsf[r * SINTER + k * 8 + 4];
            fma44(aca[r], fa, v0, v1);
            fma44(acb[r], fb, v0, v1);
        }
    }
    #pragma unroll
    for (int r = 0; r < 8; ++r) {
        accum[(size_t)(t0 + r) * DIM + d0] = aca[r];
        accum[(size_t)(t0 + r) * DIM + d1] = acb[r];
    }
}

__global__ __launch_bounds__(256) void k_shared(const void* xg, const void* wsg,
                                                const void* wsu, const void* wsd,
                                                const int* __restrict__ flag,
                                                float* accum, int bfonly) {
    if (bfonly && !*flag) return;
    __shared__ __align__(16) float xs[8 * DIM];
    __shared__ __align__(16) float vsf[8 * SINTER];
    if (*flag) shared_body<true >(xg, wsg, wsu, wsd, accum, xs, vsf);
    else       shared_body<false>(xg, wsg, wsu, wsd, accum, xs, vsf);
}

template<bool BF>
__device__ __forceinline__ void routed_body(const void* __restrict__ xg,
                                            const void* __restrict__ w1,
                                            const void* __restrict__ w2,
                                            const void* __restrict__ w3,
                                            const int* __restrict__ offsets,
                                            const int* __restrict__ counts,
                                            const int* __restrict__ tokl,
                                            const float* __restrict__ wgtl,
                                            float* __restrict__ accum,
                                            float* xs /*16*DIM*/, float* hsf /*16*INTER*/,
                                            int* stok, float* ssw) {
    const int e = blockIdx.x & 63;
    const int slice = blockIdx.x >> 6;
    const int tid = threadIdx.x;
    const int n = counts[e];
    const int base = offsets[e];
    const size_t wbase = (size_t)e * INTER * DIM;

    for (int tile = slice * 16; tile < n; tile += 64) {
        const int nt = min(16, n - tile);
        __syncthreads();
        if (tid < 16) {
            int ok = tid < nt;
            stok[tid] = ok ? tokl[base + tile + tid] : 0;
            ssw[tid]  = ok ? wgtl[base + tile + tid] : 0.f;
        }
        __syncthreads();
        for (int idx = tid; idx < 16 * 64; idx += 256) {
            int r = idx >> 6, c = idx & 63;
            float* xp = &xs[r * DIM + c * 8];
            if (r < nt) {
                ld8<BF>(xg, (size_t)stok[r] * DIM + c * 8, xp);
            } else {
                #pragma unroll
                for (int q = 0; q < 8; ++q) xp[q] = 0.f;
            }
        }
        __syncthreads();

        {
            float a1[16] = {0}, a3[16] = {0};
            for (int k = 0; k < 64; ++k) {
                float f1[8], f3[8];
                ld8<BF>(w1, wbase + (size_t)tid * DIM + k * 8, f1);
                ld8<BF>(w3, wbase + (size_t)tid * DIM + k * 8, f3);
                #pragma unroll
                for (int t = 0; t < 16; ++t) {
                    float4 xa = *(const float4*)&xs[t * DIM + k * 8];
                    float4 xb = *(const float4*)&xs[t * DIM + k * 8 + 4];
                    fma44(a1[t], f1, xa, xb);
                    fma44(a3[t], f3, xa, xb);
                }
            }
            #pragma unroll
            for (int t = 0; t < 16; ++t) {
                float g = a1[t];
                hsf[t * INTER + tid] = g / (1.f + __expf(-g)) * a3[t] * ssw[t];
            }
        }
        __syncthreads();

        {
            const int d0 = 2 * tid;
            float ay0[16] = {0}, ay1[16] = {0};
            for (int i = 0; i < INTER; i += 4) {
                float b0[4], b1[4];
                #pragma unroll
                for (int ii = 0; ii < 4; ++ii)
                    ld2<BF>(w2, wbase + (size_t)(i + ii) * DIM + d0, b0[ii], b1[ii]);
                #pragma unroll
                for (int t = 0; t < 16; ++t) {
                    float4 h4 = *(const float4*)&hsf[t * INTER + i];
                    ay0[t] = fmaf(h4.x, b0[0], ay0[t]); ay0[t] = fmaf(h4.y, b0[1], ay0[t]);
                    ay0[t] = fmaf(h4.z, b0[2], ay0[t]); ay0[t] = fmaf(h4.w, b0[3], ay0[t]);
                    ay1[t] = fmaf(h4.x, b1[0], ay1[t]); ay1[t] = fmaf(h4.y, b1[1], ay1[t]);
                    ay1[t] = fmaf(h4.z, b1[2], ay1[t]); ay1[t] = fmaf(h4.w, b1[3], ay1[t]);
                }
            }
            for (int t = 0; t < nt; ++t) {
                float* dst = &accum[(size_t)stok[t] * DIM + d0];
                atomicAdd(dst, ay0[t]);
                atomicAdd(dst + 1, ay1[t]);
            }
        }
    }
}

__global__ __launch_bounds__(256) void k_routed(const void* xg, const void* w1,
                                                const void* w2, const void* w3,
                                                const int* __restrict__ flag,
                                                const int* offsets, const int* counts,
                                                const int* tokl, const float* wgtl,
                                                float* accum, int bfonly) {
    if (bfonly && !*flag) return;
    __shared__ __align__(16) float xs[16 * DIM];
    __shared__ __align__(16) float hsf[16 * INTER];
    __shared__ int   stok[16];
    __shared__ float ssw[16];
    if (*flag) routed_body<true >(xg, w1, w2, w3, offsets, counts, tokl, wgtl, accum, xs, hsf, stok, ssw);
    else       routed_body<false>(xg, w1, w2, w3, offsets, counts, tokl, wgtl, accum, xs, hsf, stok, ssw);
}

// ---------------- kernel 6: combine accum + gathered Y -> output ----------------
// Block = one token; thread covers 2 dims.
__global__ __launch_bounds__(256) void k_final(const float* __restrict__ accum,
                                               const float* __restrict__ ybuf,
                                               const int* __restrict__ posl,
                                               void* __restrict__ out,
                                               const int* __restrict__ flag, int useY) {
    const int t = blockIdx.x;
    const int d0 = threadIdx.x * 2;
    float2 v = *(const float2*)&accum[(size_t)t * DIM + d0];
    if (useY && !*flag) {
        #pragma unroll
        for (int s = 0; s < TOPK; ++s) {
            int pos = posl[t * TOPK + s];
            float2 y = *(const float2*)&ybuf[(size_t)pos * DIM + d0];
            v.x += y.x; v.y += y.y;
        }
    }
    size_t i = (size_t)t * (DIM / 2) + threadIdx.x;
    if (*flag) {
        ((u32*)out)[i] = (u32)f2bf(v.x) | ((u32)f2bf(v.y) << 16);
    } else {
        ((float2*)out)[i] = v;
    }
}

extern "C" void kernel_launch(void* const* d_in, const int* in_sizes, int n_in,
                              void* d_out, int out_size, void* d_ws, size_t ws_size,
                              hipStream_t stream) {
    const void* x   = d_in[0];
    const void* wg  = d_in[1];
    const void* w1  = d_in[2];
    const void* w2  = d_in[3];
    const void* w3  = d_in[4];
    const void* wsg = d_in[5];
    const void* wsu = d_in[6];
    const void* wsd = d_in[7];

    char* ws = (char*)d_ws;
    float* accum  = (float*)ws;                              // [0, 2MiB)
    char* ctrl    = ws + ((size_t)2 << 20);
    int* counts   = (int*)ctrl;
    int* offsets  = counts + 64;
    int* cursors  = offsets + 64;
    int* topki    = cursors + 64;                            // 6144 ints
    float* topkw  = (float*)(topki + T_TOK * TOPK);          // 6144 floats
    int* tokl     = (int*)(topkw + T_TOK * TOPK);            // 6144 ints
    float* wgtl   = (float*)(tokl + T_TOK * TOPK);           // 6144 floats
    int* flag     = (int*)(wgtl + T_TOK * TOPK);
    int* tileE    = flag + 1;                                // MAXTILES ints
    int* tileT    = tileE + MAXTILES;
    int* tileC    = tileT + MAXTILES;
    int* ntiles   = tileC + MAXTILES;
    int* slot2tile = ntiles + 1;                             // MAXTILES ints
    int* posl     = slot2tile + MAXTILES;                    // 6144 ints
    u16* w2th = (u16*)(ws + ((size_t)3   << 20));            // 16 MiB [3,19)
    u16* w2tl = (u16*)(ws + ((size_t)19  << 20));            // 16 MiB [19,35)
    u16* vh   = (u16*)(ws + ((size_t)35  << 20));            //  2 MiB [35,37)
    u16* vl   = (u16*)(ws + ((size_t)37  << 20));            //  2 MiB [37,39)
    u16* w1h  = (u16*)(ws + ((size_t)40  << 20));            // 16 MiB [40,56)
    u16* w1l  = (u16*)(ws + ((size_t)56  << 20));            // 16 MiB [56,72)
    u16* w3h  = (u16*)(ws + ((size_t)72  << 20));            // 16 MiB [72,88)
    u16* w3l  = (u16*)(ws + ((size_t)88  << 20));            // 16 MiB [88,104)
    u16* wsgh = (u16*)(ws + ((size_t)104 << 20));            // 1 MiB each...
    u16* wsgl = (u16*)(ws + ((size_t)105 << 20));
    u16* wsuh = (u16*)(ws + ((size_t)106 << 20));
    u16* wsul = (u16*)(ws + ((size_t)107 << 20));
    u16* wsdh = (u16*)(ws + ((size_t)108 << 20));
    u16* wsdl = (u16*)(ws + ((size_t)109 << 20));
    u16* xh   = (u16*)(ws + ((size_t)110 << 20));
    u16* xl   = (u16*)(ws + ((size_t)111 << 20));
    u16* hh   = (u16*)(ws + ((size_t)112 << 20));            // 4 MiB [112,116)
    u16* hl   = (u16*)(ws + ((size_t)116 << 20));            // 4 MiB [116,120)
    // ybuf ALIASES w1h/w1l region [40,52): w1 planes are dead after k_up (stream-ordered),
    // ybuf is written by k_dn and read by k_final. 6144*512*4B = 12 MiB.
    float* ybuf = (float*)(ws + ((size_t)40 << 20));
    const bool fast3 = ws_size >= ((size_t)120 << 20);

    k_probe_init<<<1, 64, 0, stream>>>((const u32*)x, flag, counts);
    k_prep  <<<10752, 256, 0, stream>>>((const float*)x, x, wg,
                                        (const float*)w1, (const float*)w3,
                                        (const float*)wsg, (const float*)wsu,
                                        (const float*)wsd, (const float*)w2,
                                        w1h, w1l, w3h, w3l, wsgh, wsgl, wsuh, wsul,
                                        wsdh, wsdl, xh, xl, w2th, w2tl,
                                        counts, topki, topkw, accum, flag, fast3 ? 1 : 0);
    k_prefix<<<1, 64, 0, stream>>>(counts, offsets, cursors, tileE, tileT, tileC,
                                   ntiles, slot2tile);
    k_scatter<<<4, 256, 0, stream>>>(topki, topkw, cursors, tokl, wgtl, posl);

    if (fast3) {
        k_up <<<1536, 256, 0, stream>>>(xh, xl, w1h, w1l, w3h, w3l,
                                        wsgh, wsgl, wsuh, wsul, flag,
                                        offsets, tokl, wgtl,
                                        tileE, tileT, tileC, slot2tile,
                                        hh, hl, vh, vl);
        k_dn <<<1536, 256, 0, stream>>>(hh, hl, w2th, w2tl, vh, vl, wsdh, wsdl,
                                        flag, offsets,
                                        tileE, tileT, tileC, slot2tile, ybuf, accum);
        // bf16-input fallback (no-ops when flag==0)
        k_shared <<<128, 256, 0, stream>>>(x, wsg, wsu, wsd, flag, accum, 1);
        k_routed <<<256, 256, 0, stream>>>(x, w1, w2, w3, flag, offsets, counts, tokl, wgtl, accum, 1);
        k_final  <<<1024, 256, 0, stream>>>(accum, ybuf, posl, d_out, flag, 1);
    } else {
        // small workspace: legacy VALU path for both dtypes
        k_shared <<<128, 256, 0, stream>>>(x, wsg, wsu, wsd, flag, accum, 0);
        k_routed <<<256, 256, 0, stream>>>(x, w1, w2, w3, flag, offsets, counts, tokl, wgtl, accum, 0);
        k_final  <<<1024, 256, 0, stream>>>(accum, ybuf, posl, d_out, flag, 0);
    }
}